// Round 4
// baseline (1267.422 us; speedup 1.0000x reference)
//
#include <hip/hip_runtime.h>
#include <hip/hip_bf16.h>
#include <cstdint>
#include <cstddef>

constexpr int N_  = 20000;
constexpr int E_  = 320000;
constexpr int DIM_ = 128;
constexpr int L_  = 4;
constexpr int MP_ = 20032;   // M padded to multiple of 64

typedef short bf16x8 __attribute__((ext_vector_type(8)));
typedef float f32x4  __attribute__((ext_vector_type(4)));

__device__ __forceinline__ float gelu_f(float x) {
  float x3 = x * x * x;
  float t = tanhf(0.7978845608028654f * (x + 0.044715f * x3));
  return 0.5f * x * (1.0f + t);
}

__device__ __forceinline__ unsigned short f2bf(float x) {  // RNE
  unsigned u = __float_as_uint(x);
  u += 0x7fff + ((u >> 16) & 1);
  return (unsigned short)(u >> 16);
}
__device__ __forceinline__ float bf2f(unsigned short s) {
  return __uint_as_float((unsigned)s << 16);
}
__device__ __forceinline__ void splitf(float x, unsigned short& h, unsigned short& l) {
  h = f2bf(x);
  l = f2bf(x - bf2f(h));
}

// ---------------------------------------------------------------------------
// MFMA GEMM, bf16x2 split, dual accumulator streams (k0, k0+32) for ILP.
// Block 256 thr = 4 waves; wave tile 16 rows x 64 cols (ct=4).
// A planes [M][K] bf16; Bt planes [NC][K] bf16 (pre-transposed).
// EPI: 0 none, 1 gelu, 2 +res. QPACK: q fp32 [M][128] + kv bf16 [M][256].
// ---------------------------------------------------------------------------
template <int K, int NC, int EPI, bool WF32, bool WBF, bool QPACK>
__global__ __launch_bounds__(256) void mgemm_k(
    const unsigned short* __restrict__ Ahi, const unsigned short* __restrict__ Alo,
    const unsigned short* __restrict__ Bthi, const unsigned short* __restrict__ Btlo,
    const float* __restrict__ bias, const float* __restrict__ res,
    float* __restrict__ Cf, unsigned short* __restrict__ Chi, unsigned short* __restrict__ Clo,
    int M)
{
  const int wave = threadIdx.x >> 6;
  const int lane = threadIdx.x & 63;
  const int l15  = lane & 15;
  const int kq8  = (lane >> 4) * 8;
  const int r0   = blockIdx.x * 64 + wave * 16;
  const int c0   = blockIdx.y * 64;

  f32x4 acc[4], acc2[4];
#pragma unroll
  for (int ct = 0; ct < 4; ++ct) {
    acc[ct] = (f32x4){0.f, 0.f, 0.f, 0.f};
    acc2[ct] = (f32x4){0.f, 0.f, 0.f, 0.f};
  }

  const unsigned short* arh = Ahi + (size_t)(r0 + l15) * K + kq8;
  const unsigned short* arl = Alo + (size_t)(r0 + l15) * K + kq8;
  const unsigned short* bth = Bthi + (size_t)(c0 + l15) * K + kq8;
  const unsigned short* btl = Btlo + (size_t)(c0 + l15) * K + kq8;

#pragma unroll 2
  for (int k0 = 0; k0 < K; k0 += 64) {
    bf16x8 ah  = *(const bf16x8*)(arh + k0);
    bf16x8 al  = *(const bf16x8*)(arl + k0);
    bf16x8 ah2 = *(const bf16x8*)(arh + k0 + 32);
    bf16x8 al2 = *(const bf16x8*)(arl + k0 + 32);
#pragma unroll
    for (int ct = 0; ct < 4; ++ct) {
      bf16x8 bh  = *(const bf16x8*)(bth + ct * 16 * K + k0);
      bf16x8 bl  = *(const bf16x8*)(btl + ct * 16 * K + k0);
      bf16x8 bh2 = *(const bf16x8*)(bth + ct * 16 * K + k0 + 32);
      bf16x8 bl2 = *(const bf16x8*)(btl + ct * 16 * K + k0 + 32);
      acc[ct]  = __builtin_amdgcn_mfma_f32_16x16x32_bf16(ah, bh, acc[ct], 0, 0, 0);
      acc2[ct] = __builtin_amdgcn_mfma_f32_16x16x32_bf16(ah2, bh2, acc2[ct], 0, 0, 0);
      acc[ct]  = __builtin_amdgcn_mfma_f32_16x16x32_bf16(ah, bl, acc[ct], 0, 0, 0);
      acc2[ct] = __builtin_amdgcn_mfma_f32_16x16x32_bf16(ah2, bl2, acc2[ct], 0, 0, 0);
      acc[ct]  = __builtin_amdgcn_mfma_f32_16x16x32_bf16(al, bh, acc[ct], 0, 0, 0);
      acc2[ct] = __builtin_amdgcn_mfma_f32_16x16x32_bf16(al2, bh2, acc2[ct], 0, 0, 0);
    }
  }

  const int ccol  = lane & 15;
  const int crow0 = (lane >> 4) * 4;
#pragma unroll
  for (int ct = 0; ct < 4; ++ct) {
    int gc = c0 + ct * 16 + ccol;
    float bb = bias[gc];
#pragma unroll
    for (int r = 0; r < 4; ++r) {
      int gr = r0 + crow0 + r;
      if (gr >= M) continue;
      float o = acc[ct][r] + acc2[ct][r] + bb;
      if (EPI == 1) o = gelu_f(o);
      if (EPI == 2) o += res[(size_t)gr * NC + gc];
      if (QPACK) {
        if (c0 < 128) Cf[(size_t)gr * 128 + gc] = o;                  // q fp32
        else          Chi[(size_t)gr * 256 + gc - 128] = f2bf(o);     // k|v bf16
      } else {
        if (WF32) Cf[(size_t)gr * NC + gc] = o;
        if (WBF) {
          unsigned short hh, ll;
          splitf(o, hh, ll);
          Chi[(size_t)gr * NC + gc] = hh;
          Clo[(size_t)gr * NC + gc] = ll;
        }
      }
    }
  }
}

// ---------------------------------------------------------------------------
// Fused O-projection (K=128, NC=128) + residual + LayerNorm.
// Block = 64 full rows; each wave owns 16 rows x 128 cols (ct=8).
// LN row-reduce: lane-local sum over ct, then shfl_xor 1/2/4/8 within the
// 16-lane group that holds the row.
// ---------------------------------------------------------------------------
__global__ __launch_bounds__(256) void ogemm_ln_k(
    const unsigned short* __restrict__ Ahi, const unsigned short* __restrict__ Alo,
    const unsigned short* __restrict__ Bthi, const unsigned short* __restrict__ Btlo,
    const float* __restrict__ bias, const float* __restrict__ resid,
    const float* __restrict__ lnw, const float* __restrict__ lnb,
    float* __restrict__ lnF, unsigned short* __restrict__ lnHi,
    unsigned short* __restrict__ lnLo, int M)
{
  const int wave = threadIdx.x >> 6;
  const int lane = threadIdx.x & 63;
  const int l15  = lane & 15;
  const int kq8  = (lane >> 4) * 8;
  const int r0   = blockIdx.x * 64 + wave * 16;

  f32x4 acc[8];
#pragma unroll
  for (int ct = 0; ct < 8; ++ct) acc[ct] = (f32x4){0.f, 0.f, 0.f, 0.f};

  const unsigned short* arh = Ahi + (size_t)(r0 + l15) * 128 + kq8;
  const unsigned short* arl = Alo + (size_t)(r0 + l15) * 128 + kq8;
  const unsigned short* bth = Bthi + (size_t)l15 * 128 + kq8;
  const unsigned short* btl = Btlo + (size_t)l15 * 128 + kq8;

#pragma unroll 2
  for (int k0 = 0; k0 < 128; k0 += 32) {
    bf16x8 ah = *(const bf16x8*)(arh + k0);
    bf16x8 al = *(const bf16x8*)(arl + k0);
#pragma unroll
    for (int ct = 0; ct < 8; ++ct) {
      bf16x8 bh = *(const bf16x8*)(bth + ct * 16 * 128 + k0);
      bf16x8 bl = *(const bf16x8*)(btl + ct * 16 * 128 + k0);
      acc[ct] = __builtin_amdgcn_mfma_f32_16x16x32_bf16(ah, bh, acc[ct], 0, 0, 0);
      acc[ct] = __builtin_amdgcn_mfma_f32_16x16x32_bf16(ah, bl, acc[ct], 0, 0, 0);
      acc[ct] = __builtin_amdgcn_mfma_f32_16x16x32_bf16(al, bh, acc[ct], 0, 0, 0);
    }
  }

  const int ccol  = lane & 15;
  const int crow0 = (lane >> 4) * 4;

  // + bias + residual
#pragma unroll
  for (int ct = 0; ct < 8; ++ct) {
    int gc = ct * 16 + ccol;
    float bb = bias[gc];
#pragma unroll
    for (int r = 0; r < 4; ++r) {
      int gr = r0 + crow0 + r;
      acc[ct][r] += bb + resid[(size_t)gr * 128 + gc];
    }
  }

  // row means
  float mu[4];
#pragma unroll
  for (int r = 0; r < 4; ++r) {
    float s = 0.f;
#pragma unroll
    for (int ct = 0; ct < 8; ++ct) s += acc[ct][r];
    s += __shfl_xor(s, 1); s += __shfl_xor(s, 2);
    s += __shfl_xor(s, 4); s += __shfl_xor(s, 8);
    mu[r] = s * (1.f / 128.f);
  }
  // row variances
  float rstd[4];
#pragma unroll
  for (int r = 0; r < 4; ++r) {
    float s = 0.f;
#pragma unroll
    for (int ct = 0; ct < 8; ++ct) { float d = acc[ct][r] - mu[r]; s += d * d; }
    s += __shfl_xor(s, 1); s += __shfl_xor(s, 2);
    s += __shfl_xor(s, 4); s += __shfl_xor(s, 8);
    rstd[r] = rsqrtf(s * (1.f / 128.f) + 1e-5f);
  }

#pragma unroll
  for (int ct = 0; ct < 8; ++ct) {
    int gc = ct * 16 + ccol;
    float ww = lnw[gc], bb = lnb[gc];
#pragma unroll
    for (int r = 0; r < 4; ++r) {
      int gr = r0 + crow0 + r;
      if (gr >= M) continue;
      float o = (acc[ct][r] - mu[r]) * rstd[r] * ww + bb;
      lnF[(size_t)gr * 128 + gc] = o;
      unsigned short hh, ll;
      splitf(o, hh, ll);
      lnHi[(size_t)gr * 128 + gc] = hh;
      lnLo[(size_t)gr * 128 + gc] = ll;
    }
  }
}

// ---------------------------------------------------------------------------
// Weight transpose + split
// ---------------------------------------------------------------------------
__global__ __launch_bounds__(256) void wsplit_k(
    const float* __restrict__ in, unsigned short* __restrict__ hi,
    unsigned short* __restrict__ lo, int Lm, int K, int Nc,
    int layerStride, int rowOff)
{
  int total = Lm * K * Nc;
  for (int idx = blockIdx.x * blockDim.x + threadIdx.x; idx < total;
       idx += gridDim.x * blockDim.x) {
    int l = idx / (K * Nc);
    int r = idx - l * (K * Nc);
    int k = r / Nc;
    int c = r - k * Nc;
    float x = in[idx];
    size_t op = (size_t)l * layerStride + (size_t)(rowOff + c) * K + k;
    unsigned short hh, ll;
    splitf(x, hh, ll);
    hi[op] = hh; lo[op] = ll;
  }
}

__global__ __launch_bounds__(256) void qkvbias_k(
    const float* __restrict__ qb, const float* __restrict__ kb,
    const float* __restrict__ vb, float* __restrict__ out)
{
  int idx = blockIdx.x * blockDim.x + threadIdx.x;
  if (idx >= L_ * 384) return;
  int l = idx / 384, c = idx - l * 384;
  float x = (c < 128) ? qb[l * 128 + c] : (c < 256) ? kb[l * 128 + c - 128] : vb[l * 128 + c - 256];
  out[idx] = x;
}

__global__ __launch_bounds__(256) void nfsplit_k(
    const float* __restrict__ in, unsigned short* __restrict__ hi,
    unsigned short* __restrict__ lo, int total)
{
  for (int i = blockIdx.x * blockDim.x + threadIdx.x; i < total; i += gridDim.x * blockDim.x) {
    unsigned short hh, ll;
    splitf(in[i], hh, ll);
    hi[i] = hh; lo[i] = ll;
  }
}

// ---------------------------------------------------------------------------
// CSR build
// ---------------------------------------------------------------------------
__global__ __launch_bounds__(256) void init_zero_k(int* deg, int* cur, float* gsum, int n) {
  int i = blockIdx.x * blockDim.x + threadIdx.x;
  int st = gridDim.x * blockDim.x;
  for (int j = i; j < n; j += st) { deg[j] = 0; cur[j] = 0; }
  if (i < 128) gsum[i] = 0.f;
}

__global__ __launch_bounds__(256) void deg_k(const int* __restrict__ dst, int* __restrict__ deg, int E) {
  int e = blockIdx.x * blockDim.x + threadIdx.x;
  if (e < E) atomicAdd(&deg[dst[e]], 1);
}

__global__ __launch_bounds__(1024) void scan_k(const int* __restrict__ deg, int* __restrict__ offs, int n) {
  __shared__ int part[1024];
  int tid = threadIdx.x;
  const int chunk = (n + 1023) / 1024;
  int base = tid * chunk;
  int s = 0;
  for (int j = 0; j < chunk; ++j) { int idx = base + j; if (idx < n) s += deg[idx]; }
  part[tid] = s;
  __syncthreads();
  int own = s;
  for (int off = 1; off < 1024; off <<= 1) {
    int t = (tid >= off) ? part[tid - off] : 0;
    __syncthreads();
    part[tid] += t;
    __syncthreads();
  }
  int run = part[tid] - own;
  for (int j = 0; j < chunk; ++j) {
    int idx = base + j;
    if (idx <= n) offs[idx] = run;
    if (idx < n) run += deg[idx];
  }
}

__global__ __launch_bounds__(256) void fill_k(
    const int* __restrict__ src, const int* __restrict__ dst,
    const int* __restrict__ offs, int* __restrict__ cur,
    int* __restrict__ csrc, int E)
{
  int e = blockIdx.x * blockDim.x + threadIdx.x;
  if (e < E) {
    int d = dst[e];
    int p = atomicAdd(&cur[d], 1);
    csrc[offs[d] + p] = src[e];
  }
}

// ---------------------------------------------------------------------------
// Fused attention: branchless 8-chain online softmax, bf16 k/v gather.
// q fp32 [M][128]; kvbf bf16 [M][256] (k cols 0..127, v cols 128..255).
// One wave per (node, head-pair); 32-lane half-wave = one head.
// ---------------------------------------------------------------------------
__global__ __launch_bounds__(256) void attn_k(
    const float* __restrict__ q, const unsigned short* __restrict__ kvbf,
    const int* __restrict__ offs, const int* __restrict__ csrc,
    unsigned short* __restrict__ aggHi, unsigned short* __restrict__ aggLo, int M)
{
  constexpr int C = 8;
  int gw = (int)((blockIdx.x * blockDim.x + threadIdx.x) >> 6);
  int lane = threadIdx.x & 63;
  int n = gw >> 1, hp = gw & 1;
  if (n >= M) return;
  int col = hp * 64 + lane;
  const int e0 = offs[n], e1 = offs[n + 1];
  if (e1 == e0) {
    aggHi[(size_t)n * 128 + col] = 0;
    aggLo[(size_t)n * 128 + col] = 0;
    return;
  }
  float qv = q[(size_t)n * 128 + col] * 0.17677669529663687f;  // 1/sqrt(32)

  float m[C], den[C], acc[C];
#pragma unroll
  for (int j = 0; j < C; ++j) { m[j] = -3.0e38f; den[j] = 0.f; acc[j] = 0.f; }

  for (int base = e0; base < e1; base += C) {
    int srcs[C];
#pragma unroll
    for (int j = 0; j < C; ++j) {
      int e = base + j;
      srcs[j] = csrc[e < e1 ? e : e1 - 1];
    }
    float kv[C], vv[C];
#pragma unroll
    for (int j = 0; j < C; ++j) {
      const unsigned short* row = kvbf + (size_t)srcs[j] * 256;
      kv[j] = bf2f(row[col]);
      vv[j] = bf2f(row[128 + col]);
    }
#pragma unroll
    for (int j = 0; j < C; ++j) {
      bool valid = (base + j) < e1;
      float p = qv * kv[j];
      p += __shfl_xor(p, 1);
      p += __shfl_xor(p, 2);
      p += __shfl_xor(p, 4);
      p += __shfl_xor(p, 8);
      p += __shfl_xor(p, 16);
      p = valid ? p : -3.0e38f;
      float nm = fmaxf(m[j], p);
      float c = __expf(m[j] - nm);
      float w = __expf(p - nm) * (valid ? 1.f : 0.f);
      den[j] = den[j] * c + w;
      acc[j] = acc[j] * c + w * vv[j];
      m[j] = nm;
    }
  }

  float M4 = m[0];
#pragma unroll
  for (int j = 1; j < C; ++j) M4 = fmaxf(M4, m[j]);
  float dsum = 0.f, asum = 0.f;
#pragma unroll
  for (int j = 0; j < C; ++j) {
    float w = __expf(m[j] - M4);
    dsum += den[j] * w;
    asum += acc[j] * w;
  }
  float o = asum / dsum;
  unsigned short hh, ll;
  splitf(o, hh, ll);
  aggHi[(size_t)n * 128 + col] = hh;
  aggLo[(size_t)n * 128 + col] = ll;
}

// ---------------------------------------------------------------------------
__global__ __launch_bounds__(256) void colsum_k(const float* __restrict__ h, float* __restrict__ gsum, int M) {
  __shared__ float sd[256];
  int tid = threadIdx.x;
  int d = tid & 127, half = tid >> 7;
  float s = 0.f;
  for (int r = blockIdx.x * 2 + half; r < M; r += gridDim.x * 2)
    s += h[(size_t)r * 128 + d];
  sd[tid] = s;
  __syncthreads();
  if (tid < 128) atomicAdd(&gsum[d], sd[tid] + sd[tid + 128]);
}

__global__ __launch_bounds__(256) void classifier_k(
    const float* __restrict__ gsum,
    const float* __restrict__ lnw, const float* __restrict__ lnb,
    const float* __restrict__ cw1, const float* __restrict__ cb1,
    const float* __restrict__ cw2, const float* __restrict__ cb2,
    const float* __restrict__ clsw, const float* __restrict__ clsb,
    float* __restrict__ out_logits, float* __restrict__ out_g, float invN)
{
  __shared__ float z[128], h1[256], z2[128];
  int tid = threadIdx.x;
  if (tid < 128) {
    float gg = gsum[tid] * invN;
    out_g[tid] = gg;
    z[tid] = gg;
  }
  __syncthreads();
  if (tid < 64) {
    float a = z[tid], b2 = z[tid + 64];
    float s = a + b2;
#pragma unroll
    for (int d = 1; d < 64; d <<= 1) s += __shfl_xor(s, d);
    float mean = s * (1.f / 128.f);
    float ea = a - mean, eb = b2 - mean;
    float sq = ea * ea + eb * eb;
#pragma unroll
    for (int d = 1; d < 64; d <<= 1) sq += __shfl_xor(sq, d);
    float rstd = rsqrtf(sq * (1.f / 128.f) + 1e-5f);
    z[tid]      = ea * rstd * lnw[tid] + lnb[tid];
    z[tid + 64] = eb * rstd * lnw[tid + 64] + lnb[tid + 64];
  }
  __syncthreads();
  {
    float acc = cb1[tid];
    for (int f = 0; f < 128; ++f) acc = fmaf(z[f], cw1[f * 256 + tid], acc);
    h1[tid] = gelu_f(acc);
  }
  __syncthreads();
  if (tid < 128) {
    float acc = cb2[tid];
    for (int f = 0; f < 256; ++f) acc = fmaf(h1[f], cw2[f * 128 + tid], acc);
    z2[tid] = acc;
  }
  __syncthreads();
  if (tid < 10) {
    float acc = clsb[tid];
    for (int f = 0; f < 128; ++f) acc = fmaf(z2[f], clsw[f * 10 + tid], acc);
    out_logits[tid] = acc;
  }
}

// ---------------------------------------------------------------------------
extern "C" void kernel_launch(void* const* d_in, const int* in_sizes, int n_in,
                              void* d_out, int out_size, void* d_ws, size_t ws_size,
                              hipStream_t stream) {
  const float* node_features = (const float*)d_in[0];
  const int*   ei            = (const int*)d_in[1];
  const float* emb_w = (const float*)d_in[3];
  const float* emb_b = (const float*)d_in[4];
  const float* qw  = (const float*)d_in[7];  const float* qb  = (const float*)d_in[8];
  const float* kw  = (const float*)d_in[9];  const float* kb  = (const float*)d_in[10];
  const float* vw  = (const float*)d_in[11]; const float* vb  = (const float*)d_in[12];
  const float* ow  = (const float*)d_in[13]; const float* ob  = (const float*)d_in[14];
  const float* lnw = (const float*)d_in[15]; const float* lnb = (const float*)d_in[16];
  const float* mw1 = (const float*)d_in[17]; const float* mb1 = (const float*)d_in[18];
  const float* mw2 = (const float*)d_in[19]; const float* mb2 = (const float*)d_in[20];
  const float* clnw = (const float*)d_in[21]; const float* clnb = (const float*)d_in[22];
  const float* cw1 = (const float*)d_in[23]; const float* cb1 = (const float*)d_in[24];
  const float* cw2 = (const float*)d_in[25]; const float* cb2 = (const float*)d_in[26];
  const float* clsw = (const float*)d_in[27]; const float* clsb = (const float*)d_in[28];

  float* out = (float*)d_out;
  float* out_h = out + 10;
  float* out_g = out + 10 + (size_t)N_ * DIM_;

  char* p = (char*)d_ws;
  auto alloc = [&](size_t bytes) { char* r = p; p += (bytes + 255) & ~(size_t)255; return r; };

  float* h    = (float*)alloc((size_t)MP_ * 128 * 4);        // residual stream fp32
  float* qbuf = (float*)alloc((size_t)MP_ * 128 * 4);        // q fp32
  float* tmp  = (float*)alloc((size_t)MP_ * 128 * 4);        // LN fp32
  unsigned short* kvbf = (unsigned short*)alloc((size_t)MP_ * 256 * 2);  // k|v bf16
  unsigned short* h_hi = (unsigned short*)alloc((size_t)MP_ * 128 * 2);
  unsigned short* h_lo = (unsigned short*)alloc((size_t)MP_ * 128 * 2);
  unsigned short* sp_hi = (unsigned short*)alloc((size_t)MP_ * 128 * 2);  // agg planes
  unsigned short* sp_lo = (unsigned short*)alloc((size_t)MP_ * 128 * 2);
  unsigned short* ln_hi = (unsigned short*)alloc((size_t)MP_ * 128 * 2);  // LN planes
  unsigned short* ln_lo = (unsigned short*)alloc((size_t)MP_ * 128 * 2);
  unsigned short* hid_hi = (unsigned short*)alloc((size_t)MP_ * 512 * 2);
  unsigned short* hid_lo = (unsigned short*)alloc((size_t)MP_ * 512 * 2);
  unsigned short* wqkv_hi = (unsigned short*)alloc((size_t)L_ * 384 * 128 * 2);
  unsigned short* wqkv_lo = (unsigned short*)alloc((size_t)L_ * 384 * 128 * 2);
  unsigned short* wo_hi   = (unsigned short*)alloc((size_t)L_ * 128 * 128 * 2);
  unsigned short* wo_lo   = (unsigned short*)alloc((size_t)L_ * 128 * 128 * 2);
  unsigned short* w1_hi   = (unsigned short*)alloc((size_t)L_ * 512 * 128 * 2);
  unsigned short* w1_lo   = (unsigned short*)alloc((size_t)L_ * 512 * 128 * 2);
  unsigned short* w2_hi   = (unsigned short*)alloc((size_t)L_ * 128 * 512 * 2);
  unsigned short* w2_lo   = (unsigned short*)alloc((size_t)L_ * 128 * 512 * 2);
  unsigned short* we_hi   = (unsigned short*)alloc((size_t)128 * 64 * 2);
  unsigned short* we_lo   = (unsigned short*)alloc((size_t)128 * 64 * 2);
  float* qkvb = (float*)alloc((size_t)L_ * 384 * 4);
  float* gsum = (float*)alloc(128 * 4);
  int* deg  = (int*)alloc((size_t)N_ * 4);
  int* cur  = (int*)alloc((size_t)N_ * 4);
  int* offs = (int*)alloc(((size_t)N_ + 1) * 4);
  int* csrc = (int*)alloc((size_t)E_ * 4);
  unsigned short* nf_hi = hid_hi;   // alias: nf planes dead before hid written
  unsigned short* nf_lo = hid_lo;

  const int* esrc = ei;
  const int* edst = ei + E_;

  // CSR build
  init_zero_k<<<64, 256, 0, stream>>>(deg, cur, gsum, N_);
  deg_k<<<(E_ + 255) / 256, 256, 0, stream>>>(edst, deg, E_);
  scan_k<<<1, 1024, 0, stream>>>(deg, offs, N_);
  fill_k<<<(E_ + 255) / 256, 256, 0, stream>>>(esrc, edst, offs, cur, csrc, E_);

  // weight conversions
  auto wgrid = [](int total) { int g = (total + 255) / 256; return g > 2048 ? 2048 : g; };
  wsplit_k<<<wgrid(L_*128*128), 256, 0, stream>>>(qw, wqkv_hi, wqkv_lo, L_, 128, 128, 384*128, 0);
  wsplit_k<<<wgrid(L_*128*128), 256, 0, stream>>>(kw, wqkv_hi, wqkv_lo, L_, 128, 128, 384*128, 128);
  wsplit_k<<<wgrid(L_*128*128), 256, 0, stream>>>(vw, wqkv_hi, wqkv_lo, L_, 128, 128, 384*128, 256);
  wsplit_k<<<wgrid(L_*128*128), 256, 0, stream>>>(ow, wo_hi, wo_lo, L_, 128, 128, 128*128, 0);
  wsplit_k<<<wgrid(L_*128*512), 256, 0, stream>>>(mw1, w1_hi, w1_lo, L_, 128, 512, 512*128, 0);
  wsplit_k<<<wgrid(L_*512*128), 256, 0, stream>>>(mw2, w2_hi, w2_lo, L_, 512, 128, 128*512, 0);
  wsplit_k<<<wgrid(64*128), 256, 0, stream>>>(emb_w, we_hi, we_lo, 1, 64, 128, 128*64, 0);
  qkvbias_k<<<(L_*384 + 255) / 256, 256, 0, stream>>>(qb, kb, vb, qkvb);
  nfsplit_k<<<2048, 256, 0, stream>>>(node_features, nf_hi, nf_lo, N_ * 64);

  const int MB = (N_ + 63) / 64;  // 313

  // embed: h = nf @ emb_w + emb_b (fp32 + planes)
  mgemm_k<64, 128, 0, true, true, false><<<dim3(MB, 2), 256, 0, stream>>>(
      nf_hi, nf_lo, we_hi, we_lo, emb_b, nullptr, h, h_hi, h_lo, N_);

  for (int i = 0; i < L_; ++i) {
    const unsigned short* wq_h = wqkv_hi + (size_t)i * 384 * 128;
    const unsigned short* wq_l = wqkv_lo + (size_t)i * 384 * 128;

    // fused QKV -> q fp32 + kv bf16 packed
    mgemm_k<128, 384, 0, false, false, true><<<dim3(MB, 6), 256, 0, stream>>>(
        h_hi, h_lo, wq_h, wq_l, qkvb + (size_t)i * 384, nullptr,
        qbuf, kvbf, nullptr, N_);

    // attention -> agg planes (sp)
    attn_k<<<(2 * N_ * 64 + 255) / 256, 256, 0, stream>>>(
        qbuf, kvbf, offs, csrc, sp_hi, sp_lo, N_);

    // fused O-proj + residual(h) + LN -> tmp fp32 + ln planes
    ogemm_ln_k<<<dim3(MB), 256, 0, stream>>>(
        sp_hi, sp_lo, wo_hi + (size_t)i * 128 * 128, wo_lo + (size_t)i * 128 * 128,
        ob + (size_t)i * 128, h, lnw + (size_t)i * 128, lnb + (size_t)i * 128,
        tmp, ln_hi, ln_lo, N_);

    // MLP up: hid planes = gelu(ln @ mw1 + mb1)
    mgemm_k<128, 512, 1, false, true, false><<<dim3(MB, 8), 256, 0, stream>>>(
        ln_hi, ln_lo, w1_hi + (size_t)i * 512 * 128, w1_lo + (size_t)i * 512 * 128,
        mb1 + (size_t)i * 512, nullptr, nullptr, hid_hi, hid_lo, N_);

    // MLP down + residual(tmp): h = hid @ mw2 + mb2 + tmp (last layer -> out_h)
    float* hdst = (i == L_ - 1) ? out_h : h;
    mgemm_k<512, 128, 2, true, true, false><<<dim3(MB, 2), 256, 0, stream>>>(
        hid_hi, hid_lo, w2_hi + (size_t)i * 128 * 512, w2_lo + (size_t)i * 128 * 512,
        mb2 + (size_t)i * 128, tmp, hdst, h_hi, h_lo, N_);
  }

  colsum_k<<<64, 256, 0, stream>>>(out_h, gsum, N_);
  classifier_k<<<1, 256, 0, stream>>>(gsum, clnw, clnb, cw1, cb1, cw2, cb2, clsw, clsb,
                                      out, out_g, 1.0f / (float)N_);
}

// Round 5
// 1087.410 us; speedup vs baseline: 1.1655x; 1.1655x over previous
//
#include <hip/hip_runtime.h>
#include <hip/hip_bf16.h>
#include <cstdint>
#include <cstddef>

constexpr int N_  = 20000;
constexpr int E_  = 320000;
constexpr int DIM_ = 128;
constexpr int L_  = 4;
constexpr int MP_ = 20032;   // M padded to multiple of 64

typedef short bf16x8 __attribute__((ext_vector_type(8)));
typedef float f32x4  __attribute__((ext_vector_type(4)));

__device__ __forceinline__ float gelu_f(float x) {
  float x3 = x * x * x;
  float t = tanhf(0.7978845608028654f * (x + 0.044715f * x3));
  return 0.5f * x * (1.0f + t);
}

__device__ __forceinline__ unsigned short f2bf(float x) {  // RNE
  unsigned u = __float_as_uint(x);
  u += 0x7fff + ((u >> 16) & 1);
  return (unsigned short)(u >> 16);
}
__device__ __forceinline__ float bf2f(unsigned short s) {
  return __uint_as_float((unsigned)s << 16);
}
__device__ __forceinline__ void splitf(float x, unsigned short& h, unsigned short& l) {
  h = f2bf(x);
  l = f2bf(x - bf2f(h));
}

// ---------------------------------------------------------------------------
// MFMA GEMM, bf16x2 split (Ahi*Bhi + Ahi*Blo + Alo*Bhi ~= fp32). Single
// stream (lower VGPR), __launch_bounds__(256,4) caps VGPR at 128 so >=4
// blocks/CU. Block 256 thr = 4 waves; wave tile 16 rows x 64 cols (ct=4).
// A planes [M][K] bf16; Bt planes [NC][K] bf16 (pre-transposed).
// EPI: 0 none, 1 gelu, 2 +res. QPACK: q fp32 [M][128] + kv bf16 [M][256].
// ---------------------------------------------------------------------------
template <int K, int NC, int EPI, bool WF32, bool WBF, bool QPACK>
__global__ __launch_bounds__(256, 4) void mgemm_k(
    const unsigned short* __restrict__ Ahi, const unsigned short* __restrict__ Alo,
    const unsigned short* __restrict__ Bthi, const unsigned short* __restrict__ Btlo,
    const float* __restrict__ bias, const float* __restrict__ res,
    float* __restrict__ Cf, unsigned short* __restrict__ Chi, unsigned short* __restrict__ Clo,
    int M)
{
  const int wave = threadIdx.x >> 6;
  const int lane = threadIdx.x & 63;
  const int l15  = lane & 15;
  const int kq8  = (lane >> 4) * 8;
  const int r0   = blockIdx.x * 64 + wave * 16;
  const int c0   = blockIdx.y * 64;

  f32x4 acc[4];
#pragma unroll
  for (int ct = 0; ct < 4; ++ct) acc[ct] = (f32x4){0.f, 0.f, 0.f, 0.f};

  const unsigned short* arh = Ahi + (size_t)(r0 + l15) * K + kq8;
  const unsigned short* arl = Alo + (size_t)(r0 + l15) * K + kq8;
  const unsigned short* bth = Bthi + (size_t)(c0 + l15) * K + kq8;
  const unsigned short* btl = Btlo + (size_t)(c0 + l15) * K + kq8;

#pragma unroll 4
  for (int k0 = 0; k0 < K; k0 += 32) {
    bf16x8 ah = *(const bf16x8*)(arh + k0);
    bf16x8 al = *(const bf16x8*)(arl + k0);
#pragma unroll
    for (int ct = 0; ct < 4; ++ct) {
      bf16x8 bh = *(const bf16x8*)(bth + ct * 16 * K + k0);
      bf16x8 bl = *(const bf16x8*)(btl + ct * 16 * K + k0);
      acc[ct] = __builtin_amdgcn_mfma_f32_16x16x32_bf16(ah, bh, acc[ct], 0, 0, 0);
      acc[ct] = __builtin_amdgcn_mfma_f32_16x16x32_bf16(ah, bl, acc[ct], 0, 0, 0);
      acc[ct] = __builtin_amdgcn_mfma_f32_16x16x32_bf16(al, bh, acc[ct], 0, 0, 0);
    }
  }

  const int ccol  = lane & 15;
  const int crow0 = (lane >> 4) * 4;
#pragma unroll
  for (int ct = 0; ct < 4; ++ct) {
    int gc = c0 + ct * 16 + ccol;
    float bb = bias[gc];
#pragma unroll
    for (int r = 0; r < 4; ++r) {
      int gr = r0 + crow0 + r;
      if (gr >= M) continue;
      float o = acc[ct][r] + bb;
      if (EPI == 1) o = gelu_f(o);
      if (EPI == 2) o += res[(size_t)gr * NC + gc];
      if (QPACK) {
        if (c0 < 128) Cf[(size_t)gr * 128 + gc] = o;                  // q fp32
        else          Chi[(size_t)gr * 256 + gc - 128] = f2bf(o);     // k|v bf16
      } else {
        if (WF32) Cf[(size_t)gr * NC + gc] = o;
        if (WBF) {
          unsigned short hh, ll;
          splitf(o, hh, ll);
          Chi[(size_t)gr * NC + gc] = hh;
          Clo[(size_t)gr * NC + gc] = ll;
        }
      }
    }
  }
}

// ---------------------------------------------------------------------------
// Fused O-projection (K=128, NC=128) + residual + LayerNorm.
// ---------------------------------------------------------------------------
__global__ __launch_bounds__(256, 4) void ogemm_ln_k(
    const unsigned short* __restrict__ Ahi, const unsigned short* __restrict__ Alo,
    const unsigned short* __restrict__ Bthi, const unsigned short* __restrict__ Btlo,
    const float* __restrict__ bias, const float* __restrict__ resid,
    const float* __restrict__ lnw, const float* __restrict__ lnb,
    float* __restrict__ lnF, unsigned short* __restrict__ lnHi,
    unsigned short* __restrict__ lnLo, int M)
{
  const int wave = threadIdx.x >> 6;
  const int lane = threadIdx.x & 63;
  const int l15  = lane & 15;
  const int kq8  = (lane >> 4) * 8;
  const int r0   = blockIdx.x * 64 + wave * 16;

  f32x4 acc[8];
#pragma unroll
  for (int ct = 0; ct < 8; ++ct) acc[ct] = (f32x4){0.f, 0.f, 0.f, 0.f};

  const unsigned short* arh = Ahi + (size_t)(r0 + l15) * 128 + kq8;
  const unsigned short* arl = Alo + (size_t)(r0 + l15) * 128 + kq8;
  const unsigned short* bth = Bthi + (size_t)l15 * 128 + kq8;
  const unsigned short* btl = Btlo + (size_t)l15 * 128 + kq8;

#pragma unroll 2
  for (int k0 = 0; k0 < 128; k0 += 32) {
    bf16x8 ah = *(const bf16x8*)(arh + k0);
    bf16x8 al = *(const bf16x8*)(arl + k0);
#pragma unroll
    for (int ct = 0; ct < 8; ++ct) {
      bf16x8 bh = *(const bf16x8*)(bth + ct * 16 * 128 + k0);
      bf16x8 bl = *(const bf16x8*)(btl + ct * 16 * 128 + k0);
      acc[ct] = __builtin_amdgcn_mfma_f32_16x16x32_bf16(ah, bh, acc[ct], 0, 0, 0);
      acc[ct] = __builtin_amdgcn_mfma_f32_16x16x32_bf16(ah, bl, acc[ct], 0, 0, 0);
      acc[ct] = __builtin_amdgcn_mfma_f32_16x16x32_bf16(al, bh, acc[ct], 0, 0, 0);
    }
  }

  const int ccol  = lane & 15;
  const int crow0 = (lane >> 4) * 4;

#pragma unroll
  for (int ct = 0; ct < 8; ++ct) {
    int gc = ct * 16 + ccol;
    float bb = bias[gc];
#pragma unroll
    for (int r = 0; r < 4; ++r) {
      int gr = r0 + crow0 + r;
      acc[ct][r] += bb + resid[(size_t)gr * 128 + gc];
    }
  }

  float mu[4];
#pragma unroll
  for (int r = 0; r < 4; ++r) {
    float s = 0.f;
#pragma unroll
    for (int ct = 0; ct < 8; ++ct) s += acc[ct][r];
    s += __shfl_xor(s, 1); s += __shfl_xor(s, 2);
    s += __shfl_xor(s, 4); s += __shfl_xor(s, 8);
    mu[r] = s * (1.f / 128.f);
  }
  float rstd[4];
#pragma unroll
  for (int r = 0; r < 4; ++r) {
    float s = 0.f;
#pragma unroll
    for (int ct = 0; ct < 8; ++ct) { float d = acc[ct][r] - mu[r]; s += d * d; }
    s += __shfl_xor(s, 1); s += __shfl_xor(s, 2);
    s += __shfl_xor(s, 4); s += __shfl_xor(s, 8);
    rstd[r] = rsqrtf(s * (1.f / 128.f) + 1e-5f);
  }

#pragma unroll
  for (int ct = 0; ct < 8; ++ct) {
    int gc = ct * 16 + ccol;
    float ww = lnw[gc], bb = lnb[gc];
#pragma unroll
    for (int r = 0; r < 4; ++r) {
      int gr = r0 + crow0 + r;
      if (gr >= M) continue;
      float o = (acc[ct][r] - mu[r]) * rstd[r] * ww + bb;
      lnF[(size_t)gr * 128 + gc] = o;
      unsigned short hh, ll;
      splitf(o, hh, ll);
      lnHi[(size_t)gr * 128 + gc] = hh;
      lnLo[(size_t)gr * 128 + gc] = ll;
    }
  }
}

// ---------------------------------------------------------------------------
// Weight transpose + split
// ---------------------------------------------------------------------------
__global__ __launch_bounds__(256) void wsplit_k(
    const float* __restrict__ in, unsigned short* __restrict__ hi,
    unsigned short* __restrict__ lo, int Lm, int K, int Nc,
    int layerStride, int rowOff)
{
  int total = Lm * K * Nc;
  for (int idx = blockIdx.x * blockDim.x + threadIdx.x; idx < total;
       idx += gridDim.x * blockDim.x) {
    int l = idx / (K * Nc);
    int r = idx - l * (K * Nc);
    int k = r / Nc;
    int c = r - k * Nc;
    float x = in[idx];
    size_t op = (size_t)l * layerStride + (size_t)(rowOff + c) * K + k;
    unsigned short hh, ll;
    splitf(x, hh, ll);
    hi[op] = hh; lo[op] = ll;
  }
}

__global__ __launch_bounds__(256) void qkvbias_k(
    const float* __restrict__ qb, const float* __restrict__ kb,
    const float* __restrict__ vb, float* __restrict__ out)
{
  int idx = blockIdx.x * blockDim.x + threadIdx.x;
  if (idx >= L_ * 384) return;
  int l = idx / 384, c = idx - l * 384;
  float x = (c < 128) ? qb[l * 128 + c] : (c < 256) ? kb[l * 128 + c - 128] : vb[l * 128 + c - 256];
  out[idx] = x;
}

__global__ __launch_bounds__(256) void nfsplit_k(
    const float* __restrict__ in, unsigned short* __restrict__ hi,
    unsigned short* __restrict__ lo, int total)
{
  for (int i = blockIdx.x * blockDim.x + threadIdx.x; i < total; i += gridDim.x * blockDim.x) {
    unsigned short hh, ll;
    splitf(in[i], hh, ll);
    hi[i] = hh; lo[i] = ll;
  }
}

// ---------------------------------------------------------------------------
// CSR build (csrc = source node per slot, cdst = destination node per slot)
// ---------------------------------------------------------------------------
__global__ __launch_bounds__(256) void init_zero_k(int* deg, int* cur, float* gsum, int n) {
  int i = blockIdx.x * blockDim.x + threadIdx.x;
  int st = gridDim.x * blockDim.x;
  for (int j = i; j < n; j += st) { deg[j] = 0; cur[j] = 0; }
  if (i < 128) gsum[i] = 0.f;
}

__global__ __launch_bounds__(256) void deg_k(const int* __restrict__ dst, int* __restrict__ deg, int E) {
  int e = blockIdx.x * blockDim.x + threadIdx.x;
  if (e < E) atomicAdd(&deg[dst[e]], 1);
}

__global__ __launch_bounds__(1024) void scan_k(const int* __restrict__ deg, int* __restrict__ offs, int n) {
  __shared__ int part[1024];
  int tid = threadIdx.x;
  const int chunk = (n + 1023) / 1024;
  int base = tid * chunk;
  int s = 0;
  for (int j = 0; j < chunk; ++j) { int idx = base + j; if (idx < n) s += deg[idx]; }
  part[tid] = s;
  __syncthreads();
  int own = s;
  for (int off = 1; off < 1024; off <<= 1) {
    int t = (tid >= off) ? part[tid - off] : 0;
    __syncthreads();
    part[tid] += t;
    __syncthreads();
  }
  int run = part[tid] - own;
  for (int j = 0; j < chunk; ++j) {
    int idx = base + j;
    if (idx <= n) offs[idx] = run;
    if (idx < n) run += deg[idx];
  }
}

__global__ __launch_bounds__(256) void fill_k(
    const int* __restrict__ src, const int* __restrict__ dst,
    const int* __restrict__ offs, int* __restrict__ cur,
    int* __restrict__ csrc, int* __restrict__ cdst, int E)
{
  int e = blockIdx.x * blockDim.x + threadIdx.x;
  if (e < E) {
    int d = dst[e];
    int p = atomicAdd(&cur[d], 1);
    int o = offs[d] + p;
    csrc[o] = src[e];
    cdst[o] = d;
  }
}

// ---------------------------------------------------------------------------
// Attention phase 1: edge-parallel scores. One LANE per (CSR slot, head);
// lane layout: lane = h*16 + slot_local so 16 lanes of one head read 16
// different k-rows at the same 64B quarter. No cross-lane ops at all.
// sc layout [4][E] (head-major), CSR slot order.
// ---------------------------------------------------------------------------
__global__ __launch_bounds__(256) void scores_k(
    const float* __restrict__ q, const unsigned short* __restrict__ kvbf,
    const int* __restrict__ csrc, const int* __restrict__ cdst,
    float* __restrict__ sc)
{
  int t = blockIdx.x * 256 + threadIdx.x;
  int lane = t & 63;
  int slot = (t >> 6) * 16 + (lane & 15);
  int h = lane >> 4;
  if (slot >= E_) return;
  int s = csrc[slot], d = cdst[slot];
  const unsigned short* kr = kvbf + (size_t)s * 256 + h * 32;
  const float* qr = q + (size_t)d * 128 + h * 32;
  float acc = 0.f;
#pragma unroll
  for (int i = 0; i < 4; ++i) {
    bf16x8 k8 = *(const bf16x8*)(kr + i * 8);
    float4 q0 = *(const float4*)(qr + i * 8);
    float4 q1 = *(const float4*)(qr + i * 8 + 4);
    acc = fmaf(q0.x, bf2f((unsigned short)k8[0]), acc);
    acc = fmaf(q0.y, bf2f((unsigned short)k8[1]), acc);
    acc = fmaf(q0.z, bf2f((unsigned short)k8[2]), acc);
    acc = fmaf(q0.w, bf2f((unsigned short)k8[3]), acc);
    acc = fmaf(q1.x, bf2f((unsigned short)k8[4]), acc);
    acc = fmaf(q1.y, bf2f((unsigned short)k8[5]), acc);
    acc = fmaf(q1.z, bf2f((unsigned short)k8[6]), acc);
    acc = fmaf(q1.w, bf2f((unsigned short)k8[7]), acc);
  }
  sc[(size_t)h * E_ + slot] = acc * 0.17677669529663687f;  // 1/sqrt(32)
}

// ---------------------------------------------------------------------------
// Attention phase 2: exact softmax + weighted V aggregation.
// Wave per (node, head-pair); half-wave (32 lanes) = one head's 32 dims.
// Per 32-edge chunk: one shfl max/sum reduce; per edge: 2 broadcasts +
// 1 v-load + 1 FMA, 4-way unrolled so loads overlap.
// ---------------------------------------------------------------------------
__global__ __launch_bounds__(256) void agg_k(
    const float* __restrict__ sc, const unsigned short* __restrict__ kvbf,
    const int* __restrict__ offs, const int* __restrict__ csrc,
    unsigned short* __restrict__ aggHi, unsigned short* __restrict__ aggLo, int M)
{
  int gw = (int)((blockIdx.x * 256 + threadIdx.x) >> 6);
  int lane = threadIdx.x & 63;
  int n = gw >> 1, hp = gw & 1;
  if (n >= M) return;
  int col = hp * 64 + lane;
  const int e0 = offs[n], e1 = offs[n + 1];
  if (e0 == e1) {
    aggHi[(size_t)n * 128 + col] = 0;
    aggLo[(size_t)n * 128 + col] = 0;
    return;
  }
  const int h2 = hp * 2 + (lane >> 5);
  const int l31 = lane & 31;
  const float* scp = sc + (size_t)h2 * E_;

  // pass A: max (per half-wave)
  float mym = -3.0e38f;
  for (int c = e0; c < e1; c += 32) {
    int e = c + l31;
    float s = (e < e1) ? scp[e] : -3.0e38f;
    mym = fmaxf(mym, s);
  }
  mym = fmaxf(mym, __shfl_xor(mym, 1));
  mym = fmaxf(mym, __shfl_xor(mym, 2));
  mym = fmaxf(mym, __shfl_xor(mym, 4));
  mym = fmaxf(mym, __shfl_xor(mym, 8));
  mym = fmaxf(mym, __shfl_xor(mym, 16));

  // pass B: denominator + aggregation
  float den = 0.f, acc = 0.f;
  for (int c = e0; c < e1; c += 32) {
    int e = c + l31;
    bool val = e < e1;
    float w = val ? __expf(scp[e] - mym) : 0.f;
    int sv = val ? csrc[e] : 0;
    float ds = w;
    ds += __shfl_xor(ds, 1);
    ds += __shfl_xor(ds, 2);
    ds += __shfl_xor(ds, 4);
    ds += __shfl_xor(ds, 8);
    ds += __shfl_xor(ds, 16);
    den += ds;
    int cnt = e1 - c; if (cnt > 32) cnt = 32;
    int cnt4 = (cnt + 3) & ~3;
    for (int i = 0; i < cnt4; i += 4) {
      float wb0 = __shfl(w, (lane & 32) + i + 0);
      float wb1 = __shfl(w, (lane & 32) + i + 1);
      float wb2 = __shfl(w, (lane & 32) + i + 2);
      float wb3 = __shfl(w, (lane & 32) + i + 3);
      int sb0 = __shfl(sv, i + 0);
      int sb1 = __shfl(sv, i + 1);
      int sb2 = __shfl(sv, i + 2);
      int sb3 = __shfl(sv, i + 3);
      float v0 = bf2f(kvbf[(size_t)sb0 * 256 + 128 + col]);
      float v1 = bf2f(kvbf[(size_t)sb1 * 256 + 128 + col]);
      float v2 = bf2f(kvbf[(size_t)sb2 * 256 + 128 + col]);
      float v3 = bf2f(kvbf[(size_t)sb3 * 256 + 128 + col]);
      acc = fmaf(wb0, v0, acc);
      acc = fmaf(wb1, v1, acc);
      acc = fmaf(wb2, v2, acc);
      acc = fmaf(wb3, v3, acc);
    }
  }
  float o = acc / den;
  unsigned short hh, ll;
  splitf(o, hh, ll);
  aggHi[(size_t)n * 128 + col] = hh;
  aggLo[(size_t)n * 128 + col] = ll;
}

// ---------------------------------------------------------------------------
__global__ __launch_bounds__(256) void colsum_k(const float* __restrict__ h, float* __restrict__ gsum, int M) {
  __shared__ float sd[256];
  int tid = threadIdx.x;
  int d = tid & 127, half = tid >> 7;
  float s = 0.f;
  for (int r = blockIdx.x * 2 + half; r < M; r += gridDim.x * 2)
    s += h[(size_t)r * 128 + d];
  sd[tid] = s;
  __syncthreads();
  if (tid < 128) atomicAdd(&gsum[d], sd[tid] + sd[tid + 128]);
}

__global__ __launch_bounds__(256) void classifier_k(
    const float* __restrict__ gsum,
    const float* __restrict__ lnw, const float* __restrict__ lnb,
    const float* __restrict__ cw1, const float* __restrict__ cb1,
    const float* __restrict__ cw2, const float* __restrict__ cb2,
    const float* __restrict__ clsw, const float* __restrict__ clsb,
    float* __restrict__ out_logits, float* __restrict__ out_g, float invN)
{
  __shared__ float z[128], h1[256], z2[128];
  int tid = threadIdx.x;
  if (tid < 128) {
    float gg = gsum[tid] * invN;
    out_g[tid] = gg;
    z[tid] = gg;
  }
  __syncthreads();
  if (tid < 64) {
    float a = z[tid], b2 = z[tid + 64];
    float s = a + b2;
#pragma unroll
    for (int d = 1; d < 64; d <<= 1) s += __shfl_xor(s, d);
    float mean = s * (1.f / 128.f);
    float ea = a - mean, eb = b2 - mean;
    float sq = ea * ea + eb * eb;
#pragma unroll
    for (int d = 1; d < 64; d <<= 1) sq += __shfl_xor(sq, d);
    float rstd = rsqrtf(sq * (1.f / 128.f) + 1e-5f);
    z[tid]      = ea * rstd * lnw[tid] + lnb[tid];
    z[tid + 64] = eb * rstd * lnw[tid + 64] + lnb[tid + 64];
  }
  __syncthreads();
  {
    float acc = cb1[tid];
    for (int f = 0; f < 128; ++f) acc = fmaf(z[f], cw1[f * 256 + tid], acc);
    h1[tid] = gelu_f(acc);
  }
  __syncthreads();
  if (tid < 128) {
    float acc = cb2[tid];
    for (int f = 0; f < 256; ++f) acc = fmaf(h1[f], cw2[f * 128 + tid], acc);
    z2[tid] = acc;
  }
  __syncthreads();
  if (tid < 10) {
    float acc = clsb[tid];
    for (int f = 0; f < 128; ++f) acc = fmaf(z2[f], clsw[f * 10 + tid], acc);
    out_logits[tid] = acc;
  }
}

// ---------------------------------------------------------------------------
extern "C" void kernel_launch(void* const* d_in, const int* in_sizes, int n_in,
                              void* d_out, int out_size, void* d_ws, size_t ws_size,
                              hipStream_t stream) {
  const float* node_features = (const float*)d_in[0];
  const int*   ei            = (const int*)d_in[1];
  const float* emb_w = (const float*)d_in[3];
  const float* emb_b = (const float*)d_in[4];
  const float* qw  = (const float*)d_in[7];  const float* qb  = (const float*)d_in[8];
  const float* kw  = (const float*)d_in[9];  const float* kb  = (const float*)d_in[10];
  const float* vw  = (const float*)d_in[11]; const float* vb  = (const float*)d_in[12];
  const float* ow  = (const float*)d_in[13]; const float* ob  = (const float*)d_in[14];
  const float* lnw = (const float*)d_in[15]; const float* lnb = (const float*)d_in[16];
  const float* mw1 = (const float*)d_in[17]; const float* mb1 = (const float*)d_in[18];
  const float* mw2 = (const float*)d_in[19]; const float* mb2 = (const float*)d_in[20];
  const float* clnw = (const float*)d_in[21]; const float* clnb = (const float*)d_in[22];
  const float* cw1 = (const float*)d_in[23]; const float* cb1 = (const float*)d_in[24];
  const float* cw2 = (const float*)d_in[25]; const float* cb2 = (const float*)d_in[26];
  const float* clsw = (const float*)d_in[27]; const float* clsb = (const float*)d_in[28];

  float* out = (float*)d_out;
  float* out_h = out + 10;
  float* out_g = out + 10 + (size_t)N_ * DIM_;

  char* p = (char*)d_ws;
  auto alloc = [&](size_t bytes) { char* r = p; p += (bytes + 255) & ~(size_t)255; return r; };

  float* h    = (float*)alloc((size_t)MP_ * 128 * 4);        // residual stream fp32
  float* qbuf = (float*)alloc((size_t)MP_ * 128 * 4);        // q fp32
  float* tmp  = (float*)alloc((size_t)MP_ * 128 * 4);        // LN fp32
  unsigned short* kvbf = (unsigned short*)alloc((size_t)MP_ * 256 * 2);  // k|v bf16
  float* scb  = (float*)alloc((size_t)4 * E_ * 4);           // scores [4][E]
  unsigned short* h_hi = (unsigned short*)alloc((size_t)MP_ * 128 * 2);
  unsigned short* h_lo = (unsigned short*)alloc((size_t)MP_ * 128 * 2);
  unsigned short* sp_hi = (unsigned short*)alloc((size_t)MP_ * 128 * 2);  // agg planes
  unsigned short* sp_lo = (unsigned short*)alloc((size_t)MP_ * 128 * 2);
  unsigned short* ln_hi = (unsigned short*)alloc((size_t)MP_ * 128 * 2);  // LN planes
  unsigned short* ln_lo = (unsigned short*)alloc((size_t)MP_ * 128 * 2);
  unsigned short* hid_hi = (unsigned short*)alloc((size_t)MP_ * 512 * 2);
  unsigned short* hid_lo = (unsigned short*)alloc((size_t)MP_ * 512 * 2);
  unsigned short* wqkv_hi = (unsigned short*)alloc((size_t)L_ * 384 * 128 * 2);
  unsigned short* wqkv_lo = (unsigned short*)alloc((size_t)L_ * 384 * 128 * 2);
  unsigned short* wo_hi   = (unsigned short*)alloc((size_t)L_ * 128 * 128 * 2);
  unsigned short* wo_lo   = (unsigned short*)alloc((size_t)L_ * 128 * 128 * 2);
  unsigned short* w1_hi   = (unsigned short*)alloc((size_t)L_ * 512 * 128 * 2);
  unsigned short* w1_lo   = (unsigned short*)alloc((size_t)L_ * 512 * 128 * 2);
  unsigned short* w2_hi   = (unsigned short*)alloc((size_t)L_ * 128 * 512 * 2);
  unsigned short* w2_lo   = (unsigned short*)alloc((size_t)L_ * 128 * 512 * 2);
  unsigned short* we_hi   = (unsigned short*)alloc((size_t)128 * 64 * 2);
  unsigned short* we_lo   = (unsigned short*)alloc((size_t)128 * 64 * 2);
  float* qkvb = (float*)alloc((size_t)L_ * 384 * 4);
  float* gsum = (float*)alloc(128 * 4);
  int* deg  = (int*)alloc((size_t)N_ * 4);
  int* cur  = (int*)alloc((size_t)N_ * 4);
  int* offs = (int*)alloc(((size_t)N_ + 1) * 4);
  int* csrc = (int*)alloc((size_t)E_ * 4);
  int* cdst = (int*)alloc((size_t)E_ * 4);
  unsigned short* nf_hi = hid_hi;   // alias: nf planes dead before hid written
  unsigned short* nf_lo = hid_lo;

  const int* esrc = ei;
  const int* edst = ei + E_;

  // CSR build
  init_zero_k<<<64, 256, 0, stream>>>(deg, cur, gsum, N_);
  deg_k<<<(E_ + 255) / 256, 256, 0, stream>>>(edst, deg, E_);
  scan_k<<<1, 1024, 0, stream>>>(deg, offs, N_);
  fill_k<<<(E_ + 255) / 256, 256, 0, stream>>>(esrc, edst, offs, cur, csrc, cdst, E_);

  // weight conversions
  auto wgrid = [](int total) { int g = (total + 255) / 256; return g > 2048 ? 2048 : g; };
  wsplit_k<<<wgrid(L_*128*128), 256, 0, stream>>>(qw, wqkv_hi, wqkv_lo, L_, 128, 128, 384*128, 0);
  wsplit_k<<<wgrid(L_*128*128), 256, 0, stream>>>(kw, wqkv_hi, wqkv_lo, L_, 128, 128, 384*128, 128);
  wsplit_k<<<wgrid(L_*128*128), 256, 0, stream>>>(vw, wqkv_hi, wqkv_lo, L_, 128, 128, 384*128, 256);
  wsplit_k<<<wgrid(L_*128*128), 256, 0, stream>>>(ow, wo_hi, wo_lo, L_, 128, 128, 128*128, 0);
  wsplit_k<<<wgrid(L_*128*512), 256, 0, stream>>>(mw1, w1_hi, w1_lo, L_, 128, 512, 512*128, 0);
  wsplit_k<<<wgrid(L_*512*128), 256, 0, stream>>>(mw2, w2_hi, w2_lo, L_, 512, 128, 128*512, 0);
  wsplit_k<<<wgrid(64*128), 256, 0, stream>>>(emb_w, we_hi, we_lo, 1, 64, 128, 128*64, 0);
  qkvbias_k<<<(L_*384 + 255) / 256, 256, 0, stream>>>(qb, kb, vb, qkvb);
  nfsplit_k<<<2048, 256, 0, stream>>>(node_features, nf_hi, nf_lo, N_ * 64);

  const int MB = (N_ + 63) / 64;  // 313

  // embed: h = nf @ emb_w + emb_b (fp32 + planes)
  mgemm_k<64, 128, 0, true, true, false><<<dim3(MB, 2), 256, 0, stream>>>(
      nf_hi, nf_lo, we_hi, we_lo, emb_b, nullptr, h, h_hi, h_lo, N_);

  for (int i = 0; i < L_; ++i) {
    const unsigned short* wq_h = wqkv_hi + (size_t)i * 384 * 128;
    const unsigned short* wq_l = wqkv_lo + (size_t)i * 384 * 128;

    // fused QKV -> q fp32 + kv bf16 packed
    mgemm_k<128, 384, 0, false, false, true><<<dim3(MB, 6), 256, 0, stream>>>(
        h_hi, h_lo, wq_h, wq_l, qkvb + (size_t)i * 384, nullptr,
        qbuf, kvbf, nullptr, N_);

    // attention phase 1: edge-parallel scores
    scores_k<<<(E_ * 4 + 255) / 256, 256, 0, stream>>>(qbuf, kvbf, csrc, cdst, scb);

    // attention phase 2: exact softmax + V aggregation -> agg planes (sp)
    agg_k<<<(2 * N_ * 64 + 255) / 256, 256, 0, stream>>>(
        scb, kvbf, offs, csrc, sp_hi, sp_lo, N_);

    // fused O-proj + residual(h) + LN -> tmp fp32 + ln planes
    ogemm_ln_k<<<dim3(MB), 256, 0, stream>>>(
        sp_hi, sp_lo, wo_hi + (size_t)i * 128 * 128, wo_lo + (size_t)i * 128 * 128,
        ob + (size_t)i * 128, h, lnw + (size_t)i * 128, lnb + (size_t)i * 128,
        tmp, ln_hi, ln_lo, N_);

    // MLP up: hid planes = gelu(ln @ mw1 + mb1)
    mgemm_k<128, 512, 1, false, true, false><<<dim3(MB, 8), 256, 0, stream>>>(
        ln_hi, ln_lo, w1_hi + (size_t)i * 512 * 128, w1_lo + (size_t)i * 512 * 128,
        mb1 + (size_t)i * 512, nullptr, nullptr, hid_hi, hid_lo, N_);

    // MLP down + residual(tmp): h = hid @ mw2 + mb2 + tmp (last layer -> out_h)
    float* hdst = (i == L_ - 1) ? out_h : h;
    mgemm_k<512, 128, 2, true, true, false><<<dim3(MB, 2), 256, 0, stream>>>(
        hid_hi, hid_lo, w2_hi + (size_t)i * 128 * 512, w2_lo + (size_t)i * 128 * 512,
        mb2 + (size_t)i * 128, tmp, hdst, h_hi, h_lo, N_);
  }

  colsum_k<<<64, 256, 0, stream>>>(out_h, gsum, N_);
  classifier_k<<<1, 256, 0, stream>>>(gsum, clnw, clnb, cw1, cb1, cw2, cb2, clsw, clsb,
                                      out, out_g, 1.0f / (float)N_);
}

// Round 6
// 839.925 us; speedup vs baseline: 1.5090x; 1.2947x over previous
//
#include <hip/hip_runtime.h>
#include <hip/hip_bf16.h>
#include <cstdint>
#include <cstddef>

constexpr int N_  = 20000;
constexpr int E_  = 320000;
constexpr int DIM_ = 128;
constexpr int L_  = 4;
constexpr int MP_ = 20032;   // M padded

typedef short bf16x8 __attribute__((ext_vector_type(8)));
typedef float f32x4  __attribute__((ext_vector_type(4)));

__device__ __forceinline__ float gelu_f(float x) {
  float x3 = x * x * x;
  float z = 0.7978845608028654f * (x + 0.044715f * x3);
  float t = 1.f - 2.f / (__expf(2.f * z) + 1.f);   // tanh via fast exp
  return 0.5f * x * (1.0f + t);
}

__device__ __forceinline__ unsigned short f2bf(float x) {  // RNE
  unsigned u = __float_as_uint(x);
  u += 0x7fff + ((u >> 16) & 1);
  return (unsigned short)(u >> 16);
}
__device__ __forceinline__ float bf2f(unsigned short s) {
  return __uint_as_float((unsigned)s << 16);
}
__device__ __forceinline__ void splitf(float x, unsigned short& h, unsigned short& l) {
  h = f2bf(x);
  l = f2bf(x - bf2f(h));
}

// ---------------------------------------------------------------------------
// MFMA GEMM, bf16x2 split, B staged in LDS (shared by the block's 2 waves).
// Block 128 thr = 2 waves; block tile 32 rows x 64 cols; wave tile 16x64.
// LDS Bs[64][72]: stride 72 elems = 144 B -> 16B-aligned rows, near-optimal
// banking for both ds_write_b128 (staging) and ds_read_b128 (fragments).
// A direct from global (read-once). Chunked K (BK=64), barrier per chunk.
// WB: 0 none, 1 split hi/lo, 2 single bf16. EPI: 0 none, 1 gelu, 2 +res.
// QPACK: q fp32 [M][128] + kv bf16 [M][256]. ASPLIT: A has lo plane.
// ---------------------------------------------------------------------------
template <int K, int NC, int EPI, bool WF32, int WB, bool QPACK, bool ASPLIT>
__global__ __launch_bounds__(128, 4) void mgemm2_k(
    const unsigned short* __restrict__ Ahi, const unsigned short* __restrict__ Alo,
    const unsigned short* __restrict__ Bthi, const unsigned short* __restrict__ Btlo,
    const float* __restrict__ bias, const float* __restrict__ res,
    float* __restrict__ Cf, unsigned short* __restrict__ Chi, unsigned short* __restrict__ Clo,
    int M)
{
  __shared__ unsigned short BsH[64][72];
  __shared__ unsigned short BsL[64][72];
  const int tid  = threadIdx.x;
  const int wave = tid >> 6;
  const int lane = tid & 63;
  const int l15  = lane & 15;
  const int kq8  = (lane >> 4) * 8;
  const int r0   = blockIdx.x * 32 + wave * 16;
  const int c0   = blockIdx.y * 64;

  const int brow  = tid & 63;    // staging: B row (output col)
  const int bhalf = tid >> 6;    // staging: which 32-k half

  f32x4 acc[4];
#pragma unroll
  for (int ct = 0; ct < 4; ++ct) acc[ct] = (f32x4){0.f, 0.f, 0.f, 0.f};

  const unsigned short* arh = Ahi + (size_t)(r0 + l15) * K + kq8;
  const unsigned short* arl = ASPLIT ? (Alo + (size_t)(r0 + l15) * K + kq8) : Ahi;
  const unsigned short* bh_src = Bthi + (size_t)(c0 + brow) * K + bhalf * 32;
  const unsigned short* bl_src = Btlo + (size_t)(c0 + brow) * K + bhalf * 32;

  constexpr int NCH = K / 64;
#pragma unroll
  for (int c = 0; c < NCH; ++c) {
    const int ck = c * 64;
#pragma unroll
    for (int s = 0; s < 4; ++s) {
      *(bf16x8*)&BsH[brow][bhalf * 32 + s * 8] = *(const bf16x8*)(bh_src + ck + s * 8);
      *(bf16x8*)&BsL[brow][bhalf * 32 + s * 8] = *(const bf16x8*)(bl_src + ck + s * 8);
    }
    __syncthreads();
#pragma unroll
    for (int k0 = 0; k0 < 64; k0 += 32) {
      bf16x8 ah = *(const bf16x8*)(arh + ck + k0);
      bf16x8 al = ah;
      if (ASPLIT) al = *(const bf16x8*)(arl + ck + k0);
#pragma unroll
      for (int ct = 0; ct < 4; ++ct) {
        bf16x8 bh = *(const bf16x8*)&BsH[ct * 16 + l15][k0 + kq8];
        bf16x8 bl = *(const bf16x8*)&BsL[ct * 16 + l15][k0 + kq8];
        acc[ct] = __builtin_amdgcn_mfma_f32_16x16x32_bf16(ah, bh, acc[ct], 0, 0, 0);
        acc[ct] = __builtin_amdgcn_mfma_f32_16x16x32_bf16(ah, bl, acc[ct], 0, 0, 0);
        if (ASPLIT)
          acc[ct] = __builtin_amdgcn_mfma_f32_16x16x32_bf16(al, bh, acc[ct], 0, 0, 0);
      }
    }
    if (c + 1 < NCH) __syncthreads();
  }

  const int ccol  = lane & 15;
  const int crow0 = (lane >> 4) * 4;
#pragma unroll
  for (int ct = 0; ct < 4; ++ct) {
    int gc = c0 + ct * 16 + ccol;
    float bb = bias[gc];
#pragma unroll
    for (int r = 0; r < 4; ++r) {
      int gr = r0 + crow0 + r;
      if (gr >= M) continue;
      float o = acc[ct][r] + bb;
      if (EPI == 1) o = gelu_f(o);
      if (EPI == 2) o += res[(size_t)gr * NC + gc];
      if (QPACK) {
        if (c0 < 128) Cf[(size_t)gr * 128 + gc] = o;                 // q fp32
        else          Chi[(size_t)gr * 256 + gc - 128] = f2bf(o);    // k|v bf16
      } else {
        if (WF32) Cf[(size_t)gr * NC + gc] = o;
        if (WB == 1) {
          unsigned short hh, ll;
          splitf(o, hh, ll);
          Chi[(size_t)gr * NC + gc] = hh;
          Clo[(size_t)gr * NC + gc] = ll;
        }
        if (WB == 2) Chi[(size_t)gr * NC + gc] = f2bf(o);
      }
    }
  }
}

// ---------------------------------------------------------------------------
// Fused O-projection (K=128, NC=128) + residual + LayerNorm.
// 2-wave blocks, 32 rows each, full 128 cols per wave (ct=8).
// ---------------------------------------------------------------------------
__global__ __launch_bounds__(128, 4) void ogemm_ln_k(
    const unsigned short* __restrict__ Ahi, const unsigned short* __restrict__ Alo,
    const unsigned short* __restrict__ Bthi, const unsigned short* __restrict__ Btlo,
    const float* __restrict__ bias, const float* __restrict__ resid,
    const float* __restrict__ lnw, const float* __restrict__ lnb,
    float* __restrict__ lnF, unsigned short* __restrict__ lnHi,
    unsigned short* __restrict__ lnLo, int M)
{
  const int wave = threadIdx.x >> 6;
  const int lane = threadIdx.x & 63;
  const int l15  = lane & 15;
  const int kq8  = (lane >> 4) * 8;
  const int r0   = blockIdx.x * 32 + wave * 16;

  f32x4 acc[8];
#pragma unroll
  for (int ct = 0; ct < 8; ++ct) acc[ct] = (f32x4){0.f, 0.f, 0.f, 0.f};

  const unsigned short* arh = Ahi + (size_t)(r0 + l15) * 128 + kq8;
  const unsigned short* arl = Alo + (size_t)(r0 + l15) * 128 + kq8;
  const unsigned short* bth = Bthi + (size_t)l15 * 128 + kq8;
  const unsigned short* btl = Btlo + (size_t)l15 * 128 + kq8;

#pragma unroll
  for (int k0 = 0; k0 < 128; k0 += 32) {
    bf16x8 ah = *(const bf16x8*)(arh + k0);
    bf16x8 al = *(const bf16x8*)(arl + k0);
#pragma unroll
    for (int ct = 0; ct < 8; ++ct) {
      bf16x8 bh = *(const bf16x8*)(bth + ct * 16 * 128 + k0);
      bf16x8 bl = *(const bf16x8*)(btl + ct * 16 * 128 + k0);
      acc[ct] = __builtin_amdgcn_mfma_f32_16x16x32_bf16(ah, bh, acc[ct], 0, 0, 0);
      acc[ct] = __builtin_amdgcn_mfma_f32_16x16x32_bf16(ah, bl, acc[ct], 0, 0, 0);
      acc[ct] = __builtin_amdgcn_mfma_f32_16x16x32_bf16(al, bh, acc[ct], 0, 0, 0);
    }
  }

  const int ccol  = lane & 15;
  const int crow0 = (lane >> 4) * 4;

#pragma unroll
  for (int ct = 0; ct < 8; ++ct) {
    int gc = ct * 16 + ccol;
    float bb = bias[gc];
#pragma unroll
    for (int r = 0; r < 4; ++r) {
      int gr = r0 + crow0 + r;
      acc[ct][r] += bb + resid[(size_t)gr * 128 + gc];
    }
  }

  float mu[4];
#pragma unroll
  for (int r = 0; r < 4; ++r) {
    float s = 0.f;
#pragma unroll
    for (int ct = 0; ct < 8; ++ct) s += acc[ct][r];
    s += __shfl_xor(s, 1); s += __shfl_xor(s, 2);
    s += __shfl_xor(s, 4); s += __shfl_xor(s, 8);
    mu[r] = s * (1.f / 128.f);
  }
  float rstd[4];
#pragma unroll
  for (int r = 0; r < 4; ++r) {
    float s = 0.f;
#pragma unroll
    for (int ct = 0; ct < 8; ++ct) { float d = acc[ct][r] - mu[r]; s += d * d; }
    s += __shfl_xor(s, 1); s += __shfl_xor(s, 2);
    s += __shfl_xor(s, 4); s += __shfl_xor(s, 8);
    rstd[r] = rsqrtf(s * (1.f / 128.f) + 1e-5f);
  }

#pragma unroll
  for (int ct = 0; ct < 8; ++ct) {
    int gc = ct * 16 + ccol;
    float ww = lnw[gc], bb = lnb[gc];
#pragma unroll
    for (int r = 0; r < 4; ++r) {
      int gr = r0 + crow0 + r;
      if (gr >= M) continue;
      float o = (acc[ct][r] - mu[r]) * rstd[r] * ww + bb;
      lnF[(size_t)gr * 128 + gc] = o;
      unsigned short hh, ll;
      splitf(o, hh, ll);
      lnHi[(size_t)gr * 128 + gc] = hh;
      lnLo[(size_t)gr * 128 + gc] = ll;
    }
  }
}

// ---------------------------------------------------------------------------
// Weight transpose + split
// ---------------------------------------------------------------------------
__global__ __launch_bounds__(256) void wsplit_k(
    const float* __restrict__ in, unsigned short* __restrict__ hi,
    unsigned short* __restrict__ lo, int Lm, int K, int Nc,
    int layerStride, int rowOff)
{
  int total = Lm * K * Nc;
  for (int idx = blockIdx.x * blockDim.x + threadIdx.x; idx < total;
       idx += gridDim.x * blockDim.x) {
    int l = idx / (K * Nc);
    int r = idx - l * (K * Nc);
    int k = r / Nc;
    int c = r - k * Nc;
    float x = in[idx];
    size_t op = (size_t)l * layerStride + (size_t)(rowOff + c) * K + k;
    unsigned short hh, ll;
    splitf(x, hh, ll);
    hi[op] = hh; lo[op] = ll;
  }
}

__global__ __launch_bounds__(256) void qkvbias_k(
    const float* __restrict__ qb, const float* __restrict__ kb,
    const float* __restrict__ vb, float* __restrict__ out)
{
  int idx = blockIdx.x * blockDim.x + threadIdx.x;
  if (idx >= L_ * 384) return;
  int l = idx / 384, c = idx - l * 384;
  float x = (c < 128) ? qb[l * 128 + c] : (c < 256) ? kb[l * 128 + c - 128] : vb[l * 128 + c - 256];
  out[idx] = x;
}

__global__ __launch_bounds__(256) void nfsplit_k(
    const float* __restrict__ in, unsigned short* __restrict__ hi,
    unsigned short* __restrict__ lo, int total)
{
  for (int i = blockIdx.x * blockDim.x + threadIdx.x; i < total; i += gridDim.x * blockDim.x) {
    unsigned short hh, ll;
    splitf(in[i], hh, ll);
    hi[i] = hh; lo[i] = ll;
  }
}

// ---------------------------------------------------------------------------
// CSR build
// ---------------------------------------------------------------------------
__global__ __launch_bounds__(256) void init_zero_k(int* deg, int* cur, float* gsum, int n) {
  int i = blockIdx.x * blockDim.x + threadIdx.x;
  int st = gridDim.x * blockDim.x;
  for (int j = i; j < n; j += st) { deg[j] = 0; cur[j] = 0; }
  if (i < 128) gsum[i] = 0.f;
}

__global__ __launch_bounds__(256) void deg_k(const int* __restrict__ dst, int* __restrict__ deg, int E) {
  int e = blockIdx.x * blockDim.x + threadIdx.x;
  if (e < E) atomicAdd(&deg[dst[e]], 1);
}

__global__ __launch_bounds__(1024) void scan_k(const int* __restrict__ deg, int* __restrict__ offs, int n) {
  __shared__ int part[1024];
  int tid = threadIdx.x;
  const int chunk = (n + 1023) / 1024;
  int base = tid * chunk;
  int s = 0;
  for (int j = 0; j < chunk; ++j) { int idx = base + j; if (idx < n) s += deg[idx]; }
  part[tid] = s;
  __syncthreads();
  int own = s;
  for (int off = 1; off < 1024; off <<= 1) {
    int t = (tid >= off) ? part[tid - off] : 0;
    __syncthreads();
    part[tid] += t;
    __syncthreads();
  }
  int run = part[tid] - own;
  for (int j = 0; j < chunk; ++j) {
    int idx = base + j;
    if (idx <= n) offs[idx] = run;
    if (idx < n) run += deg[idx];
  }
}

__global__ __launch_bounds__(256) void fill_k(
    const int* __restrict__ src, const int* __restrict__ dst,
    const int* __restrict__ offs, int* __restrict__ cur,
    int* __restrict__ csrc, int* __restrict__ cdst, int E)
{
  int e = blockIdx.x * blockDim.x + threadIdx.x;
  if (e < E) {
    int d = dst[e];
    int p = atomicAdd(&cur[d], 1);
    int o = offs[d] + p;
    csrc[o] = src[e];
    cdst[o] = d;
  }
}

// ---------------------------------------------------------------------------
// Attention phase 1: edge-parallel scores (lane per (slot, head), no shfl)
// ---------------------------------------------------------------------------
__global__ __launch_bounds__(256) void scores_k(
    const float* __restrict__ q, const unsigned short* __restrict__ kvbf,
    const int* __restrict__ csrc, const int* __restrict__ cdst,
    float* __restrict__ sc)
{
  int t = blockIdx.x * 256 + threadIdx.x;
  int lane = t & 63;
  int slot = (t >> 6) * 16 + (lane & 15);
  int h = lane >> 4;
  if (slot >= E_) return;
  int s = csrc[slot], d = cdst[slot];
  const unsigned short* kr = kvbf + (size_t)s * 256 + h * 32;
  const float* qr = q + (size_t)d * 128 + h * 32;
  float acc = 0.f;
#pragma unroll
  for (int i = 0; i < 4; ++i) {
    bf16x8 k8 = *(const bf16x8*)(kr + i * 8);
    float4 q0 = *(const float4*)(qr + i * 8);
    float4 q1 = *(const float4*)(qr + i * 8 + 4);
    acc = fmaf(q0.x, bf2f((unsigned short)k8[0]), acc);
    acc = fmaf(q0.y, bf2f((unsigned short)k8[1]), acc);
    acc = fmaf(q0.z, bf2f((unsigned short)k8[2]), acc);
    acc = fmaf(q0.w, bf2f((unsigned short)k8[3]), acc);
    acc = fmaf(q1.x, bf2f((unsigned short)k8[4]), acc);
    acc = fmaf(q1.y, bf2f((unsigned short)k8[5]), acc);
    acc = fmaf(q1.z, bf2f((unsigned short)k8[6]), acc);
    acc = fmaf(q1.w, bf2f((unsigned short)k8[7]), acc);
  }
  sc[(size_t)h * E_ + slot] = acc * 0.17677669529663687f;
}

// ---------------------------------------------------------------------------
// Attention phase 2: exact softmax + weighted V aggregation
// ---------------------------------------------------------------------------
__global__ __launch_bounds__(256) void agg_k(
    const float* __restrict__ sc, const unsigned short* __restrict__ kvbf,
    const int* __restrict__ offs, const int* __restrict__ csrc,
    unsigned short* __restrict__ aggHi, unsigned short* __restrict__ aggLo, int M)
{
  int gw = (int)((blockIdx.x * 256 + threadIdx.x) >> 6);
  int lane = threadIdx.x & 63;
  int n = gw >> 1, hp = gw & 1;
  if (n >= M) return;
  int col = hp * 64 + lane;
  const int e0 = offs[n], e1 = offs[n + 1];
  if (e0 == e1) {
    aggHi[(size_t)n * 128 + col] = 0;
    aggLo[(size_t)n * 128 + col] = 0;
    return;
  }
  const int h2 = hp * 2 + (lane >> 5);
  const int l31 = lane & 31;
  const float* scp = sc + (size_t)h2 * E_;

  float mym = -3.0e38f;
  for (int c = e0; c < e1; c += 32) {
    int e = c + l31;
    float s = (e < e1) ? scp[e] : -3.0e38f;
    mym = fmaxf(mym, s);
  }
  mym = fmaxf(mym, __shfl_xor(mym, 1));
  mym = fmaxf(mym, __shfl_xor(mym, 2));
  mym = fmaxf(mym, __shfl_xor(mym, 4));
  mym = fmaxf(mym, __shfl_xor(mym, 8));
  mym = fmaxf(mym, __shfl_xor(mym, 16));

  float den = 0.f, acc = 0.f;
  for (int c = e0; c < e1; c += 32) {
    int e = c + l31;
    bool val = e < e1;
    float w = val ? __expf(scp[e] - mym) : 0.f;
    int sv = val ? csrc[e] : 0;
    float ds = w;
    ds += __shfl_xor(ds, 1);
    ds += __shfl_xor(ds, 2);
    ds += __shfl_xor(ds, 4);
    ds += __shfl_xor(ds, 8);
    ds += __shfl_xor(ds, 16);
    den += ds;
    int cnt = e1 - c; if (cnt > 32) cnt = 32;
    int cnt4 = (cnt + 3) & ~3;
    for (int i = 0; i < cnt4; i += 4) {
      float wb0 = __shfl(w, (lane & 32) + i + 0);
      float wb1 = __shfl(w, (lane & 32) + i + 1);
      float wb2 = __shfl(w, (lane & 32) + i + 2);
      float wb3 = __shfl(w, (lane & 32) + i + 3);
      int sb0 = __shfl(sv, i + 0);
      int sb1 = __shfl(sv, i + 1);
      int sb2 = __shfl(sv, i + 2);
      int sb3 = __shfl(sv, i + 3);
      float v0 = bf2f(kvbf[(size_t)sb0 * 256 + 128 + col]);
      float v1 = bf2f(kvbf[(size_t)sb1 * 256 + 128 + col]);
      float v2 = bf2f(kvbf[(size_t)sb2 * 256 + 128 + col]);
      float v3 = bf2f(kvbf[(size_t)sb3 * 256 + 128 + col]);
      acc = fmaf(wb0, v0, acc);
      acc = fmaf(wb1, v1, acc);
      acc = fmaf(wb2, v2, acc);
      acc = fmaf(wb3, v3, acc);
    }
  }
  float o = acc / den;
  unsigned short hh, ll;
  splitf(o, hh, ll);
  aggHi[(size_t)n * 128 + col] = hh;
  aggLo[(size_t)n * 128 + col] = ll;
}

// ---------------------------------------------------------------------------
__global__ __launch_bounds__(256) void colsum_k(const float* __restrict__ h, float* __restrict__ gsum, int M) {
  __shared__ float sd[256];
  int tid = threadIdx.x;
  int d = tid & 127, half = tid >> 7;
  float s = 0.f;
  for (int r = blockIdx.x * 2 + half; r < M; r += gridDim.x * 2)
    s += h[(size_t)r * 128 + d];
  sd[tid] = s;
  __syncthreads();
  if (tid < 128) atomicAdd(&gsum[d], sd[tid] + sd[tid + 128]);
}

__global__ __launch_bounds__(256) void classifier_k(
    const float* __restrict__ gsum,
    const float* __restrict__ lnw, const float* __restrict__ lnb,
    const float* __restrict__ cw1, const float* __restrict__ cb1,
    const float* __restrict__ cw2, const float* __restrict__ cb2,
    const float* __restrict__ clsw, const float* __restrict__ clsb,
    float* __restrict__ out_logits, float* __restrict__ out_g, float invN)
{
  __shared__ float z[128], h1[256], z2[128];
  int tid = threadIdx.x;
  if (tid < 128) {
    float gg = gsum[tid] * invN;
    out_g[tid] = gg;
    z[tid] = gg;
  }
  __syncthreads();
  if (tid < 64) {
    float a = z[tid], b2 = z[tid + 64];
    float s = a + b2;
#pragma unroll
    for (int d = 1; d < 64; d <<= 1) s += __shfl_xor(s, d);
    float mean = s * (1.f / 128.f);
    float ea = a - mean, eb = b2 - mean;
    float sq = ea * ea + eb * eb;
#pragma unroll
    for (int d = 1; d < 64; d <<= 1) sq += __shfl_xor(sq, d);
    float rstd = rsqrtf(sq * (1.f / 128.f) + 1e-5f);
    z[tid]      = ea * rstd * lnw[tid] + lnb[tid];
    z[tid + 64] = eb * rstd * lnw[tid + 64] + lnb[tid + 64];
  }
  __syncthreads();
  {
    float acc = cb1[tid];
    for (int f = 0; f < 128; ++f) acc = fmaf(z[f], cw1[f * 256 + tid], acc);
    h1[tid] = gelu_f(acc);
  }
  __syncthreads();
  if (tid < 128) {
    float acc = cb2[tid];
    for (int f = 0; f < 256; ++f) acc = fmaf(h1[f], cw2[f * 128 + tid], acc);
    z2[tid] = acc;
  }
  __syncthreads();
  if (tid < 10) {
    float acc = clsb[tid];
    for (int f = 0; f < 128; ++f) acc = fmaf(z2[f], clsw[f * 10 + tid], acc);
    out_logits[tid] = acc;
  }
}

// ---------------------------------------------------------------------------
extern "C" void kernel_launch(void* const* d_in, const int* in_sizes, int n_in,
                              void* d_out, int out_size, void* d_ws, size_t ws_size,
                              hipStream_t stream) {
  const float* node_features = (const float*)d_in[0];
  const int*   ei            = (const int*)d_in[1];
  const float* emb_w = (const float*)d_in[3];
  const float* emb_b = (const float*)d_in[4];
  const float* qw  = (const float*)d_in[7];  const float* qb  = (const float*)d_in[8];
  const float* kw  = (const float*)d_in[9];  const float* kb  = (const float*)d_in[10];
  const float* vw  = (const float*)d_in[11]; const float* vb  = (const float*)d_in[12];
  const float* ow  = (const float*)d_in[13]; const float* ob  = (const float*)d_in[14];
  const float* lnw = (const float*)d_in[15]; const float* lnb = (const float*)d_in[16];
  const float* mw1 = (const float*)d_in[17]; const float* mb1 = (const float*)d_in[18];
  const float* mw2 = (const float*)d_in[19]; const float* mb2 = (const float*)d_in[20];
  const float* clnw = (const float*)d_in[21]; const float* clnb = (const float*)d_in[22];
  const float* cw1 = (const float*)d_in[23]; const float* cb1 = (const float*)d_in[24];
  const float* cw2 = (const float*)d_in[25]; const float* cb2 = (const float*)d_in[26];
  const float* clsw = (const float*)d_in[27]; const float* clsb = (const float*)d_in[28];

  float* out = (float*)d_out;
  float* out_h = out + 10;
  float* out_g = out + 10 + (size_t)N_ * DIM_;

  char* p = (char*)d_ws;
  auto alloc = [&](size_t bytes) { char* r = p; p += (bytes + 255) & ~(size_t)255; return r; };

  float* h    = (float*)alloc((size_t)MP_ * 128 * 4);        // residual stream fp32
  float* qbuf = (float*)alloc((size_t)MP_ * 128 * 4);        // q fp32
  float* tmp  = (float*)alloc((size_t)MP_ * 128 * 4);        // LN fp32
  unsigned short* kvbf = (unsigned short*)alloc((size_t)MP_ * 256 * 2);  // k|v bf16
  float* scb  = (float*)alloc((size_t)4 * E_ * 4);           // scores [4][E]
  unsigned short* h_hi = (unsigned short*)alloc((size_t)MP_ * 128 * 2);
  unsigned short* h_lo = (unsigned short*)alloc((size_t)MP_ * 128 * 2);
  unsigned short* sp_hi = (unsigned short*)alloc((size_t)MP_ * 128 * 2);  // agg planes
  unsigned short* sp_lo = (unsigned short*)alloc((size_t)MP_ * 128 * 2);
  unsigned short* ln_hi = (unsigned short*)alloc((size_t)MP_ * 128 * 2);  // LN planes
  unsigned short* ln_lo = (unsigned short*)alloc((size_t)MP_ * 128 * 2);
  unsigned short* hid   = (unsigned short*)alloc((size_t)MP_ * 512 * 2);  // single bf16
  unsigned short* wqkv_hi = (unsigned short*)alloc((size_t)L_ * 384 * 128 * 2);
  unsigned short* wqkv_lo = (unsigned short*)alloc((size_t)L_ * 384 * 128 * 2);
  unsigned short* wo_hi   = (unsigned short*)alloc((size_t)L_ * 128 * 128 * 2);
  unsigned short* wo_lo   = (unsigned short*)alloc((size_t)L_ * 128 * 128 * 2);
  unsigned short* w1_hi   = (unsigned short*)alloc((size_t)L_ * 512 * 128 * 2);
  unsigned short* w1_lo   = (unsigned short*)alloc((size_t)L_ * 512 * 128 * 2);
  unsigned short* w2_hi   = (unsigned short*)alloc((size_t)L_ * 128 * 512 * 2);
  unsigned short* w2_lo   = (unsigned short*)alloc((size_t)L_ * 128 * 512 * 2);
  unsigned short* we_hi   = (unsigned short*)alloc((size_t)128 * 64 * 2);
  unsigned short* we_lo   = (unsigned short*)alloc((size_t)128 * 64 * 2);
  float* qkvb = (float*)alloc((size_t)L_ * 384 * 4);
  float* gsum = (float*)alloc(128 * 4);
  int* deg  = (int*)alloc((size_t)N_ * 4);
  int* cur  = (int*)alloc((size_t)N_ * 4);
  int* offs = (int*)alloc(((size_t)N_ + 1) * 4);
  int* csrc = (int*)alloc((size_t)E_ * 4);
  int* cdst = (int*)alloc((size_t)E_ * 4);
  // nf planes alias hid (nf dead before MLP-up writes hid)
  unsigned short* nf_hi = hid;
  unsigned short* nf_lo = hid + (size_t)MP_ * 64;

  const int* esrc = ei;
  const int* edst = ei + E_;

  // CSR build
  init_zero_k<<<64, 256, 0, stream>>>(deg, cur, gsum, N_);
  deg_k<<<(E_ + 255) / 256, 256, 0, stream>>>(edst, deg, E_);
  scan_k<<<1, 1024, 0, stream>>>(deg, offs, N_);
  fill_k<<<(E_ + 255) / 256, 256, 0, stream>>>(esrc, edst, offs, cur, csrc, cdst, E_);

  // weight conversions
  auto wgrid = [](int total) { int g = (total + 255) / 256; return g > 2048 ? 2048 : g; };
  wsplit_k<<<wgrid(L_*128*128), 256, 0, stream>>>(qw, wqkv_hi, wqkv_lo, L_, 128, 128, 384*128, 0);
  wsplit_k<<<wgrid(L_*128*128), 256, 0, stream>>>(kw, wqkv_hi, wqkv_lo, L_, 128, 128, 384*128, 128);
  wsplit_k<<<wgrid(L_*128*128), 256, 0, stream>>>(vw, wqkv_hi, wqkv_lo, L_, 128, 128, 384*128, 256);
  wsplit_k<<<wgrid(L_*128*128), 256, 0, stream>>>(ow, wo_hi, wo_lo, L_, 128, 128, 128*128, 0);
  wsplit_k<<<wgrid(L_*128*512), 256, 0, stream>>>(mw1, w1_hi, w1_lo, L_, 128, 512, 512*128, 0);
  wsplit_k<<<wgrid(L_*512*128), 256, 0, stream>>>(mw2, w2_hi, w2_lo, L_, 512, 128, 128*512, 0);
  wsplit_k<<<wgrid(64*128), 256, 0, stream>>>(emb_w, we_hi, we_lo, 1, 64, 128, 128*64, 0);
  qkvbias_k<<<(L_*384 + 255) / 256, 256, 0, stream>>>(qb, kb, vb, qkvb);
  nfsplit_k<<<2048, 256, 0, stream>>>(node_features, nf_hi, nf_lo, N_ * 64);

  const int MBR = (N_ + 31) / 32;  // 625

  // embed: h = nf @ emb_w + emb_b (fp32 + split planes)
  mgemm2_k<64, 128, 0, true, 1, false, true><<<dim3(MBR, 2), 128, 0, stream>>>(
      nf_hi, nf_lo, we_hi, we_lo, emb_b, nullptr, h, h_hi, h_lo, N_);

  for (int i = 0; i < L_; ++i) {
    const unsigned short* wq_h = wqkv_hi + (size_t)i * 384 * 128;
    const unsigned short* wq_l = wqkv_lo + (size_t)i * 384 * 128;

    // fused QKV -> q fp32 + kv bf16 packed
    mgemm2_k<128, 384, 0, false, 0, true, true><<<dim3(MBR, 6), 128, 0, stream>>>(
        h_hi, h_lo, wq_h, wq_l, qkvb + (size_t)i * 384, nullptr,
        qbuf, kvbf, nullptr, N_);

    // attention
    scores_k<<<(E_ * 4 + 255) / 256, 256, 0, stream>>>(qbuf, kvbf, csrc, cdst, scb);
    agg_k<<<(2 * N_ * 64 + 255) / 256, 256, 0, stream>>>(
        scb, kvbf, offs, csrc, sp_hi, sp_lo, N_);

    // fused O-proj + residual(h) + LN -> tmp fp32 + ln planes
    ogemm_ln_k<<<dim3(MBR), 128, 0, stream>>>(
        sp_hi, sp_lo, wo_hi + (size_t)i * 128 * 128, wo_lo + (size_t)i * 128 * 128,
        ob + (size_t)i * 128, h, lnw + (size_t)i * 128, lnb + (size_t)i * 128,
        tmp, ln_hi, ln_lo, N_);

    // MLP up: hid (single bf16) = gelu(ln @ mw1 + mb1)
    mgemm2_k<128, 512, 1, false, 2, false, true><<<dim3(MBR, 8), 128, 0, stream>>>(
        ln_hi, ln_lo, w1_hi + (size_t)i * 512 * 128, w1_lo + (size_t)i * 512 * 128,
        mb1 + (size_t)i * 512, nullptr, nullptr, hid, nullptr, N_);

    // MLP down + residual(tmp): h = hid @ mw2 + mb2 + tmp
    if (i == L_ - 1) {
      mgemm2_k<512, 128, 2, true, 0, false, false><<<dim3(MBR, 2), 128, 0, stream>>>(
          hid, nullptr, w2_hi + (size_t)i * 128 * 512, w2_lo + (size_t)i * 128 * 512,
          mb2 + (size_t)i * 128, tmp, out_h, nullptr, nullptr, N_);
    } else {
      mgemm2_k<512, 128, 2, true, 1, false, false><<<dim3(MBR, 2), 128, 0, stream>>>(
          hid, nullptr, w2_hi + (size_t)i * 128 * 512, w2_lo + (size_t)i * 128 * 512,
          mb2 + (size_t)i * 128, tmp, h, h_hi, h_lo, N_);
    }
  }

  colsum_k<<<64, 256, 0, stream>>>(out_h, gsum, N_);
  classifier_k<<<1, 256, 0, stream>>>(gsum, clnw, clnb, cw1, cb1, cw2, cb2, clsw, clsb,
                                      out, out_g, 1.0f / (float)N_);
}

// Round 7
// 822.519 us; speedup vs baseline: 1.5409x; 1.0212x over previous
//
#include <hip/hip_runtime.h>
#include <hip/hip_bf16.h>
#include <cstdint>
#include <cstddef>

constexpr int N_  = 20000;
constexpr int E_  = 320000;
constexpr int DIM_ = 128;
constexpr int L_  = 4;
constexpr int MP_ = 20032;   // M padded
constexpr int RPB8_ = 79;    // ceil(625 row-blocks / 8 XCDs)

typedef short bf16x8 __attribute__((ext_vector_type(8)));
typedef float f32x4  __attribute__((ext_vector_type(4)));

__device__ __forceinline__ float gelu_f(float x) {
  float x3 = x * x * x;
  float z = 0.7978845608028654f * (x + 0.044715f * x3);
  float t = 1.f - 2.f / (__expf(2.f * z) + 1.f);   // tanh via fast exp
  return 0.5f * x * (1.0f + t);
}

__device__ __forceinline__ unsigned short f2bf(float x) {  // RNE
  unsigned u = __float_as_uint(x);
  u += 0x7fff + ((u >> 16) & 1);
  return (unsigned short)(u >> 16);
}
__device__ __forceinline__ float bf2f(unsigned short s) {
  return __uint_as_float((unsigned)s << 16);
}
__device__ __forceinline__ void splitf(float x, unsigned short& h, unsigned short& l) {
  h = f2bf(x);
  l = f2bf(x - bf2f(h));
}

// ---------------------------------------------------------------------------
// MFMA GEMM, bf16x2 split, B staged in LDS, XCD-aware 1D grid:
//   bid -> xcd g = bid&7, slot s = bid>>3, rb = g*RPB8 + s/NCY, cc = s%NCY.
// All NCY col-chunks of a row-block land on the SAME XCD back-to-back, so
// the shared A-slice (16-32 KB) L2-hits instead of re-fetching from HBM.
// Block 128 thr = 2 waves; block tile 32 rows x 64 cols; wave tile 16x64.
// WB: 0 none, 1 split hi/lo, 2 single bf16. EPI: 0 none, 1 gelu, 2 +res.
// QPACK: q fp32 (pre-scaled by 1/sqrt(32)) + kv bf16 [M][256].
// ---------------------------------------------------------------------------
template <int K, int NC, int EPI, bool WF32, int WB, bool QPACK, bool ASPLIT>
__global__ __launch_bounds__(128, 4) void mgemm2_k(
    const unsigned short* __restrict__ Ahi, const unsigned short* __restrict__ Alo,
    const unsigned short* __restrict__ Bthi, const unsigned short* __restrict__ Btlo,
    const float* __restrict__ bias, const float* __restrict__ res,
    float* __restrict__ Cf, unsigned short* __restrict__ Chi, unsigned short* __restrict__ Clo,
    int M)
{
  constexpr int NCY = NC / 64;
  __shared__ unsigned short BsH[64][72];
  __shared__ unsigned short BsL[64][72];
  const int bid = blockIdx.x;
  const int g   = bid & 7;
  const int s   = bid >> 3;
  const int lr  = s / NCY;
  const int cc  = s - lr * NCY;
  const int rb  = g * RPB8_ + lr;
  if (rb * 32 >= M) return;

  const int tid  = threadIdx.x;
  const int wave = tid >> 6;
  const int lane = tid & 63;
  const int l15  = lane & 15;
  const int kq8  = (lane >> 4) * 8;
  const int r0   = rb * 32 + wave * 16;
  const int c0   = cc * 64;

  const int brow  = tid & 63;    // staging: B row (output col)
  const int bhalf = tid >> 6;    // staging: which 32-k half

  f32x4 acc[4];
#pragma unroll
  for (int ct = 0; ct < 4; ++ct) acc[ct] = (f32x4){0.f, 0.f, 0.f, 0.f};

  const unsigned short* arh = Ahi + (size_t)(r0 + l15) * K + kq8;
  const unsigned short* arl = ASPLIT ? (Alo + (size_t)(r0 + l15) * K + kq8) : Ahi;
  const unsigned short* bh_src = Bthi + (size_t)(c0 + brow) * K + bhalf * 32;
  const unsigned short* bl_src = Btlo + (size_t)(c0 + brow) * K + bhalf * 32;

  constexpr int NCH = K / 64;
#pragma unroll
  for (int c = 0; c < NCH; ++c) {
    const int ck = c * 64;
#pragma unroll
    for (int st = 0; st < 4; ++st) {
      *(bf16x8*)&BsH[brow][bhalf * 32 + st * 8] = *(const bf16x8*)(bh_src + ck + st * 8);
      *(bf16x8*)&BsL[brow][bhalf * 32 + st * 8] = *(const bf16x8*)(bl_src + ck + st * 8);
    }
    __syncthreads();
#pragma unroll
    for (int k0 = 0; k0 < 64; k0 += 32) {
      bf16x8 ah = *(const bf16x8*)(arh + ck + k0);
      bf16x8 al = ah;
      if (ASPLIT) al = *(const bf16x8*)(arl + ck + k0);
#pragma unroll
      for (int ct = 0; ct < 4; ++ct) {
        bf16x8 bh = *(const bf16x8*)&BsH[ct * 16 + l15][k0 + kq8];
        bf16x8 bl = *(const bf16x8*)&BsL[ct * 16 + l15][k0 + kq8];
        acc[ct] = __builtin_amdgcn_mfma_f32_16x16x32_bf16(ah, bh, acc[ct], 0, 0, 0);
        acc[ct] = __builtin_amdgcn_mfma_f32_16x16x32_bf16(ah, bl, acc[ct], 0, 0, 0);
        if (ASPLIT)
          acc[ct] = __builtin_amdgcn_mfma_f32_16x16x32_bf16(al, bh, acc[ct], 0, 0, 0);
      }
    }
    if (c + 1 < NCH) __syncthreads();
  }

  const int ccol  = lane & 15;
  const int crow0 = (lane >> 4) * 4;
#pragma unroll
  for (int ct = 0; ct < 4; ++ct) {
    int gc = c0 + ct * 16 + ccol;
    float bb = bias[gc];
#pragma unroll
    for (int r = 0; r < 4; ++r) {
      int gr = r0 + crow0 + r;
      if (gr >= M) continue;
      float o = acc[ct][r] + bb;
      if (EPI == 1) o = gelu_f(o);
      if (EPI == 2) o += res[(size_t)gr * NC + gc];
      if (QPACK) {
        if (c0 < 128) Cf[(size_t)gr * 128 + gc] = o * 0.17677669529663687f;  // q pre-scaled
        else          Chi[(size_t)gr * 256 + gc - 128] = f2bf(o);            // k|v bf16
      } else {
        if (WF32) Cf[(size_t)gr * NC + gc] = o;
        if (WB == 1) {
          unsigned short hh, ll;
          splitf(o, hh, ll);
          Chi[(size_t)gr * NC + gc] = hh;
          Clo[(size_t)gr * NC + gc] = ll;
        }
        if (WB == 2) Chi[(size_t)gr * NC + gc] = f2bf(o);
      }
    }
  }
}

// ---------------------------------------------------------------------------
// Fused O-projection (K=128, NC=128) + residual + LayerNorm.
// ---------------------------------------------------------------------------
__global__ __launch_bounds__(128, 4) void ogemm_ln_k(
    const unsigned short* __restrict__ Ahi, const unsigned short* __restrict__ Alo,
    const unsigned short* __restrict__ Bthi, const unsigned short* __restrict__ Btlo,
    const float* __restrict__ bias, const float* __restrict__ resid,
    const float* __restrict__ lnw, const float* __restrict__ lnb,
    float* __restrict__ lnF, unsigned short* __restrict__ lnHi,
    unsigned short* __restrict__ lnLo, int M)
{
  const int wave = threadIdx.x >> 6;
  const int lane = threadIdx.x & 63;
  const int l15  = lane & 15;
  const int kq8  = (lane >> 4) * 8;
  const int r0   = blockIdx.x * 32 + wave * 16;

  f32x4 acc[8];
#pragma unroll
  for (int ct = 0; ct < 8; ++ct) acc[ct] = (f32x4){0.f, 0.f, 0.f, 0.f};

  const unsigned short* arh = Ahi + (size_t)(r0 + l15) * 128 + kq8;
  const unsigned short* arl = Alo + (size_t)(r0 + l15) * 128 + kq8;
  const unsigned short* bth = Bthi + (size_t)l15 * 128 + kq8;
  const unsigned short* btl = Btlo + (size_t)l15 * 128 + kq8;

#pragma unroll
  for (int k0 = 0; k0 < 128; k0 += 32) {
    bf16x8 ah = *(const bf16x8*)(arh + k0);
    bf16x8 al = *(const bf16x8*)(arl + k0);
#pragma unroll
    for (int ct = 0; ct < 8; ++ct) {
      bf16x8 bh = *(const bf16x8*)(bth + ct * 16 * 128 + k0);
      bf16x8 bl = *(const bf16x8*)(btl + ct * 16 * 128 + k0);
      acc[ct] = __builtin_amdgcn_mfma_f32_16x16x32_bf16(ah, bh, acc[ct], 0, 0, 0);
      acc[ct] = __builtin_amdgcn_mfma_f32_16x16x32_bf16(ah, bl, acc[ct], 0, 0, 0);
      acc[ct] = __builtin_amdgcn_mfma_f32_16x16x32_bf16(al, bh, acc[ct], 0, 0, 0);
    }
  }

  const int ccol  = lane & 15;
  const int crow0 = (lane >> 4) * 4;

#pragma unroll
  for (int ct = 0; ct < 8; ++ct) {
    int gc = ct * 16 + ccol;
    float bb = bias[gc];
#pragma unroll
    for (int r = 0; r < 4; ++r) {
      int gr = r0 + crow0 + r;
      acc[ct][r] += bb + resid[(size_t)gr * 128 + gc];
    }
  }

  float mu[4];
#pragma unroll
  for (int r = 0; r < 4; ++r) {
    float s = 0.f;
#pragma unroll
    for (int ct = 0; ct < 8; ++ct) s += acc[ct][r];
    s += __shfl_xor(s, 1); s += __shfl_xor(s, 2);
    s += __shfl_xor(s, 4); s += __shfl_xor(s, 8);
    mu[r] = s * (1.f / 128.f);
  }
  float rstd[4];
#pragma unroll
  for (int r = 0; r < 4; ++r) {
    float s = 0.f;
#pragma unroll
    for (int ct = 0; ct < 8; ++ct) { float d = acc[ct][r] - mu[r]; s += d * d; }
    s += __shfl_xor(s, 1); s += __shfl_xor(s, 2);
    s += __shfl_xor(s, 4); s += __shfl_xor(s, 8);
    rstd[r] = rsqrtf(s * (1.f / 128.f) + 1e-5f);
  }

#pragma unroll
  for (int ct = 0; ct < 8; ++ct) {
    int gc = ct * 16 + ccol;
    float ww = lnw[gc], bb = lnb[gc];
#pragma unroll
    for (int r = 0; r < 4; ++r) {
      int gr = r0 + crow0 + r;
      if (gr >= M) continue;
      float o = (acc[ct][r] - mu[r]) * rstd[r] * ww + bb;
      lnF[(size_t)gr * 128 + gc] = o;
      unsigned short hh, ll;
      splitf(o, hh, ll);
      lnHi[(size_t)gr * 128 + gc] = hh;
      lnLo[(size_t)gr * 128 + gc] = ll;
    }
  }
}

// ---------------------------------------------------------------------------
// prep_k: ALL per-launch weight prep fused into one grid-stride kernel.
// Regions (element index space):
//  [0,3*65536)    qw/kw/vw -> wqkv planes (transposed, split)
//  [..+65536)     ow -> wo planes
//  [..+262144)    mw1 -> w1 planes
//  [..+262144)    mw2 -> w2 planes
//  [..+8192)      emb_w -> we planes
//  [..+1536)      qb|kb|vb -> qkvb
//  [..+1280000)   node_features -> nf planes (elementwise split)
//  [..+40128)     zero deg, cur, gsum
// ---------------------------------------------------------------------------
__global__ __launch_bounds__(256) void prep_k(
    const float* __restrict__ qw, const float* __restrict__ kw,
    const float* __restrict__ vw, const float* __restrict__ ow,
    const float* __restrict__ mw1, const float* __restrict__ mw2,
    const float* __restrict__ emb_w,
    const float* __restrict__ qb, const float* __restrict__ kb,
    const float* __restrict__ vb,
    const float* __restrict__ nf,
    unsigned short* __restrict__ wqkv_hi, unsigned short* __restrict__ wqkv_lo,
    unsigned short* __restrict__ wo_hi, unsigned short* __restrict__ wo_lo,
    unsigned short* __restrict__ w1_hi, unsigned short* __restrict__ w1_lo,
    unsigned short* __restrict__ w2_hi, unsigned short* __restrict__ w2_lo,
    unsigned short* __restrict__ we_hi, unsigned short* __restrict__ we_lo,
    float* __restrict__ qkvb,
    unsigned short* __restrict__ nf_hi, unsigned short* __restrict__ nf_lo,
    int* __restrict__ deg, int* __restrict__ cur, float* __restrict__ gsum)
{
  constexpr int T_qkv = 3 * L_ * 16384;          // 196608
  constexpr int T_o   = T_qkv + L_ * 16384;      // 262144
  constexpr int T_w1  = T_o + L_ * 65536;        // 524288
  constexpr int T_w2  = T_w1 + L_ * 65536;       // 786432
  constexpr int T_we  = T_w2 + 8192;             // 794624
  constexpr int T_b   = T_we + L_ * 384;         // 796160
  constexpr int T_nf  = T_b + N_ * 64;           // 2076160
  constexpr int T_z   = T_nf + 2 * N_ + 128;     // 2116288

  unsigned short hh, ll;
  for (int i = blockIdx.x * 256 + threadIdx.x; i < T_z; i += gridDim.x * 256) {
    if (i < T_qkv) {
      int which = i / (L_ * 16384);
      int r = i - which * (L_ * 16384);
      int l = r >> 14, rr = r & 16383;
      int k = rr >> 7, c = rr & 127;
      const float* src = (which == 0) ? qw : (which == 1) ? kw : vw;
      splitf(src[r], hh, ll);
      size_t op = (size_t)l * 49152 + (size_t)(which * 128 + c) * 128 + k;
      wqkv_hi[op] = hh; wqkv_lo[op] = ll;
    } else if (i < T_o) {
      int r = i - T_qkv;
      int l = r >> 14, rr = r & 16383;
      int k = rr >> 7, c = rr & 127;
      splitf(ow[r], hh, ll);
      size_t op = (size_t)l * 16384 + (size_t)c * 128 + k;
      wo_hi[op] = hh; wo_lo[op] = ll;
    } else if (i < T_w1) {
      int r = i - T_o;
      int l = r >> 16, rr = r & 65535;
      int k = rr >> 9, c = rr & 511;
      splitf(mw1[r], hh, ll);
      size_t op = (size_t)l * 65536 + (size_t)c * 128 + k;
      w1_hi[op] = hh; w1_lo[op] = ll;
    } else if (i < T_w2) {
      int r = i - T_w1;
      int l = r >> 16, rr = r & 65535;
      int k = rr >> 7, c = rr & 127;
      splitf(mw2[r], hh, ll);
      size_t op = (size_t)l * 65536 + (size_t)c * 512 + k;
      w2_hi[op] = hh; w2_lo[op] = ll;
    } else if (i < T_we) {
      int r = i - T_w2;
      int k = r >> 7, c = r & 127;
      splitf(emb_w[r], hh, ll);
      size_t op = (size_t)c * 64 + k;
      we_hi[op] = hh; we_lo[op] = ll;
    } else if (i < T_b) {
      int r = i - T_we;
      int l = r / 384, c = r - l * 384;
      float x = (c < 128) ? qb[l * 128 + c]
              : (c < 256) ? kb[l * 128 + c - 128]
                          : vb[l * 128 + c - 256];
      qkvb[r] = x;
    } else if (i < T_nf) {
      int r = i - T_b;
      splitf(nf[r], hh, ll);
      nf_hi[r] = hh; nf_lo[r] = ll;
    } else {
      int r = i - T_nf;
      if (r < N_) deg[r] = 0;
      else if (r < 2 * N_) cur[r - N_] = 0;
      else gsum[r - 2 * N_] = 0.f;
    }
  }
}

// ---------------------------------------------------------------------------
// CSR build
// ---------------------------------------------------------------------------
__global__ __launch_bounds__(256) void deg_k(const int* __restrict__ dst, int* __restrict__ deg, int E) {
  int e = blockIdx.x * blockDim.x + threadIdx.x;
  if (e < E) atomicAdd(&deg[dst[e]], 1);
}

__global__ __launch_bounds__(1024) void scan_k(const int* __restrict__ deg, int* __restrict__ offs, int n) {
  __shared__ int part[1024];
  int tid = threadIdx.x;
  const int chunk = (n + 1023) / 1024;
  int base = tid * chunk;
  int s = 0;
  for (int j = 0; j < chunk; ++j) { int idx = base + j; if (idx < n) s += deg[idx]; }
  part[tid] = s;
  __syncthreads();
  int own = s;
  for (int off = 1; off < 1024; off <<= 1) {
    int t = (tid >= off) ? part[tid - off] : 0;
    __syncthreads();
    part[tid] += t;
    __syncthreads();
  }
  int run = part[tid] - own;
  for (int j = 0; j < chunk; ++j) {
    int idx = base + j;
    if (idx <= n) offs[idx] = run;
    if (idx < n) run += deg[idx];
  }
}

__global__ __launch_bounds__(256) void fill_k(
    const int* __restrict__ src, const int* __restrict__ dst,
    const int* __restrict__ offs, int* __restrict__ cur,
    int* __restrict__ csrc, int* __restrict__ cdst, int E)
{
  int e = blockIdx.x * blockDim.x + threadIdx.x;
  if (e < E) {
    int d = dst[e];
    int p = atomicAdd(&cur[d], 1);
    int o = offs[d] + p;
    csrc[o] = src[e];
    cdst[o] = d;
  }
}

// ---------------------------------------------------------------------------
// Attention phase 1: edge-parallel scores (q pre-scaled; no shuffles)
// ---------------------------------------------------------------------------
__global__ __launch_bounds__(256) void scores_k(
    const float* __restrict__ q, const unsigned short* __restrict__ kvbf,
    const int* __restrict__ csrc, const int* __restrict__ cdst,
    float* __restrict__ sc)
{
  int t = blockIdx.x * 256 + threadIdx.x;
  int lane = t & 63;
  int slot = (t >> 6) * 16 + (lane & 15);
  int h = lane >> 4;
  if (slot >= E_) return;
  int s = csrc[slot], d = cdst[slot];
  const unsigned short* kr = kvbf + (size_t)s * 256 + h * 32;
  const float* qr = q + (size_t)d * 128 + h * 32;
  float acc = 0.f;
#pragma unroll
  for (int i = 0; i < 4; ++i) {
    bf16x8 k8 = *(const bf16x8*)(kr + i * 8);
    float4 q0 = *(const float4*)(qr + i * 8);
    float4 q1 = *(const float4*)(qr + i * 8 + 4);
    acc = fmaf(q0.x, bf2f((unsigned short)k8[0]), acc);
    acc = fmaf(q0.y, bf2f((unsigned short)k8[1]), acc);
    acc = fmaf(q0.z, bf2f((unsigned short)k8[2]), acc);
    acc = fmaf(q0.w, bf2f((unsigned short)k8[3]), acc);
    acc = fmaf(q1.x, bf2f((unsigned short)k8[4]), acc);
    acc = fmaf(q1.y, bf2f((unsigned short)k8[5]), acc);
    acc = fmaf(q1.z, bf2f((unsigned short)k8[6]), acc);
    acc = fmaf(q1.w, bf2f((unsigned short)k8[7]), acc);
  }
  sc[(size_t)h * E_ + slot] = acc;
}

// ---------------------------------------------------------------------------
// Attention phase 2: exact softmax + weighted V aggregation
// ---------------------------------------------------------------------------
__global__ __launch_bounds__(256) void agg_k(
    const float* __restrict__ sc, const unsigned short* __restrict__ kvbf,
    const int* __restrict__ offs, const int* __restrict__ csrc,
    unsigned short* __restrict__ aggHi, unsigned short* __restrict__ aggLo, int M)
{
  int gw = (int)((blockIdx.x * 256 + threadIdx.x) >> 6);
  int lane = threadIdx.x & 63;
  int n = gw >> 1, hp = gw & 1;
  if (n >= M) return;
  int col = hp * 64 + lane;
  const int e0 = offs[n], e1 = offs[n + 1];
  if (e0 == e1) {
    aggHi[(size_t)n * 128 + col] = 0;
    aggLo[(size_t)n * 128 + col] = 0;
    return;
  }
  const int h2 = hp * 2 + (lane >> 5);
  const int l31 = lane & 31;
  const float* scp = sc + (size_t)h2 * E_;

  float mym = -3.0e38f;
  for (int c = e0; c < e1; c += 32) {
    int e = c + l31;
    float s = (e < e1) ? scp[e] : -3.0e38f;
    mym = fmaxf(mym, s);
  }
  mym = fmaxf(mym, __shfl_xor(mym, 1));
  mym = fmaxf(mym, __shfl_xor(mym, 2));
  mym = fmaxf(mym, __shfl_xor(mym, 4));
  mym = fmaxf(mym, __shfl_xor(mym, 8));
  mym = fmaxf(mym, __shfl_xor(mym, 16));

  float den = 0.f, acc = 0.f;
  for (int c = e0; c < e1; c += 32) {
    int e = c + l31;
    bool val = e < e1;
    float w = val ? __expf(scp[e] - mym) : 0.f;
    int sv = val ? csrc[e] : 0;
    float ds = w;
    ds += __shfl_xor(ds, 1);
    ds += __shfl_xor(ds, 2);
    ds += __shfl_xor(ds, 4);
    ds += __shfl_xor(ds, 8);
    ds += __shfl_xor(ds, 16);
    den += ds;
    int cnt = e1 - c; if (cnt > 32) cnt = 32;
    int cnt4 = (cnt + 3) & ~3;
    for (int i = 0; i < cnt4; i += 4) {
      float wb0 = __shfl(w, (lane & 32) + i + 0);
      float wb1 = __shfl(w, (lane & 32) + i + 1);
      float wb2 = __shfl(w, (lane & 32) + i + 2);
      float wb3 = __shfl(w, (lane & 32) + i + 3);
      int sb0 = __shfl(sv, i + 0);
      int sb1 = __shfl(sv, i + 1);
      int sb2 = __shfl(sv, i + 2);
      int sb3 = __shfl(sv, i + 3);
      float v0 = bf2f(kvbf[(size_t)sb0 * 256 + 128 + col]);
      float v1 = bf2f(kvbf[(size_t)sb1 * 256 + 128 + col]);
      float v2 = bf2f(kvbf[(size_t)sb2 * 256 + 128 + col]);
      float v3 = bf2f(kvbf[(size_t)sb3 * 256 + 128 + col]);
      acc = fmaf(wb0, v0, acc);
      acc = fmaf(wb1, v1, acc);
      acc = fmaf(wb2, v2, acc);
      acc = fmaf(wb3, v3, acc);
    }
  }
  float o = acc / den;
  unsigned short hh, ll;
  splitf(o, hh, ll);
  aggHi[(size_t)n * 128 + col] = hh;
  aggLo[(size_t)n * 128 + col] = ll;
}

// ---------------------------------------------------------------------------
// Column sum (mean pool): 512 blocks, float4, LDS tree, 1 atomic/col/block
// ---------------------------------------------------------------------------
__global__ __launch_bounds__(256) void colsum_k(const float* __restrict__ h, float* __restrict__ gsum, int M) {
  __shared__ float sd[8][128];
  int tid = threadIdx.x;
  int cq = (tid & 31) * 4;
  int rg = tid >> 5;
  float4 s = make_float4(0.f, 0.f, 0.f, 0.f);
  for (int r = blockIdx.x * 8 + rg; r < M; r += gridDim.x * 8) {
    float4 v = *(const float4*)(h + (size_t)r * 128 + cq);
    s.x += v.x; s.y += v.y; s.z += v.z; s.w += v.w;
  }
  *(float4*)&sd[rg][cq] = s;
  __syncthreads();
  if (tid < 32) {
    int c4 = tid * 4;
    float4 a = *(float4*)&sd[0][c4];
#pragma unroll
    for (int g2 = 1; g2 < 8; ++g2) {
      float4 b = *(float4*)&sd[g2][c4];
      a.x += b.x; a.y += b.y; a.z += b.z; a.w += b.w;
    }
    atomicAdd(&gsum[c4 + 0], a.x);
    atomicAdd(&gsum[c4 + 1], a.y);
    atomicAdd(&gsum[c4 + 2], a.z);
    atomicAdd(&gsum[c4 + 3], a.w);
  }
}

__global__ __launch_bounds__(256) void classifier_k(
    const float* __restrict__ gsum,
    const float* __restrict__ lnw, const float* __restrict__ lnb,
    const float* __restrict__ cw1, const float* __restrict__ cb1,
    const float* __restrict__ cw2, const float* __restrict__ cb2,
    const float* __restrict__ clsw, const float* __restrict__ clsb,
    float* __restrict__ out_logits, float* __restrict__ out_g, float invN)
{
  __shared__ float z[128], h1[256], z2[128];
  int tid = threadIdx.x;
  if (tid < 128) {
    float gg = gsum[tid] * invN;
    out_g[tid] = gg;
    z[tid] = gg;
  }
  __syncthreads();
  if (tid < 64) {
    float a = z[tid], b2 = z[tid + 64];
    float s = a + b2;
#pragma unroll
    for (int d = 1; d < 64; d <<= 1) s += __shfl_xor(s, d);
    float mean = s * (1.f / 128.f);
    float ea = a - mean, eb = b2 - mean;
    float sq = ea * ea + eb * eb;
#pragma unroll
    for (int d = 1; d < 64; d <<= 1) sq += __shfl_xor(sq, d);
    float rstd = rsqrtf(sq * (1.f / 128.f) + 1e-5f);
    z[tid]      = ea * rstd * lnw[tid] + lnb[tid];
    z[tid + 64] = eb * rstd * lnw[tid + 64] + lnb[tid + 64];
  }
  __syncthreads();
  {
    float acc = cb1[tid];
    for (int f = 0; f < 128; ++f) acc = fmaf(z[f], cw1[f * 256 + tid], acc);
    h1[tid] = gelu_f(acc);
  }
  __syncthreads();
  if (tid < 128) {
    float acc = cb2[tid];
    for (int f = 0; f < 256; ++f) acc = fmaf(h1[f], cw2[f * 128 + tid], acc);
    z2[tid] = acc;
  }
  __syncthreads();
  if (tid < 10) {
    float acc = clsb[tid];
    for (int f = 0; f < 128; ++f) acc = fmaf(z2[f], clsw[f * 10 + tid], acc);
    out_logits[tid] = acc;
  }
}

// ---------------------------------------------------------------------------
extern "C" void kernel_launch(void* const* d_in, const int* in_sizes, int n_in,
                              void* d_out, int out_size, void* d_ws, size_t ws_size,
                              hipStream_t stream) {
  const float* node_features = (const float*)d_in[0];
  const int*   ei            = (const int*)d_in[1];
  const float* emb_w = (const float*)d_in[3];
  const float* emb_b = (const float*)d_in[4];
  const float* qw  = (const float*)d_in[7];  const float* qb  = (const float*)d_in[8];
  const float* kw  = (const float*)d_in[9];  const float* kb  = (const float*)d_in[10];
  const float* vw  = (const float*)d_in[11]; const float* vb  = (const float*)d_in[12];
  const float* ow  = (const float*)d_in[13]; const float* ob  = (const float*)d_in[14];
  const float* lnw = (const float*)d_in[15]; const float* lnb = (const float*)d_in[16];
  const float* mw1 = (const float*)d_in[17]; const float* mb1 = (const float*)d_in[18];
  const float* mw2 = (const float*)d_in[19]; const float* mb2 = (const float*)d_in[20];
  const float* clnw = (const float*)d_in[21]; const float* clnb = (const float*)d_in[22];
  const float* cw1 = (const float*)d_in[23]; const float* cb1 = (const float*)d_in[24];
  const float* cw2 = (const float*)d_in[25]; const float* cb2 = (const float*)d_in[26];
  const float* clsw = (const float*)d_in[27]; const float* clsb = (const float*)d_in[28];

  float* out = (float*)d_out;
  float* out_h = out + 10;
  float* out_g = out + 10 + (size_t)N_ * DIM_;

  char* p = (char*)d_ws;
  auto alloc = [&](size_t bytes) { char* r = p; p += (bytes + 255) & ~(size_t)255; return r; };

  float* h    = (float*)alloc((size_t)MP_ * 128 * 4);        // residual stream fp32
  float* qbuf = (float*)alloc((size_t)MP_ * 128 * 4);        // q fp32 (pre-scaled)
  float* tmp  = (float*)alloc((size_t)MP_ * 128 * 4);        // LN fp32
  unsigned short* kvbf = (unsigned short*)alloc((size_t)MP_ * 256 * 2);  // k|v bf16
  float* scb  = (float*)alloc((size_t)4 * E_ * 4);           // scores [4][E]
  unsigned short* h_hi = (unsigned short*)alloc((size_t)MP_ * 128 * 2);
  unsigned short* h_lo = (unsigned short*)alloc((size_t)MP_ * 128 * 2);
  unsigned short* sp_hi = (unsigned short*)alloc((size_t)MP_ * 128 * 2);  // agg planes
  unsigned short* sp_lo = (unsigned short*)alloc((size_t)MP_ * 128 * 2);
  unsigned short* ln_hi = (unsigned short*)alloc((size_t)MP_ * 128 * 2);  // LN planes
  unsigned short* ln_lo = (unsigned short*)alloc((size_t)MP_ * 128 * 2);
  unsigned short* hid   = (unsigned short*)alloc((size_t)MP_ * 512 * 2);  // single bf16
  unsigned short* wqkv_hi = (unsigned short*)alloc((size_t)L_ * 384 * 128 * 2);
  unsigned short* wqkv_lo = (unsigned short*)alloc((size_t)L_ * 384 * 128 * 2);
  unsigned short* wo_hi   = (unsigned short*)alloc((size_t)L_ * 128 * 128 * 2);
  unsigned short* wo_lo   = (unsigned short*)alloc((size_t)L_ * 128 * 128 * 2);
  unsigned short* w1_hi   = (unsigned short*)alloc((size_t)L_ * 512 * 128 * 2);
  unsigned short* w1_lo   = (unsigned short*)alloc((size_t)L_ * 512 * 128 * 2);
  unsigned short* w2_hi   = (unsigned short*)alloc((size_t)L_ * 128 * 512 * 2);
  unsigned short* w2_lo   = (unsigned short*)alloc((size_t)L_ * 128 * 512 * 2);
  unsigned short* we_hi   = (unsigned short*)alloc((size_t)128 * 64 * 2);
  unsigned short* we_lo   = (unsigned short*)alloc((size_t)128 * 64 * 2);
  float* qkvb = (float*)alloc((size_t)L_ * 384 * 4);
  float* gsum = (float*)alloc(128 * 4);
  int* deg  = (int*)alloc((size_t)N_ * 4);
  int* cur  = (int*)alloc((size_t)N_ * 4);
  int* offs = (int*)alloc(((size_t)N_ + 1) * 4);
  int* csrc = (int*)alloc((size_t)E_ * 4);
  int* cdst = (int*)alloc((size_t)E_ * 4);
  // nf planes alias hid (nf dead before MLP-up writes hid)
  unsigned short* nf_hi = hid;
  unsigned short* nf_lo = hid + (size_t)MP_ * 64;

  const int* esrc = ei;
  const int* edst = ei + E_;

  // fused prep: all weight transposes/splits + bias pack + nf split + zeroing
  prep_k<<<2048, 256, 0, stream>>>(
      qw, kw, vw, ow, mw1, mw2, emb_w, qb, kb, vb, node_features,
      wqkv_hi, wqkv_lo, wo_hi, wo_lo, w1_hi, w1_lo, w2_hi, w2_lo,
      we_hi, we_lo, qkvb, nf_hi, nf_lo, deg, cur, gsum);

  // CSR build
  deg_k<<<(E_ + 255) / 256, 256, 0, stream>>>(edst, deg, E_);
  scan_k<<<1, 1024, 0, stream>>>(deg, offs, N_);
  fill_k<<<(E_ + 255) / 256, 256, 0, stream>>>(esrc, edst, offs, cur, csrc, cdst, E_);

  // swizzled grids: 8 XCDs * RPB8 row-groups * NCY col-chunks
  auto sgrid = [](int ncy) { return dim3(8 * RPB8_ * ncy); };

  // embed: h = nf @ emb_w + emb_b (fp32 + split planes)
  mgemm2_k<64, 128, 0, true, 1, false, true><<<sgrid(2), 128, 0, stream>>>(
      nf_hi, nf_lo, we_hi, we_lo, emb_b, nullptr, h, h_hi, h_lo, N_);

  for (int i = 0; i < L_; ++i) {
    const unsigned short* wq_h = wqkv_hi + (size_t)i * 384 * 128;
    const unsigned short* wq_l = wqkv_lo + (size_t)i * 384 * 128;

    // fused QKV -> q fp32 (pre-scaled) + kv bf16 packed
    mgemm2_k<128, 384, 0, false, 0, true, true><<<sgrid(6), 128, 0, stream>>>(
        h_hi, h_lo, wq_h, wq_l, qkvb + (size_t)i * 384, nullptr,
        qbuf, kvbf, nullptr, N_);

    // attention
    scores_k<<<(E_ * 4 + 255) / 256, 256, 0, stream>>>(qbuf, kvbf, csrc, cdst, scb);
    agg_k<<<(2 * N_ * 64 + 255) / 256, 256, 0, stream>>>(
        scb, kvbf, offs, csrc, sp_hi, sp_lo, N_);

    // fused O-proj + residual(h) + LN -> tmp fp32 + ln planes
    ogemm_ln_k<<<dim3((N_ + 31) / 32), 128, 0, stream>>>(
        sp_hi, sp_lo, wo_hi + (size_t)i * 128 * 128, wo_lo + (size_t)i * 128 * 128,
        ob + (size_t)i * 128, h, lnw + (size_t)i * 128, lnb + (size_t)i * 128,
        tmp, ln_hi, ln_lo, N_);

    // MLP up: hid (single bf16) = gelu(ln @ mw1 + mb1)
    mgemm2_k<128, 512, 1, false, 2, false, true><<<sgrid(8), 128, 0, stream>>>(
        ln_hi, ln_lo, w1_hi + (size_t)i * 512 * 128, w1_lo + (size_t)i * 512 * 128,
        mb1 + (size_t)i * 512, nullptr, nullptr, hid, nullptr, N_);

    // MLP down + residual(tmp): h = hid @ mw2 + mb2 + tmp
    if (i == L_ - 1) {
      mgemm2_k<512, 128, 2, true, 0, false, false><<<sgrid(2), 128, 0, stream>>>(
          hid, nullptr, w2_hi + (size_t)i * 128 * 512, w2_lo + (size_t)i * 128 * 512,
          mb2 + (size_t)i * 128, tmp, out_h, nullptr, nullptr, N_);
    } else {
      mgemm2_k<512, 128, 2, true, 1, false, false><<<sgrid(2), 128, 0, stream>>>(
          hid, nullptr, w2_hi + (size_t)i * 128 * 512, w2_lo + (size_t)i * 128 * 512,
          mb2 + (size_t)i * 128, tmp, h, h_hi, h_lo, N_);
    }
  }

  colsum_k<<<512, 256, 0, stream>>>(out_h, gsum, N_);
  classifier_k<<<1, 256, 0, stream>>>(gsum, clnw, clnb, cw1, cb1, cw2, cb2, clsw, clsb,
                                      out, out_g, 1.0f / (float)N_);
}

// Round 8
// 816.014 us; speedup vs baseline: 1.5532x; 1.0080x over previous
//
#include <hip/hip_runtime.h>
#include <hip/hip_bf16.h>
#include <cstdint>
#include <cstddef>

constexpr int N_  = 20000;
constexpr int E_  = 320000;
constexpr int DIM_ = 128;
constexpr int L_  = 4;
constexpr int MP_ = 20032;   // M padded
constexpr int RPB8_ = 79;    // ceil(625 row-blocks / 8 XCDs)

typedef short bf16x8 __attribute__((ext_vector_type(8)));
typedef float f32x4  __attribute__((ext_vector_type(4)));

__device__ __forceinline__ float gelu_f(float x) {
  float x3 = x * x * x;
  float z = 0.7978845608028654f * (x + 0.044715f * x3);
  float t = 1.f - 2.f / (__expf(2.f * z) + 1.f);   // tanh via fast exp
  return 0.5f * x * (1.0f + t);
}

__device__ __forceinline__ unsigned short f2bf(float x) {  // RNE
  unsigned u = __float_as_uint(x);
  u += 0x7fff + ((u >> 16) & 1);
  return (unsigned short)(u >> 16);
}
__device__ __forceinline__ float bf2f(unsigned short s) {
  return __uint_as_float((unsigned)s << 16);
}
__device__ __forceinline__ void splitf(float x, unsigned short& h, unsigned short& l) {
  h = f2bf(x);
  l = f2bf(x - bf2f(h));
}

// ---------------------------------------------------------------------------
// MFMA GEMM, bf16x2 split, B staged in LDS, XCD-aware 1D grid.
// Block 128 thr = 2 waves; block tile 32 rows x 64 cols; wave tile 16x64.
// WB: 0 none, 1 split hi/lo, 2 single bf16. EPI: 0 none, 1 gelu, 2 +res.
// QPACK: q fp32 (pre-scaled) + kv bf16 [M][256]. Cf2: optional second fp32
// output (used to mirror h into d_out without ever reading d_out).
// ---------------------------------------------------------------------------
template <int K, int NC, int EPI, bool WF32, int WB, bool QPACK, bool ASPLIT>
__global__ __launch_bounds__(128, 4) void mgemm2_k(
    const unsigned short* __restrict__ Ahi, const unsigned short* __restrict__ Alo,
    const unsigned short* __restrict__ Bthi, const unsigned short* __restrict__ Btlo,
    const float* __restrict__ bias, const float* __restrict__ res,
    float* __restrict__ Cf, float* __restrict__ Cf2,
    unsigned short* __restrict__ Chi, unsigned short* __restrict__ Clo,
    int M)
{
  constexpr int NCY = NC / 64;
  __shared__ unsigned short BsH[64][72];
  __shared__ unsigned short BsL[64][72];
  const int bid = blockIdx.x;
  const int g   = bid & 7;
  const int s   = bid >> 3;
  const int lr  = s / NCY;
  const int cc  = s - lr * NCY;
  const int rb  = g * RPB8_ + lr;
  if (rb * 32 >= M) return;

  const int tid  = threadIdx.x;
  const int wave = tid >> 6;
  const int lane = tid & 63;
  const int l15  = lane & 15;
  const int kq8  = (lane >> 4) * 8;
  const int r0   = rb * 32 + wave * 16;
  const int c0   = cc * 64;

  const int brow  = tid & 63;
  const int bhalf = tid >> 6;

  f32x4 acc[4];
#pragma unroll
  for (int ct = 0; ct < 4; ++ct) acc[ct] = (f32x4){0.f, 0.f, 0.f, 0.f};

  const unsigned short* arh = Ahi + (size_t)(r0 + l15) * K + kq8;
  const unsigned short* arl = ASPLIT ? (Alo + (size_t)(r0 + l15) * K + kq8) : Ahi;
  const unsigned short* bh_src = Bthi + (size_t)(c0 + brow) * K + bhalf * 32;
  const unsigned short* bl_src = Btlo + (size_t)(c0 + brow) * K + bhalf * 32;

  constexpr int NCH = K / 64;
#pragma unroll
  for (int c = 0; c < NCH; ++c) {
    const int ck = c * 64;
#pragma unroll
    for (int st = 0; st < 4; ++st) {
      *(bf16x8*)&BsH[brow][bhalf * 32 + st * 8] = *(const bf16x8*)(bh_src + ck + st * 8);
      *(bf16x8*)&BsL[brow][bhalf * 32 + st * 8] = *(const bf16x8*)(bl_src + ck + st * 8);
    }
    __syncthreads();
#pragma unroll
    for (int k0 = 0; k0 < 64; k0 += 32) {
      bf16x8 ah = *(const bf16x8*)(arh + ck + k0);
      bf16x8 al = ah;
      if (ASPLIT) al = *(const bf16x8*)(arl + ck + k0);
#pragma unroll
      for (int ct = 0; ct < 4; ++ct) {
        bf16x8 bh = *(const bf16x8*)&BsH[ct * 16 + l15][k0 + kq8];
        bf16x8 bl = *(const bf16x8*)&BsL[ct * 16 + l15][k0 + kq8];
        acc[ct] = __builtin_amdgcn_mfma_f32_16x16x32_bf16(ah, bh, acc[ct], 0, 0, 0);
        acc[ct] = __builtin_amdgcn_mfma_f32_16x16x32_bf16(ah, bl, acc[ct], 0, 0, 0);
        if (ASPLIT)
          acc[ct] = __builtin_amdgcn_mfma_f32_16x16x32_bf16(al, bh, acc[ct], 0, 0, 0);
      }
    }
    if (c + 1 < NCH) __syncthreads();
  }

  const int ccol  = lane & 15;
  const int crow0 = (lane >> 4) * 4;
#pragma unroll
  for (int ct = 0; ct < 4; ++ct) {
    int gc = c0 + ct * 16 + ccol;
    float bb = bias[gc];
#pragma unroll
    for (int r = 0; r < 4; ++r) {
      int gr = r0 + crow0 + r;
      if (gr >= M) continue;
      float o = acc[ct][r] + bb;
      if (EPI == 1) o = gelu_f(o);
      if (EPI == 2) o += res[(size_t)gr * NC + gc];
      if (QPACK) {
        if (c0 < 128) Cf[(size_t)gr * 128 + gc] = o * 0.17677669529663687f;
        else          Chi[(size_t)gr * 256 + gc - 128] = f2bf(o);
      } else {
        if (WF32) {
          Cf[(size_t)gr * NC + gc] = o;
          if (Cf2) Cf2[(size_t)gr * NC + gc] = o;
        }
        if (WB == 1) {
          unsigned short hh, ll;
          splitf(o, hh, ll);
          Chi[(size_t)gr * NC + gc] = hh;
          Clo[(size_t)gr * NC + gc] = ll;
        }
        if (WB == 2) Chi[(size_t)gr * NC + gc] = f2bf(o);
      }
    }
  }
}

// ---------------------------------------------------------------------------
// Fused O-projection (K=128, NC=128) + residual + LayerNorm.
// ---------------------------------------------------------------------------
__global__ __launch_bounds__(128, 4) void ogemm_ln_k(
    const unsigned short* __restrict__ Ahi, const unsigned short* __restrict__ Alo,
    const unsigned short* __restrict__ Bthi, const unsigned short* __restrict__ Btlo,
    const float* __restrict__ bias, const float* __restrict__ resid,
    const float* __restrict__ lnw, const float* __restrict__ lnb,
    float* __restrict__ lnF, unsigned short* __restrict__ lnHi,
    unsigned short* __restrict__ lnLo, int M)
{
  const int wave = threadIdx.x >> 6;
  const int lane = threadIdx.x & 63;
  const int l15  = lane & 15;
  const int kq8  = (lane >> 4) * 8;
  const int r0   = blockIdx.x * 32 + wave * 16;

  f32x4 acc[8];
#pragma unroll
  for (int ct = 0; ct < 8; ++ct) acc[ct] = (f32x4){0.f, 0.f, 0.f, 0.f};

  const unsigned short* arh = Ahi + (size_t)(r0 + l15) * 128 + kq8;
  const unsigned short* arl = Alo + (size_t)(r0 + l15) * 128 + kq8;
  const unsigned short* bth = Bthi + (size_t)l15 * 128 + kq8;
  const unsigned short* btl = Btlo + (size_t)l15 * 128 + kq8;

#pragma unroll
  for (int k0 = 0; k0 < 128; k0 += 32) {
    bf16x8 ah = *(const bf16x8*)(arh + k0);
    bf16x8 al = *(const bf16x8*)(arl + k0);
#pragma unroll
    for (int ct = 0; ct < 8; ++ct) {
      bf16x8 bh = *(const bf16x8*)(bth + ct * 16 * 128 + k0);
      bf16x8 bl = *(const bf16x8*)(btl + ct * 16 * 128 + k0);
      acc[ct] = __builtin_amdgcn_mfma_f32_16x16x32_bf16(ah, bh, acc[ct], 0, 0, 0);
      acc[ct] = __builtin_amdgcn_mfma_f32_16x16x32_bf16(ah, bl, acc[ct], 0, 0, 0);
      acc[ct] = __builtin_amdgcn_mfma_f32_16x16x32_bf16(al, bh, acc[ct], 0, 0, 0);
    }
  }

  const int ccol  = lane & 15;
  const int crow0 = (lane >> 4) * 4;

#pragma unroll
  for (int ct = 0; ct < 8; ++ct) {
    int gc = ct * 16 + ccol;
    float bb = bias[gc];
#pragma unroll
    for (int r = 0; r < 4; ++r) {
      int gr = r0 + crow0 + r;
      acc[ct][r] += bb + resid[(size_t)gr * 128 + gc];
    }
  }

  float mu[4];
#pragma unroll
  for (int r = 0; r < 4; ++r) {
    float s = 0.f;
#pragma unroll
    for (int ct = 0; ct < 8; ++ct) s += acc[ct][r];
    s += __shfl_xor(s, 1); s += __shfl_xor(s, 2);
    s += __shfl_xor(s, 4); s += __shfl_xor(s, 8);
    mu[r] = s * (1.f / 128.f);
  }
  float rstd[4];
#pragma unroll
  for (int r = 0; r < 4; ++r) {
    float s = 0.f;
#pragma unroll
    for (int ct = 0; ct < 8; ++ct) { float d = acc[ct][r] - mu[r]; s += d * d; }
    s += __shfl_xor(s, 1); s += __shfl_xor(s, 2);
    s += __shfl_xor(s, 4); s += __shfl_xor(s, 8);
    rstd[r] = rsqrtf(s * (1.f / 128.f) + 1e-5f);
  }

#pragma unroll
  for (int ct = 0; ct < 8; ++ct) {
    int gc = ct * 16 + ccol;
    float ww = lnw[gc], bb = lnb[gc];
#pragma unroll
    for (int r = 0; r < 4; ++r) {
      int gr = r0 + crow0 + r;
      if (gr >= M) continue;
      float o = (acc[ct][r] - mu[r]) * rstd[r] * ww + bb;
      lnF[(size_t)gr * 128 + gc] = o;
      unsigned short hh, ll;
      splitf(o, hh, ll);
      lnHi[(size_t)gr * 128 + gc] = hh;
      lnLo[(size_t)gr * 128 + gc] = ll;
    }
  }
}

// ---------------------------------------------------------------------------
// prep_k: ALL per-launch weight prep fused into one grid-stride kernel.
// ---------------------------------------------------------------------------
__global__ __launch_bounds__(256) void prep_k(
    const float* __restrict__ qw, const float* __restrict__ kw,
    const float* __restrict__ vw, const float* __restrict__ ow,
    const float* __restrict__ mw1, const float* __restrict__ mw2,
    const float* __restrict__ emb_w,
    const float* __restrict__ qb, const float* __restrict__ kb,
    const float* __restrict__ vb,
    const float* __restrict__ nf,
    unsigned short* __restrict__ wqkv_hi, unsigned short* __restrict__ wqkv_lo,
    unsigned short* __restrict__ wo_hi, unsigned short* __restrict__ wo_lo,
    unsigned short* __restrict__ w1_hi, unsigned short* __restrict__ w1_lo,
    unsigned short* __restrict__ w2_hi, unsigned short* __restrict__ w2_lo,
    unsigned short* __restrict__ we_hi, unsigned short* __restrict__ we_lo,
    float* __restrict__ qkvb,
    unsigned short* __restrict__ nf_hi, unsigned short* __restrict__ nf_lo,
    int* __restrict__ deg, int* __restrict__ cur, float* __restrict__ gsum)
{
  constexpr int T_qkv = 3 * L_ * 16384;
  constexpr int T_o   = T_qkv + L_ * 16384;
  constexpr int T_w1  = T_o + L_ * 65536;
  constexpr int T_w2  = T_w1 + L_ * 65536;
  constexpr int T_we  = T_w2 + 8192;
  constexpr int T_b   = T_we + L_ * 384;
  constexpr int T_nf  = T_b + N_ * 64;
  constexpr int T_z   = T_nf + 2 * N_ + 128;

  unsigned short hh, ll;
  for (int i = blockIdx.x * 256 + threadIdx.x; i < T_z; i += gridDim.x * 256) {
    if (i < T_qkv) {
      int which = i / (L_ * 16384);
      int r = i - which * (L_ * 16384);
      int l = r >> 14, rr = r & 16383;
      int k = rr >> 7, c = rr & 127;
      const float* src = (which == 0) ? qw : (which == 1) ? kw : vw;
      splitf(src[r], hh, ll);
      size_t op = (size_t)l * 49152 + (size_t)(which * 128 + c) * 128 + k;
      wqkv_hi[op] = hh; wqkv_lo[op] = ll;
    } else if (i < T_o) {
      int r = i - T_qkv;
      int l = r >> 14, rr = r & 16383;
      int k = rr >> 7, c = rr & 127;
      splitf(ow[r], hh, ll);
      size_t op = (size_t)l * 16384 + (size_t)c * 128 + k;
      wo_hi[op] = hh; wo_lo[op] = ll;
    } else if (i < T_w1) {
      int r = i - T_o;
      int l = r >> 16, rr = r & 65535;
      int k = rr >> 9, c = rr & 511;
      splitf(mw1[r], hh, ll);
      size_t op = (size_t)l * 65536 + (size_t)c * 128 + k;
      w1_hi[op] = hh; w1_lo[op] = ll;
    } else if (i < T_w2) {
      int r = i - T_w1;
      int l = r >> 16, rr = r & 65535;
      int k = rr >> 7, c = rr & 127;
      splitf(mw2[r], hh, ll);
      size_t op = (size_t)l * 65536 + (size_t)c * 512 + k;
      w2_hi[op] = hh; w2_lo[op] = ll;
    } else if (i < T_we) {
      int r = i - T_w2;
      int k = r >> 7, c = r & 127;
      splitf(emb_w[r], hh, ll);
      size_t op = (size_t)c * 64 + k;
      we_hi[op] = hh; we_lo[op] = ll;
    } else if (i < T_b) {
      int r = i - T_we;
      int l = r / 384, c = r - l * 384;
      float x = (c < 128) ? qb[l * 128 + c]
              : (c < 256) ? kb[l * 128 + c - 128]
                          : vb[l * 128 + c - 256];
      qkvb[r] = x;
    } else if (i < T_nf) {
      int r = i - T_b;
      splitf(nf[r], hh, ll);
      nf_hi[r] = hh; nf_lo[r] = ll;
    } else {
      int r = i - T_nf;
      if (r < N_) deg[r] = 0;
      else if (r < 2 * N_) cur[r - N_] = 0;
      else gsum[r - 2 * N_] = 0.f;
    }
  }
}

// ---------------------------------------------------------------------------
// CSR build
// ---------------------------------------------------------------------------
__global__ __launch_bounds__(256) void deg_k(const int* __restrict__ dst, int* __restrict__ deg, int E) {
  int e = blockIdx.x * blockDim.x + threadIdx.x;
  if (e < E) atomicAdd(&deg[dst[e]], 1);
}

__global__ __launch_bounds__(1024) void scan_k(const int* __restrict__ deg, int* __restrict__ offs, int n) {
  __shared__ int part[1024];
  int tid = threadIdx.x;
  const int chunk = (n + 1023) / 1024;
  int base = tid * chunk;
  int s = 0;
  for (int j = 0; j < chunk; ++j) { int idx = base + j; if (idx < n) s += deg[idx]; }
  part[tid] = s;
  __syncthreads();
  int own = s;
  for (int off = 1; off < 1024; off <<= 1) {
    int t = (tid >= off) ? part[tid - off] : 0;
    __syncthreads();
    part[tid] += t;
    __syncthreads();
  }
  int run = part[tid] - own;
  for (int j = 0; j < chunk; ++j) {
    int idx = base + j;
    if (idx <= n) offs[idx] = run;
    if (idx < n) run += deg[idx];
  }
}

__global__ __launch_bounds__(256) void fill_k(
    const int* __restrict__ src, const int* __restrict__ dst,
    const int* __restrict__ offs, int* __restrict__ cur,
    int* __restrict__ csrc, int* __restrict__ cdst, int E)
{
  int e = blockIdx.x * blockDim.x + threadIdx.x;
  if (e < E) {
    int d = dst[e];
    int p = atomicAdd(&cur[d], 1);
    int o = offs[d] + p;
    csrc[o] = src[e];
    cdst[o] = d;
  }
}

// ---------------------------------------------------------------------------
// Attention phase 1: edge-parallel scores. XCD-chunked block mapping so each
// XCD's q/dst slice (~1.25 MB) stays in its private L2. Grid = 5000 = 8*625.
// ---------------------------------------------------------------------------
__global__ __launch_bounds__(256) void scores_k(
    const float* __restrict__ q, const unsigned short* __restrict__ kvbf,
    const int* __restrict__ csrc, const int* __restrict__ cdst,
    float* __restrict__ sc)
{
  int nb = blockIdx.x;
  int bid = (nb & 7) * 625 + (nb >> 3);
  int t = bid * 256 + threadIdx.x;
  int lane = t & 63;
  int slot = (t >> 6) * 16 + (lane & 15);
  int h = lane >> 4;
  if (slot >= E_) return;
  int s = csrc[slot], d = cdst[slot];
  const unsigned short* kr = kvbf + (size_t)s * 256 + h * 32;
  const float* qr = q + (size_t)d * 128 + h * 32;
  float acc = 0.f;
#pragma unroll
  for (int i = 0; i < 4; ++i) {
    bf16x8 k8 = *(const bf16x8*)(kr + i * 8);
    float4 q0 = *(const float4*)(qr + i * 8);
    float4 q1 = *(const float4*)(qr + i * 8 + 4);
    acc = fmaf(q0.x, bf2f((unsigned short)k8[0]), acc);
    acc = fmaf(q0.y, bf2f((unsigned short)k8[1]), acc);
    acc = fmaf(q0.z, bf2f((unsigned short)k8[2]), acc);
    acc = fmaf(q0.w, bf2f((unsigned short)k8[3]), acc);
    acc = fmaf(q1.x, bf2f((unsigned short)k8[4]), acc);
    acc = fmaf(q1.y, bf2f((unsigned short)k8[5]), acc);
    acc = fmaf(q1.z, bf2f((unsigned short)k8[6]), acc);
    acc = fmaf(q1.w, bf2f((unsigned short)k8[7]), acc);
  }
  sc[(size_t)h * E_ + slot] = acc;
}

// ---------------------------------------------------------------------------
// Attention phase 2: single-pass softmax (no max subtraction — scores are
// O(10) for LN-normalized inputs, exp stays in fp32 range; mathematically
// identical result) + weighted V aggregation. XCD-chunked (grid 10000=8*1250).
// ---------------------------------------------------------------------------
__global__ __launch_bounds__(256) void agg_k(
    const float* __restrict__ sc, const unsigned short* __restrict__ kvbf,
    const int* __restrict__ offs, const int* __restrict__ csrc,
    unsigned short* __restrict__ aggHi, unsigned short* __restrict__ aggLo, int M)
{
  int nb = blockIdx.x;
  int bid = (nb & 7) * 1250 + (nb >> 3);
  int gw = bid * 4 + (int)(threadIdx.x >> 6);
  int lane = threadIdx.x & 63;
  int n = gw >> 1, hp = gw & 1;
  if (n >= M) return;
  int col = hp * 64 + lane;
  const int e0 = offs[n], e1 = offs[n + 1];
  if (e0 == e1) {
    aggHi[(size_t)n * 128 + col] = 0;
    aggLo[(size_t)n * 128 + col] = 0;
    return;
  }
  const int h2 = hp * 2 + (lane >> 5);
  const int l31 = lane & 31;
  const float* scp = sc + (size_t)h2 * E_;

  float denp = 0.f, acc = 0.f;
  for (int c = e0; c < e1; c += 32) {
    int e = c + l31;
    bool val = e < e1;
    float w = val ? __expf(scp[e]) : 0.f;
    int sv = val ? csrc[e] : 0;
    denp += w;
    int cnt = e1 - c; if (cnt > 32) cnt = 32;
    int cnt4 = (cnt + 3) & ~3;
    for (int i = 0; i < cnt4; i += 4) {
      float wb0 = __shfl(w, (lane & 32) + i + 0);
      float wb1 = __shfl(w, (lane & 32) + i + 1);
      float wb2 = __shfl(w, (lane & 32) + i + 2);
      float wb3 = __shfl(w, (lane & 32) + i + 3);
      int sb0 = __shfl(sv, i + 0);
      int sb1 = __shfl(sv, i + 1);
      int sb2 = __shfl(sv, i + 2);
      int sb3 = __shfl(sv, i + 3);
      float v0 = bf2f(kvbf[(size_t)sb0 * 256 + 128 + col]);
      float v1 = bf2f(kvbf[(size_t)sb1 * 256 + 128 + col]);
      float v2 = bf2f(kvbf[(size_t)sb2 * 256 + 128 + col]);
      float v3 = bf2f(kvbf[(size_t)sb3 * 256 + 128 + col]);
      acc = fmaf(wb0, v0, acc);
      acc = fmaf(wb1, v1, acc);
      acc = fmaf(wb2, v2, acc);
      acc = fmaf(wb3, v3, acc);
    }
  }
  float den = denp;
  den += __shfl_xor(den, 1);
  den += __shfl_xor(den, 2);
  den += __shfl_xor(den, 4);
  den += __shfl_xor(den, 8);
  den += __shfl_xor(den, 16);
  float o = acc / den;
  unsigned short hh, ll;
  splitf(o, hh, ll);
  aggHi[(size_t)n * 128 + col] = hh;
  aggLo[(size_t)n * 128 + col] = ll;
}

// ---------------------------------------------------------------------------
// Column sum (mean pool) — reads WORKSPACE h (cached), never d_out.
// ---------------------------------------------------------------------------
__global__ __launch_bounds__(256) void colsum_k(const float* __restrict__ h, float* __restrict__ gsum, int M) {
  __shared__ float sd[8][128];
  int tid = threadIdx.x;
  int cq = (tid & 31) * 4;
  int rg = tid >> 5;
  float4 s = make_float4(0.f, 0.f, 0.f, 0.f);
  for (int r = blockIdx.x * 8 + rg; r < M; r += gridDim.x * 8) {
    float4 v = *(const float4*)(h + (size_t)r * 128 + cq);
    s.x += v.x; s.y += v.y; s.z += v.z; s.w += v.w;
  }
  *(float4*)&sd[rg][cq] = s;
  __syncthreads();
  if (tid < 32) {
    int c4 = tid * 4;
    float4 a = *(float4*)&sd[0][c4];
#pragma unroll
    for (int g2 = 1; g2 < 8; ++g2) {
      float4 b = *(float4*)&sd[g2][c4];
      a.x += b.x; a.y += b.y; a.z += b.z; a.w += b.w;
    }
    atomicAdd(&gsum[c4 + 0], a.x);
    atomicAdd(&gsum[c4 + 1], a.y);
    atomicAdd(&gsum[c4 + 2], a.z);
    atomicAdd(&gsum[c4 + 3], a.w);
  }
}

__global__ __launch_bounds__(256) void classifier_k(
    const float* __restrict__ gsum,
    const float* __restrict__ lnw, const float* __restrict__ lnb,
    const float* __restrict__ cw1, const float* __restrict__ cb1,
    const float* __restrict__ cw2, const float* __restrict__ cb2,
    const float* __restrict__ clsw, const float* __restrict__ clsb,
    float* __restrict__ out_logits, float* __restrict__ out_g, float invN)
{
  __shared__ float z[128], h1[256], z2[128];
  int tid = threadIdx.x;
  if (tid < 128) {
    float gg = gsum[tid] * invN;
    out_g[tid] = gg;
    z[tid] = gg;
  }
  __syncthreads();
  if (tid < 64) {
    float a = z[tid], b2 = z[tid + 64];
    float s = a + b2;
#pragma unroll
    for (int d = 1; d < 64; d <<= 1) s += __shfl_xor(s, d);
    float mean = s * (1.f / 128.f);
    float ea = a - mean, eb = b2 - mean;
    float sq = ea * ea + eb * eb;
#pragma unroll
    for (int d = 1; d < 64; d <<= 1) sq += __shfl_xor(sq, d);
    float rstd = rsqrtf(sq * (1.f / 128.f) + 1e-5f);
    z[tid]      = ea * rstd * lnw[tid] + lnb[tid];
    z[tid + 64] = eb * rstd * lnw[tid + 64] + lnb[tid + 64];
  }
  __syncthreads();
  {
    float acc = cb1[tid];
    for (int f = 0; f < 128; ++f) acc = fmaf(z[f], cw1[f * 256 + tid], acc);
    h1[tid] = gelu_f(acc);
  }
  __syncthreads();
  if (tid < 128) {
    float acc = cb2[tid];
    for (int f = 0; f < 256; ++f) acc = fmaf(h1[f], cw2[f * 128 + tid], acc);
    z2[tid] = acc;
  }
  __syncthreads();
  if (tid < 10) {
    float acc = clsb[tid];
    for (int f = 0; f < 128; ++f) acc = fmaf(z2[f], clsw[f * 10 + tid], acc);
    out_logits[tid] = acc;
  }
}

// ---------------------------------------------------------------------------
extern "C" void kernel_launch(void* const* d_in, const int* in_sizes, int n_in,
                              void* d_out, int out_size, void* d_ws, size_t ws_size,
                              hipStream_t stream) {
  const float* node_features = (const float*)d_in[0];
  const int*   ei            = (const int*)d_in[1];
  const float* emb_w = (const float*)d_in[3];
  const float* emb_b = (const float*)d_in[4];
  const float* qw  = (const float*)d_in[7];  const float* qb  = (const float*)d_in[8];
  const float* kw  = (const float*)d_in[9];  const float* kb  = (const float*)d_in[10];
  const float* vw  = (const float*)d_in[11]; const float* vb  = (const float*)d_in[12];
  const float* ow  = (const float*)d_in[13]; const float* ob  = (const float*)d_in[14];
  const float* lnw = (const float*)d_in[15]; const float* lnb = (const float*)d_in[16];
  const float* mw1 = (const float*)d_in[17]; const float* mb1 = (const float*)d_in[18];
  const float* mw2 = (const float*)d_in[19]; const float* mb2 = (const float*)d_in[20];
  const float* clnw = (const float*)d_in[21]; const float* clnb = (const float*)d_in[22];
  const float* cw1 = (const float*)d_in[23]; const float* cb1 = (const float*)d_in[24];
  const float* cw2 = (const float*)d_in[25]; const float* cb2 = (const float*)d_in[26];
  const float* clsw = (const float*)d_in[27]; const float* clsb = (const float*)d_in[28];

  float* out = (float*)d_out;
  float* out_h = out + 10;
  float* out_g = out + 10 + (size_t)N_ * DIM_;

  char* p = (char*)d_ws;
  auto alloc = [&](size_t bytes) { char* r = p; p += (bytes + 255) & ~(size_t)255; return r; };

  float* h    = (float*)alloc((size_t)MP_ * 128 * 4);
  float* qbuf = (float*)alloc((size_t)MP_ * 128 * 4);
  float* tmp  = (float*)alloc((size_t)MP_ * 128 * 4);
  unsigned short* kvbf = (unsigned short*)alloc((size_t)MP_ * 256 * 2);
  float* scb  = (float*)alloc((size_t)4 * E_ * 4);
  unsigned short* h_hi = (unsigned short*)alloc((size_t)MP_ * 128 * 2);
  unsigned short* h_lo = (unsigned short*)alloc((size_t)MP_ * 128 * 2);
  unsigned short* sp_hi = (unsigned short*)alloc((size_t)MP_ * 128 * 2);
  unsigned short* sp_lo = (unsigned short*)alloc((size_t)MP_ * 128 * 2);
  unsigned short* ln_hi = (unsigned short*)alloc((size_t)MP_ * 128 * 2);
  unsigned short* ln_lo = (unsigned short*)alloc((size_t)MP_ * 128 * 2);
  unsigned short* hid   = (unsigned short*)alloc((size_t)MP_ * 512 * 2);
  unsigned short* wqkv_hi = (unsigned short*)alloc((size_t)L_ * 384 * 128 * 2);
  unsigned short* wqkv_lo = (unsigned short*)alloc((size_t)L_ * 384 * 128 * 2);
  unsigned short* wo_hi   = (unsigned short*)alloc((size_t)L_ * 128 * 128 * 2);
  unsigned short* wo_lo   = (unsigned short*)alloc((size_t)L_ * 128 * 128 * 2);
  unsigned short* w1_hi   = (unsigned short*)alloc((size_t)L_ * 512 * 128 * 2);
  unsigned short* w1_lo   = (unsigned short*)alloc((size_t)L_ * 512 * 128 * 2);
  unsigned short* w2_hi   = (unsigned short*)alloc((size_t)L_ * 128 * 512 * 2);
  unsigned short* w2_lo   = (unsigned short*)alloc((size_t)L_ * 128 * 512 * 2);
  unsigned short* we_hi   = (unsigned short*)alloc((size_t)128 * 64 * 2);
  unsigned short* we_lo   = (unsigned short*)alloc((size_t)128 * 64 * 2);
  float* qkvb = (float*)alloc((size_t)L_ * 384 * 4);
  float* gsum = (float*)alloc(128 * 4);
  int* deg  = (int*)alloc((size_t)N_ * 4);
  int* cur  = (int*)alloc((size_t)N_ * 4);
  int* offs = (int*)alloc(((size_t)N_ + 1) * 4);
  int* csrc = (int*)alloc((size_t)E_ * 4);
  int* cdst = (int*)alloc((size_t)E_ * 4);
  unsigned short* nf_hi = hid;
  unsigned short* nf_lo = hid + (size_t)MP_ * 64;

  const int* esrc = ei;
  const int* edst = ei + E_;

  prep_k<<<2048, 256, 0, stream>>>(
      qw, kw, vw, ow, mw1, mw2, emb_w, qb, kb, vb, node_features,
      wqkv_hi, wqkv_lo, wo_hi, wo_lo, w1_hi, w1_lo, w2_hi, w2_lo,
      we_hi, we_lo, qkvb, nf_hi, nf_lo, deg, cur, gsum);

  deg_k<<<(E_ + 255) / 256, 256, 0, stream>>>(edst, deg, E_);
  scan_k<<<1, 1024, 0, stream>>>(deg, offs, N_);
  fill_k<<<(E_ + 255) / 256, 256, 0, stream>>>(esrc, edst, offs, cur, csrc, cdst, E_);

  auto sgrid = [](int ncy) { return dim3(8 * RPB8_ * ncy); };

  // embed
  mgemm2_k<64, 128, 0, true, 1, false, true><<<sgrid(2), 128, 0, stream>>>(
      nf_hi, nf_lo, we_hi, we_lo, emb_b, nullptr, h, nullptr, h_hi, h_lo, N_);

  for (int i = 0; i < L_; ++i) {
    const unsigned short* wq_h = wqkv_hi + (size_t)i * 384 * 128;
    const unsigned short* wq_l = wqkv_lo + (size_t)i * 384 * 128;

    mgemm2_k<128, 384, 0, false, 0, true, true><<<sgrid(6), 128, 0, stream>>>(
        h_hi, h_lo, wq_h, wq_l, qkvb + (size_t)i * 384, nullptr,
        qbuf, nullptr, kvbf, nullptr, N_);

    scores_k<<<5000, 256, 0, stream>>>(qbuf, kvbf, csrc, cdst, scb);
    agg_k<<<10000, 256, 0, stream>>>(scb, kvbf, offs, csrc, sp_hi, sp_lo, N_);

    ogemm_ln_k<<<dim3((N_ + 31) / 32), 128, 0, stream>>>(
        sp_hi, sp_lo, wo_hi + (size_t)i * 128 * 128, wo_lo + (size_t)i * 128 * 128,
        ob + (size_t)i * 128, h, lnw + (size_t)i * 128, lnb + (size_t)i * 128,
        tmp, ln_hi, ln_lo, N_);

    mgemm2_k<128, 512, 1, false, 2, false, true><<<sgrid(8), 128, 0, stream>>>(
        ln_hi, ln_lo, w1_hi + (size_t)i * 512 * 128, w1_lo + (size_t)i * 512 * 128,
        mb1 + (size_t)i * 512, nullptr, nullptr, nullptr, hid, nullptr, N_);

    if (i == L_ - 1) {
      // write h (workspace, for colsum) AND mirror to out_h (d_out, never read)
      mgemm2_k<512, 128, 2, true, 0, false, false><<<sgrid(2), 128, 0, stream>>>(
          hid, nullptr, w2_hi + (size_t)i * 128 * 512, w2_lo + (size_t)i * 128 * 512,
          mb2 + (size_t)i * 128, tmp, h, out_h, nullptr, nullptr, N_);
    } else {
      mgemm2_k<512, 128, 2, true, 1, false, false><<<sgrid(2), 128, 0, stream>>>(
          hid, nullptr, w2_hi + (size_t)i * 128 * 512, w2_lo + (size_t)i * 128 * 512,
          mb2 + (size_t)i * 128, tmp, h, nullptr, h_hi, h_lo, N_);
    }
  }

  colsum_k<<<512, 256, 0, stream>>>(h, gsum, N_);
  classifier_k<<<1, 256, 0, stream>>>(gsum, clnw, clnb, cw1, cb1, cw2, cb2, clsw, clsb,
                                      out, out_g, 1.0f / (float)N_);
}

// Round 9
// 793.613 us; speedup vs baseline: 1.5970x; 1.0282x over previous
//
#include <hip/hip_runtime.h>
#include <hip/hip_bf16.h>
#include <cstdint>
#include <cstddef>

constexpr int N_  = 20000;
constexpr int E_  = 320000;
constexpr int DIM_ = 128;
constexpr int L_  = 4;
constexpr int MP_ = 20032;   // M padded
constexpr int RPB8_ = 79;    // ceil(625 row-blocks / 8 XCDs)

typedef short bf16x8 __attribute__((ext_vector_type(8)));
typedef float f32x4  __attribute__((ext_vector_type(4)));

__device__ __forceinline__ float gelu_f(float x) {
  float x3 = x * x * x;
  float z = 0.7978845608028654f * (x + 0.044715f * x3);
  float t = 1.f - 2.f / (__expf(2.f * z) + 1.f);   // tanh via fast exp
  return 0.5f * x * (1.0f + t);
}

__device__ __forceinline__ unsigned short f2bf(float x) {  // RNE
  unsigned u = __float_as_uint(x);
  u += 0x7fff + ((u >> 16) & 1);
  return (unsigned short)(u >> 16);
}
__device__ __forceinline__ float bf2f(unsigned short s) {
  return __uint_as_float((unsigned)s << 16);
}
__device__ __forceinline__ void splitf(float x, unsigned short& h, unsigned short& l) {
  h = f2bf(x);
  l = f2bf(x - bf2f(h));
}

// ---------------------------------------------------------------------------
// MFMA GEMM, bf16x2 split, B staged in LDS, XCD-aware 1D grid.
// Block 128 thr = 2 waves; block tile 32 rows x 64 cols; wave tile 16x64.
// WB: 0 none, 1 split hi/lo, 2 single bf16. EPI: 0 none, 1 gelu, 2 +res.
// QPACK: q fp32 (pre-scaled) + kv bf16 [M][256]. Cf2: optional mirror output.
// ---------------------------------------------------------------------------
template <int K, int NC, int EPI, bool WF32, int WB, bool QPACK, bool ASPLIT>
__global__ __launch_bounds__(128, 4) void mgemm2_k(
    const unsigned short* __restrict__ Ahi, const unsigned short* __restrict__ Alo,
    const unsigned short* __restrict__ Bthi, const unsigned short* __restrict__ Btlo,
    const float* __restrict__ bias, const float* __restrict__ res,
    float* __restrict__ Cf, float* __restrict__ Cf2,
    unsigned short* __restrict__ Chi, unsigned short* __restrict__ Clo,
    int M)
{
  constexpr int NCY = NC / 64;
  __shared__ unsigned short BsH[64][72];
  __shared__ unsigned short BsL[64][72];
  const int bid = blockIdx.x;
  const int g   = bid & 7;
  const int s   = bid >> 3;
  const int lr  = s / NCY;
  const int cc  = s - lr * NCY;
  const int rb  = g * RPB8_ + lr;
  if (rb * 32 >= M) return;

  const int tid  = threadIdx.x;
  const int wave = tid >> 6;
  const int lane = tid & 63;
  const int l15  = lane & 15;
  const int kq8  = (lane >> 4) * 8;
  const int r0   = rb * 32 + wave * 16;
  const int c0   = cc * 64;

  const int brow  = tid & 63;
  const int bhalf = tid >> 6;

  f32x4 acc[4];
#pragma unroll
  for (int ct = 0; ct < 4; ++ct) acc[ct] = (f32x4){0.f, 0.f, 0.f, 0.f};

  const unsigned short* arh = Ahi + (size_t)(r0 + l15) * K + kq8;
  const unsigned short* arl = ASPLIT ? (Alo + (size_t)(r0 + l15) * K + kq8) : Ahi;
  const unsigned short* bh_src = Bthi + (size_t)(c0 + brow) * K + bhalf * 32;
  const unsigned short* bl_src = Btlo + (size_t)(c0 + brow) * K + bhalf * 32;

  constexpr int NCH = K / 64;
#pragma unroll
  for (int c = 0; c < NCH; ++c) {
    const int ck = c * 64;
#pragma unroll
    for (int st = 0; st < 4; ++st) {
      *(bf16x8*)&BsH[brow][bhalf * 32 + st * 8] = *(const bf16x8*)(bh_src + ck + st * 8);
      *(bf16x8*)&BsL[brow][bhalf * 32 + st * 8] = *(const bf16x8*)(bl_src + ck + st * 8);
    }
    __syncthreads();
#pragma unroll
    for (int k0 = 0; k0 < 64; k0 += 32) {
      bf16x8 ah = *(const bf16x8*)(arh + ck + k0);
      bf16x8 al = ah;
      if (ASPLIT) al = *(const bf16x8*)(arl + ck + k0);
#pragma unroll
      for (int ct = 0; ct < 4; ++ct) {
        bf16x8 bh = *(const bf16x8*)&BsH[ct * 16 + l15][k0 + kq8];
        bf16x8 bl = *(const bf16x8*)&BsL[ct * 16 + l15][k0 + kq8];
        acc[ct] = __builtin_amdgcn_mfma_f32_16x16x32_bf16(ah, bh, acc[ct], 0, 0, 0);
        acc[ct] = __builtin_amdgcn_mfma_f32_16x16x32_bf16(ah, bl, acc[ct], 0, 0, 0);
        if (ASPLIT)
          acc[ct] = __builtin_amdgcn_mfma_f32_16x16x32_bf16(al, bh, acc[ct], 0, 0, 0);
      }
    }
    if (c + 1 < NCH) __syncthreads();
  }

  const int ccol  = lane & 15;
  const int crow0 = (lane >> 4) * 4;
#pragma unroll
  for (int ct = 0; ct < 4; ++ct) {
    int gc = c0 + ct * 16 + ccol;
    float bb = bias[gc];
#pragma unroll
    for (int r = 0; r < 4; ++r) {
      int gr = r0 + crow0 + r;
      if (gr >= M) continue;
      float o = acc[ct][r] + bb;
      if (EPI == 1) o = gelu_f(o);
      if (EPI == 2) o += res[(size_t)gr * NC + gc];
      if (QPACK) {
        if (c0 < 128) Cf[(size_t)gr * 128 + gc] = o * 0.17677669529663687f;
        else          Chi[(size_t)gr * 256 + gc - 128] = f2bf(o);
      } else {
        if (WF32) {
          Cf[(size_t)gr * NC + gc] = o;
          if (Cf2) Cf2[(size_t)gr * NC + gc] = o;
        }
        if (WB == 1) {
          unsigned short hh, ll;
          splitf(o, hh, ll);
          Chi[(size_t)gr * NC + gc] = hh;
          Clo[(size_t)gr * NC + gc] = ll;
        }
        if (WB == 2) Chi[(size_t)gr * NC + gc] = f2bf(o);
      }
    }
  }
}

// ---------------------------------------------------------------------------
// Fused O-projection (K=128, NC=128) + residual + LayerNorm.
// A is a SINGLE bf16 plane (attention output) -> 2 MFMAs per tile.
// ---------------------------------------------------------------------------
__global__ __launch_bounds__(128, 4) void ogemm_ln_k(
    const unsigned short* __restrict__ A,
    const unsigned short* __restrict__ Bthi, const unsigned short* __restrict__ Btlo,
    const float* __restrict__ bias, const float* __restrict__ resid,
    const float* __restrict__ lnw, const float* __restrict__ lnb,
    float* __restrict__ lnF, unsigned short* __restrict__ lnHi,
    unsigned short* __restrict__ lnLo, int M)
{
  const int wave = threadIdx.x >> 6;
  const int lane = threadIdx.x & 63;
  const int l15  = lane & 15;
  const int kq8  = (lane >> 4) * 8;
  const int r0   = blockIdx.x * 32 + wave * 16;

  f32x4 acc[8];
#pragma unroll
  for (int ct = 0; ct < 8; ++ct) acc[ct] = (f32x4){0.f, 0.f, 0.f, 0.f};

  const unsigned short* ar  = A + (size_t)(r0 + l15) * 128 + kq8;
  const unsigned short* bth = Bthi + (size_t)l15 * 128 + kq8;
  const unsigned short* btl = Btlo + (size_t)l15 * 128 + kq8;

#pragma unroll
  for (int k0 = 0; k0 < 128; k0 += 32) {
    bf16x8 ah = *(const bf16x8*)(ar + k0);
#pragma unroll
    for (int ct = 0; ct < 8; ++ct) {
      bf16x8 bh = *(const bf16x8*)(bth + ct * 16 * 128 + k0);
      bf16x8 bl = *(const bf16x8*)(btl + ct * 16 * 128 + k0);
      acc[ct] = __builtin_amdgcn_mfma_f32_16x16x32_bf16(ah, bh, acc[ct], 0, 0, 0);
      acc[ct] = __builtin_amdgcn_mfma_f32_16x16x32_bf16(ah, bl, acc[ct], 0, 0, 0);
    }
  }

  const int ccol  = lane & 15;
  const int crow0 = (lane >> 4) * 4;

#pragma unroll
  for (int ct = 0; ct < 8; ++ct) {
    int gc = ct * 16 + ccol;
    float bb = bias[gc];
#pragma unroll
    for (int r = 0; r < 4; ++r) {
      int gr = r0 + crow0 + r;
      acc[ct][r] += bb + resid[(size_t)gr * 128 + gc];
    }
  }

  float mu[4];
#pragma unroll
  for (int r = 0; r < 4; ++r) {
    float s = 0.f;
#pragma unroll
    for (int ct = 0; ct < 8; ++ct) s += acc[ct][r];
    s += __shfl_xor(s, 1); s += __shfl_xor(s, 2);
    s += __shfl_xor(s, 4); s += __shfl_xor(s, 8);
    mu[r] = s * (1.f / 128.f);
  }
  float rstd[4];
#pragma unroll
  for (int r = 0; r < 4; ++r) {
    float s = 0.f;
#pragma unroll
    for (int ct = 0; ct < 8; ++ct) { float d = acc[ct][r] - mu[r]; s += d * d; }
    s += __shfl_xor(s, 1); s += __shfl_xor(s, 2);
    s += __shfl_xor(s, 4); s += __shfl_xor(s, 8);
    rstd[r] = rsqrtf(s * (1.f / 128.f) + 1e-5f);
  }

#pragma unroll
  for (int ct = 0; ct < 8; ++ct) {
    int gc = ct * 16 + ccol;
    float ww = lnw[gc], bb = lnb[gc];
#pragma unroll
    for (int r = 0; r < 4; ++r) {
      int gr = r0 + crow0 + r;
      if (gr >= M) continue;
      float o = (acc[ct][r] - mu[r]) * rstd[r] * ww + bb;
      lnF[(size_t)gr * 128 + gc] = o;
      unsigned short hh, ll;
      splitf(o, hh, ll);
      lnHi[(size_t)gr * 128 + gc] = hh;
      lnLo[(size_t)gr * 128 + gc] = ll;
    }
  }
}

// ---------------------------------------------------------------------------
// prep_k: ALL per-launch weight prep fused into one grid-stride kernel.
// ---------------------------------------------------------------------------
__global__ __launch_bounds__(256) void prep_k(
    const float* __restrict__ qw, const float* __restrict__ kw,
    const float* __restrict__ vw, const float* __restrict__ ow,
    const float* __restrict__ mw1, const float* __restrict__ mw2,
    const float* __restrict__ emb_w,
    const float* __restrict__ qb, const float* __restrict__ kb,
    const float* __restrict__ vb,
    const float* __restrict__ nf,
    unsigned short* __restrict__ wqkv_hi, unsigned short* __restrict__ wqkv_lo,
    unsigned short* __restrict__ wo_hi, unsigned short* __restrict__ wo_lo,
    unsigned short* __restrict__ w1_hi, unsigned short* __restrict__ w1_lo,
    unsigned short* __restrict__ w2_hi, unsigned short* __restrict__ w2_lo,
    unsigned short* __restrict__ we_hi, unsigned short* __restrict__ we_lo,
    float* __restrict__ qkvb,
    unsigned short* __restrict__ nf_hi, unsigned short* __restrict__ nf_lo,
    int* __restrict__ deg, int* __restrict__ cur)
{
  constexpr int T_qkv = 3 * L_ * 16384;
  constexpr int T_o   = T_qkv + L_ * 16384;
  constexpr int T_w1  = T_o + L_ * 65536;
  constexpr int T_w2  = T_w1 + L_ * 65536;
  constexpr int T_we  = T_w2 + 8192;
  constexpr int T_b   = T_we + L_ * 384;
  constexpr int T_nf  = T_b + N_ * 64;
  constexpr int T_z   = T_nf + 2 * N_;

  unsigned short hh, ll;
  for (int i = blockIdx.x * 256 + threadIdx.x; i < T_z; i += gridDim.x * 256) {
    if (i < T_qkv) {
      int which = i / (L_ * 16384);
      int r = i - which * (L_ * 16384);
      int l = r >> 14, rr = r & 16383;
      int k = rr >> 7, c = rr & 127;
      const float* src = (which == 0) ? qw : (which == 1) ? kw : vw;
      splitf(src[r], hh, ll);
      size_t op = (size_t)l * 49152 + (size_t)(which * 128 + c) * 128 + k;
      wqkv_hi[op] = hh; wqkv_lo[op] = ll;
    } else if (i < T_o) {
      int r = i - T_qkv;
      int l = r >> 14, rr = r & 16383;
      int k = rr >> 7, c = rr & 127;
      splitf(ow[r], hh, ll);
      size_t op = (size_t)l * 16384 + (size_t)c * 128 + k;
      wo_hi[op] = hh; wo_lo[op] = ll;
    } else if (i < T_w1) {
      int r = i - T_o;
      int l = r >> 16, rr = r & 65535;
      int k = rr >> 9, c = rr & 511;
      splitf(mw1[r], hh, ll);
      size_t op = (size_t)l * 65536 + (size_t)c * 128 + k;
      w1_hi[op] = hh; w1_lo[op] = ll;
    } else if (i < T_w2) {
      int r = i - T_w1;
      int l = r >> 16, rr = r & 65535;
      int k = rr >> 7, c = rr & 127;
      splitf(mw2[r], hh, ll);
      size_t op = (size_t)l * 65536 + (size_t)c * 512 + k;
      w2_hi[op] = hh; w2_lo[op] = ll;
    } else if (i < T_we) {
      int r = i - T_w2;
      int k = r >> 7, c = r & 127;
      splitf(emb_w[r], hh, ll);
      size_t op = (size_t)c * 64 + k;
      we_hi[op] = hh; we_lo[op] = ll;
    } else if (i < T_b) {
      int r = i - T_we;
      int l = r / 384, c = r - l * 384;
      float x = (c < 128) ? qb[l * 128 + c]
              : (c < 256) ? kb[l * 128 + c - 128]
                          : vb[l * 128 + c - 256];
      qkvb[r] = x;
    } else if (i < T_nf) {
      int r = i - T_b;
      splitf(nf[r], hh, ll);
      nf_hi[r] = hh; nf_lo[r] = ll;
    } else {
      int r = i - T_nf;
      if (r < N_) deg[r] = 0;
      else cur[r - N_] = 0;
    }
  }
}

// ---------------------------------------------------------------------------
// CSR build
// ---------------------------------------------------------------------------
__global__ __launch_bounds__(256) void deg_k(const int* __restrict__ dst, int* __restrict__ deg, int E) {
  int e = blockIdx.x * blockDim.x + threadIdx.x;
  if (e < E) atomicAdd(&deg[dst[e]], 1);
}

__global__ __launch_bounds__(1024) void scan_k(const int* __restrict__ deg, int* __restrict__ offs, int n) {
  __shared__ int part[1024];
  int tid = threadIdx.x;
  const int chunk = (n + 1023) / 1024;
  int base = tid * chunk;
  int s = 0;
  for (int j = 0; j < chunk; ++j) { int idx = base + j; if (idx < n) s += deg[idx]; }
  part[tid] = s;
  __syncthreads();
  int own = s;
  for (int off = 1; off < 1024; off <<= 1) {
    int t = (tid >= off) ? part[tid - off] : 0;
    __syncthreads();
    part[tid] += t;
    __syncthreads();
  }
  int run = part[tid] - own;
  for (int j = 0; j < chunk; ++j) {
    int idx = base + j;
    if (idx <= n) offs[idx] = run;
    if (idx < n) run += deg[idx];
  }
}

__global__ __launch_bounds__(256) void fill_k(
    const int* __restrict__ src, const int* __restrict__ dst,
    const int* __restrict__ offs, int* __restrict__ cur,
    int* __restrict__ csrc, int* __restrict__ cdst, int E)
{
  int e = blockIdx.x * blockDim.x + threadIdx.x;
  if (e < E) {
    int d = dst[e];
    int p = atomicAdd(&cur[d], 1);
    int o = offs[d] + p;
    csrc[o] = src[e];
    cdst[o] = d;
  }
}

// ---------------------------------------------------------------------------
// Attention phase 1: edge-parallel scores, XCD-chunked (grid 5000 = 8*625)
// ---------------------------------------------------------------------------
__global__ __launch_bounds__(256) void scores_k(
    const float* __restrict__ q, const unsigned short* __restrict__ kvbf,
    const int* __restrict__ csrc, const int* __restrict__ cdst,
    float* __restrict__ sc)
{
  int nb = blockIdx.x;
  int bid = (nb & 7) * 625 + (nb >> 3);
  int t = bid * 256 + threadIdx.x;
  int lane = t & 63;
  int slot = (t >> 6) * 16 + (lane & 15);
  int h = lane >> 4;
  if (slot >= E_) return;
  int s = csrc[slot], d = cdst[slot];
  const unsigned short* kr = kvbf + (size_t)s * 256 + h * 32;
  const float* qr = q + (size_t)d * 128 + h * 32;
  float acc = 0.f;
#pragma unroll
  for (int i = 0; i < 4; ++i) {
    bf16x8 k8 = *(const bf16x8*)(kr + i * 8);
    float4 q0 = *(const float4*)(qr + i * 8);
    float4 q1 = *(const float4*)(qr + i * 8 + 4);
    acc = fmaf(q0.x, bf2f((unsigned short)k8[0]), acc);
    acc = fmaf(q0.y, bf2f((unsigned short)k8[1]), acc);
    acc = fmaf(q0.z, bf2f((unsigned short)k8[2]), acc);
    acc = fmaf(q0.w, bf2f((unsigned short)k8[3]), acc);
    acc = fmaf(q1.x, bf2f((unsigned short)k8[4]), acc);
    acc = fmaf(q1.y, bf2f((unsigned short)k8[5]), acc);
    acc = fmaf(q1.z, bf2f((unsigned short)k8[6]), acc);
    acc = fmaf(q1.w, bf2f((unsigned short)k8[7]), acc);
  }
  sc[(size_t)h * E_ + slot] = acc;
}

// ---------------------------------------------------------------------------
// Attention phase 2: single-pass softmax + V aggregation -> single bf16 plane
// ---------------------------------------------------------------------------
__global__ __launch_bounds__(256) void agg_k(
    const float* __restrict__ sc, const unsigned short* __restrict__ kvbf,
    const int* __restrict__ offs, const int* __restrict__ csrc,
    unsigned short* __restrict__ agg, int M)
{
  int nb = blockIdx.x;
  int bid = (nb & 7) * 1250 + (nb >> 3);
  int gw = bid * 4 + (int)(threadIdx.x >> 6);
  int lane = threadIdx.x & 63;
  int n = gw >> 1, hp = gw & 1;
  if (n >= M) return;
  int col = hp * 64 + lane;
  const int e0 = offs[n], e1 = offs[n + 1];
  if (e0 == e1) {
    agg[(size_t)n * 128 + col] = 0;
    return;
  }
  const int h2 = hp * 2 + (lane >> 5);
  const int l31 = lane & 31;
  const float* scp = sc + (size_t)h2 * E_;

  float denp = 0.f, acc = 0.f;
  for (int c = e0; c < e1; c += 32) {
    int e = c + l31;
    bool val = e < e1;
    float w = val ? __expf(scp[e]) : 0.f;
    int sv = val ? csrc[e] : 0;
    denp += w;
    int cnt = e1 - c; if (cnt > 32) cnt = 32;
    int cnt4 = (cnt + 3) & ~3;
    for (int i = 0; i < cnt4; i += 4) {
      float wb0 = __shfl(w, (lane & 32) + i + 0);
      float wb1 = __shfl(w, (lane & 32) + i + 1);
      float wb2 = __shfl(w, (lane & 32) + i + 2);
      float wb3 = __shfl(w, (lane & 32) + i + 3);
      int sb0 = __shfl(sv, i + 0);
      int sb1 = __shfl(sv, i + 1);
      int sb2 = __shfl(sv, i + 2);
      int sb3 = __shfl(sv, i + 3);
      float v0 = bf2f(kvbf[(size_t)sb0 * 256 + 128 + col]);
      float v1 = bf2f(kvbf[(size_t)sb1 * 256 + 128 + col]);
      float v2 = bf2f(kvbf[(size_t)sb2 * 256 + 128 + col]);
      float v3 = bf2f(kvbf[(size_t)sb3 * 256 + 128 + col]);
      acc = fmaf(wb0, v0, acc);
      acc = fmaf(wb1, v1, acc);
      acc = fmaf(wb2, v2, acc);
      acc = fmaf(wb3, v3, acc);
    }
  }
  float den = denp;
  den += __shfl_xor(den, 1);
  den += __shfl_xor(den, 2);
  den += __shfl_xor(den, 4);
  den += __shfl_xor(den, 8);
  den += __shfl_xor(den, 16);
  agg[(size_t)n * 128 + col] = f2bf(acc / den);
}

// ---------------------------------------------------------------------------
// Column sum, two-stage, NO atomics (experiment: is 52 us the atomics?)
// Stage 1: 256 blocks -> partial[256][128] (plain stores).
// Stage 2: 1 block reduces partials -> gsum.
// ---------------------------------------------------------------------------
__global__ __launch_bounds__(256) void colsum1_k(
    const float* __restrict__ h, float* __restrict__ partial, int M)
{
  __shared__ float sd[8][128];
  int tid = threadIdx.x;
  int cq = (tid & 31) * 4;
  int rg = tid >> 5;
  float4 s = make_float4(0.f, 0.f, 0.f, 0.f);
  for (int r = blockIdx.x * 8 + rg; r < M; r += gridDim.x * 8) {
    float4 v = *(const float4*)(h + (size_t)r * 128 + cq);
    s.x += v.x; s.y += v.y; s.z += v.z; s.w += v.w;
  }
  *(float4*)&sd[rg][cq] = s;
  __syncthreads();
  if (tid < 32) {
    int c4 = tid * 4;
    float4 a = *(float4*)&sd[0][c4];
#pragma unroll
    for (int g2 = 1; g2 < 8; ++g2) {
      float4 b = *(float4*)&sd[g2][c4];
      a.x += b.x; a.y += b.y; a.z += b.z; a.w += b.w;
    }
    *(float4*)&partial[(size_t)blockIdx.x * 128 + c4] = a;
  }
}

__global__ __launch_bounds__(256) void colsum2_k(
    const float* __restrict__ partial, float* __restrict__ gsum, int P)
{
  __shared__ float sd[256];
  int tid = threadIdx.x;
  int col = tid & 127, half = tid >> 7;
  float s = 0.f;
  for (int i = half; i < P; i += 2) s += partial[(size_t)i * 128 + col];
  sd[tid] = s;
  __syncthreads();
  if (tid < 128) gsum[tid] = sd[tid] + sd[tid + 128];
}

__global__ __launch_bounds__(256) void classifier_k(
    const float* __restrict__ gsum,
    const float* __restrict__ lnw, const float* __restrict__ lnb,
    const float* __restrict__ cw1, const float* __restrict__ cb1,
    const float* __restrict__ cw2, const float* __restrict__ cb2,
    const float* __restrict__ clsw, const float* __restrict__ clsb,
    float* __restrict__ out_logits, float* __restrict__ out_g, float invN)
{
  __shared__ float z[128], h1[256], z2[128];
  int tid = threadIdx.x;
  if (tid < 128) {
    float gg = gsum[tid] * invN;
    out_g[tid] = gg;
    z[tid] = gg;
  }
  __syncthreads();
  if (tid < 64) {
    float a = z[tid], b2 = z[tid + 64];
    float s = a + b2;
#pragma unroll
    for (int d = 1; d < 64; d <<= 1) s += __shfl_xor(s, d);
    float mean = s * (1.f / 128.f);
    float ea = a - mean, eb = b2 - mean;
    float sq = ea * ea + eb * eb;
#pragma unroll
    for (int d = 1; d < 64; d <<= 1) sq += __shfl_xor(sq, d);
    float rstd = rsqrtf(sq * (1.f / 128.f) + 1e-5f);
    z[tid]      = ea * rstd * lnw[tid] + lnb[tid];
    z[tid + 64] = eb * rstd * lnw[tid + 64] + lnb[tid + 64];
  }
  __syncthreads();
  {
    float acc = cb1[tid];
    for (int f = 0; f < 128; ++f) acc = fmaf(z[f], cw1[f * 256 + tid], acc);
    h1[tid] = gelu_f(acc);
  }
  __syncthreads();
  if (tid < 128) {
    float acc = cb2[tid];
    for (int f = 0; f < 256; ++f) acc = fmaf(h1[f], cw2[f * 128 + tid], acc);
    z2[tid] = acc;
  }
  __syncthreads();
  if (tid < 10) {
    float acc = clsb[tid];
    for (int f = 0; f < 128; ++f) acc = fmaf(z2[f], clsw[f * 10 + tid], acc);
    out_logits[tid] = acc;
  }
}

// ---------------------------------------------------------------------------
extern "C" void kernel_launch(void* const* d_in, const int* in_sizes, int n_in,
                              void* d_out, int out_size, void* d_ws, size_t ws_size,
                              hipStream_t stream) {
  const float* node_features = (const float*)d_in[0];
  const int*   ei            = (const int*)d_in[1];
  const float* emb_w = (const float*)d_in[3];
  const float* emb_b = (const float*)d_in[4];
  const float* qw  = (const float*)d_in[7];  const float* qb  = (const float*)d_in[8];
  const float* kw  = (const float*)d_in[9];  const float* kb  = (const float*)d_in[10];
  const float* vw  = (const float*)d_in[11]; const float* vb  = (const float*)d_in[12];
  const float* ow  = (const float*)d_in[13]; const float* ob  = (const float*)d_in[14];
  const float* lnw = (const float*)d_in[15]; const float* lnb = (const float*)d_in[16];
  const float* mw1 = (const float*)d_in[17]; const float* mb1 = (const float*)d_in[18];
  const float* mw2 = (const float*)d_in[19]; const float* mb2 = (const float*)d_in[20];
  const float* clnw = (const float*)d_in[21]; const float* clnb = (const float*)d_in[22];
  const float* cw1 = (const float*)d_in[23]; const float* cb1 = (const float*)d_in[24];
  const float* cw2 = (const float*)d_in[25]; const float* cb2 = (const float*)d_in[26];
  const float* clsw = (const float*)d_in[27]; const float* clsb = (const float*)d_in[28];

  float* out = (float*)d_out;
  float* out_h = out + 10;
  float* out_g = out + 10 + (size_t)N_ * DIM_;

  char* p = (char*)d_ws;
  auto alloc = [&](size_t bytes) { char* r = p; p += (bytes + 255) & ~(size_t)255; return r; };

  float* h    = (float*)alloc((size_t)MP_ * 128 * 4);
  float* qbuf = (float*)alloc((size_t)MP_ * 128 * 4);
  float* tmp  = (float*)alloc((size_t)MP_ * 128 * 4);
  unsigned short* kvbf = (unsigned short*)alloc((size_t)MP_ * 256 * 2);
  float* scb  = (float*)alloc((size_t)4 * E_ * 4);
  unsigned short* h_hi = (unsigned short*)alloc((size_t)MP_ * 128 * 2);
  unsigned short* h_lo = (unsigned short*)alloc((size_t)MP_ * 128 * 2);
  unsigned short* sp   = (unsigned short*)alloc((size_t)MP_ * 128 * 2);   // agg bf16
  unsigned short* ln_hi = (unsigned short*)alloc((size_t)MP_ * 128 * 2);
  unsigned short* ln_lo = (unsigned short*)alloc((size_t)MP_ * 128 * 2);
  unsigned short* hid   = (unsigned short*)alloc((size_t)MP_ * 512 * 2);
  unsigned short* wqkv_hi = (unsigned short*)alloc((size_t)L_ * 384 * 128 * 2);
  unsigned short* wqkv_lo = (unsigned short*)alloc((size_t)L_ * 384 * 128 * 2);
  unsigned short* wo_hi   = (unsigned short*)alloc((size_t)L_ * 128 * 128 * 2);
  unsigned short* wo_lo   = (unsigned short*)alloc((size_t)L_ * 128 * 128 * 2);
  unsigned short* w1_hi   = (unsigned short*)alloc((size_t)L_ * 512 * 128 * 2);
  unsigned short* w1_lo   = (unsigned short*)alloc((size_t)L_ * 512 * 128 * 2);
  unsigned short* w2_hi   = (unsigned short*)alloc((size_t)L_ * 128 * 512 * 2);
  unsigned short* w2_lo   = (unsigned short*)alloc((size_t)L_ * 128 * 512 * 2);
  unsigned short* we_hi   = (unsigned short*)alloc((size_t)128 * 64 * 2);
  unsigned short* we_lo   = (unsigned short*)alloc((size_t)128 * 64 * 2);
  float* qkvb = (float*)alloc((size_t)L_ * 384 * 4);
  float* gsum = (float*)alloc(128 * 4);
  float* cpart = (float*)alloc((size_t)256 * 128 * 4);
  int* deg  = (int*)alloc((size_t)N_ * 4);
  int* cur  = (int*)alloc((size_t)N_ * 4);
  int* offs = (int*)alloc(((size_t)N_ + 1) * 4);
  int* csrc = (int*)alloc((size_t)E_ * 4);
  int* cdst = (int*)alloc((size_t)E_ * 4);
  unsigned short* nf_hi = hid;
  unsigned short* nf_lo = hid + (size_t)MP_ * 64;

  const int* esrc = ei;
  const int* edst = ei + E_;

  prep_k<<<2048, 256, 0, stream>>>(
      qw, kw, vw, ow, mw1, mw2, emb_w, qb, kb, vb, node_features,
      wqkv_hi, wqkv_lo, wo_hi, wo_lo, w1_hi, w1_lo, w2_hi, w2_lo,
      we_hi, we_lo, qkvb, nf_hi, nf_lo, deg, cur);

  deg_k<<<(E_ + 255) / 256, 256, 0, stream>>>(edst, deg, E_);
  scan_k<<<1, 1024, 0, stream>>>(deg, offs, N_);
  fill_k<<<(E_ + 255) / 256, 256, 0, stream>>>(esrc, edst, offs, cur, csrc, cdst, E_);

  auto sgrid = [](int ncy) { return dim3(8 * RPB8_ * ncy); };

  // embed
  mgemm2_k<64, 128, 0, true, 1, false, true><<<sgrid(2), 128, 0, stream>>>(
      nf_hi, nf_lo, we_hi, we_lo, emb_b, nullptr, h, nullptr, h_hi, h_lo, N_);

  for (int i = 0; i < L_; ++i) {
    const unsigned short* wq_h = wqkv_hi + (size_t)i * 384 * 128;
    const unsigned short* wq_l = wqkv_lo + (size_t)i * 384 * 128;

    mgemm2_k<128, 384, 0, false, 0, true, true><<<sgrid(6), 128, 0, stream>>>(
        h_hi, h_lo, wq_h, wq_l, qkvb + (size_t)i * 384, nullptr,
        qbuf, nullptr, kvbf, nullptr, N_);

    scores_k<<<5000, 256, 0, stream>>>(qbuf, kvbf, csrc, cdst, scb);
    agg_k<<<10000, 256, 0, stream>>>(scb, kvbf, offs, csrc, sp, N_);

    ogemm_ln_k<<<dim3((N_ + 31) / 32), 128, 0, stream>>>(
        sp, wo_hi + (size_t)i * 128 * 128, wo_lo + (size_t)i * 128 * 128,
        ob + (size_t)i * 128, h, lnw + (size_t)i * 128, lnb + (size_t)i * 128,
        tmp, ln_hi, ln_lo, N_);

    mgemm2_k<128, 512, 1, false, 2, false, true><<<sgrid(8), 128, 0, stream>>>(
        ln_hi, ln_lo, w1_hi + (size_t)i * 512 * 128, w1_lo + (size_t)i * 512 * 128,
        mb1 + (size_t)i * 512, nullptr, nullptr, nullptr, hid, nullptr, N_);

    if (i == L_ - 1) {
      mgemm2_k<512, 128, 2, true, 0, false, false><<<sgrid(2), 128, 0, stream>>>(
          hid, nullptr, w2_hi + (size_t)i * 128 * 512, w2_lo + (size_t)i * 128 * 512,
          mb2 + (size_t)i * 128, tmp, h, out_h, nullptr, nullptr, N_);
    } else {
      mgemm2_k<512, 128, 2, true, 1, false, false><<<sgrid(2), 128, 0, stream>>>(
          hid, nullptr, w2_hi + (size_t)i * 128 * 512, w2_lo + (size_t)i * 128 * 512,
          mb2 + (size_t)i * 128, tmp, h, nullptr, h_hi, h_lo, N_);
    }
  }

  colsum1_k<<<256, 256, 0, stream>>>(h, cpart, N_);
  colsum2_k<<<1, 256, 0, stream>>>(cpart, gsum, 256);
  classifier_k<<<1, 256, 0, stream>>>(gsum, clnw, clnb, cw1, cb1, cw2, cb2, clsw, clsb,
                                      out, out_g, 1.0f / (float)N_);
}

// Round 10
// 722.613 us; speedup vs baseline: 1.7539x; 1.0983x over previous
//
#include <hip/hip_runtime.h>
#include <hip/hip_bf16.h>
#include <cstdint>
#include <cstddef>

constexpr int N_  = 20000;
constexpr int E_  = 320000;
constexpr int DIM_ = 128;
constexpr int L_  = 4;
constexpr int MP_ = 20032;   // M padded

typedef short bf16x8 __attribute__((ext_vector_type(8)));
typedef float f32x4  __attribute__((ext_vector_type(4)));

__device__ __forceinline__ float gelu_f(float x) {
  float x3 = x * x * x;
  float z = 0.7978845608028654f * (x + 0.044715f * x3);
  float t = 1.f - 2.f / (__expf(2.f * z) + 1.f);   // tanh via fast exp
  return 0.5f * x * (1.0f + t);
}

__device__ __forceinline__ unsigned short f2bf(float x) {  // RNE
  unsigned u = __float_as_uint(x);
  u += 0x7fff + ((u >> 16) & 1);
  return (unsigned short)(u >> 16);
}
__device__ __forceinline__ float bf2f(unsigned short s) {
  return __uint_as_float((unsigned)s << 16);
}
__device__ __forceinline__ void splitf(float x, unsigned short& h, unsigned short& l) {
  h = f2bf(x);
  l = f2bf(x - bf2f(h));
}

// ---------------------------------------------------------------------------
// MFMA GEMM v3: bf16x2-split weights, FRAGMENT-MAJOR LDS staging.
// LDS layout per 64-k chunk: 8 fragments (4 ct x 2 k0) of [64 lanes x 8 elems]
//   -> MFMA read addr = frag*512 + lane*8 elems (contiguous, conflict-free).
//   staging: thread (brow=tid&63, bhalf=tid>>6) holds B^T row c0+brow,
//   elems bhalf*32+st*8 -> frag (brow>>4)*2+bhalf, slot st*16+(brow&15).
// RW = row-frags per wave (1 -> 32-row blocks, 2 -> 64-row blocks).
// Block 128 thr = 2 waves. XCD-aware 1D grid (rb = xcd*RPB + s/NCY).
// WB: 0 none, 1 split hi/lo, 2 single bf16. EPI: 0 none, 1 gelu, 2 +res.
// QPACK: q fp32 (pre-scaled) + kv bf16 [M][256]. Cf2: optional mirror.
// ---------------------------------------------------------------------------
template <int K, int NC, int EPI, bool WF32, int WB, bool QPACK, bool ASPLIT, int RW>
__global__ __launch_bounds__(128, 4) void mgemm3_k(
    const unsigned short* __restrict__ Ahi, const unsigned short* __restrict__ Alo,
    const unsigned short* __restrict__ Bthi, const unsigned short* __restrict__ Btlo,
    const float* __restrict__ bias, const float* __restrict__ res,
    float* __restrict__ Cf, float* __restrict__ Cf2,
    unsigned short* __restrict__ Chi, unsigned short* __restrict__ Clo,
    int M)
{
  constexpr int NCY = NC / 64;
  constexpr int BR  = RW * 32;                 // rows per block
  constexpr int RPB = (RW == 2) ? 40 : 79;     // ceil(ceil(20000/BR)/8)
  __shared__ unsigned short BsH[8 * 512];
  __shared__ unsigned short BsL[8 * 512];

  const int bid = blockIdx.x;
  const int g   = bid & 7;
  const int s   = bid >> 3;
  const int lr  = s / NCY;
  const int cc  = s - lr * NCY;
  const int rb  = g * RPB + lr;
  if (rb * BR >= M) return;

  const int tid  = threadIdx.x;
  const int wave = tid >> 6;
  const int lane = tid & 63;
  const int l15  = lane & 15;
  const int kq8  = (lane >> 4) * 8;
  const int r0   = rb * BR + wave * (RW * 16);
  const int c0   = cc * 64;

  const int brow  = tid & 63;
  const int bhalf = tid >> 6;
  const int sbase = ((brow >> 4) * 2 + bhalf) * 512 + (brow & 15) * 8;
  const unsigned short* bh_src = Bthi + (size_t)(c0 + brow) * K + bhalf * 32;
  const unsigned short* bl_src = Btlo + (size_t)(c0 + brow) * K + bhalf * 32;

  f32x4 acc[RW][4];
#pragma unroll
  for (int rw = 0; rw < RW; ++rw)
#pragma unroll
    for (int ct = 0; ct < 4; ++ct) acc[rw][ct] = (f32x4){0.f, 0.f, 0.f, 0.f};

  const unsigned short* arh[2];
  const unsigned short* arl[2];
  arh[0] = Ahi + (size_t)(r0 + l15) * K + kq8;
  arh[1] = (RW == 2) ? (Ahi + (size_t)(r0 + 16 + l15) * K + kq8) : arh[0];
  arl[0] = ASPLIT ? (Alo + (size_t)(r0 + l15) * K + kq8) : arh[0];
  arl[1] = (ASPLIT && RW == 2) ? (Alo + (size_t)(r0 + 16 + l15) * K + kq8) : arl[0];

  constexpr int NCH = K / 64;
#pragma unroll
  for (int c = 0; c < NCH; ++c) {
    const int ck = c * 64;
#pragma unroll
    for (int st = 0; st < 4; ++st) {
      *(bf16x8*)&BsH[sbase + st * 128] = *(const bf16x8*)(bh_src + ck + st * 8);
      *(bf16x8*)&BsL[sbase + st * 128] = *(const bf16x8*)(bl_src + ck + st * 8);
    }
    __syncthreads();
#pragma unroll
    for (int k0 = 0; k0 < 2; ++k0) {
      bf16x8 ah[RW], al[RW];
#pragma unroll
      for (int rw = 0; rw < RW; ++rw) {
        ah[rw] = *(const bf16x8*)(arh[rw] + ck + k0 * 32);
        if (ASPLIT) al[rw] = *(const bf16x8*)(arl[rw] + ck + k0 * 32);
      }
#pragma unroll
      for (int ct = 0; ct < 4; ++ct) {
        const int fb = (ct * 2 + k0) * 512 + lane * 8;
        bf16x8 bh = *(const bf16x8*)&BsH[fb];
        bf16x8 bl = *(const bf16x8*)&BsL[fb];
#pragma unroll
        for (int rw = 0; rw < RW; ++rw) {
          acc[rw][ct] = __builtin_amdgcn_mfma_f32_16x16x32_bf16(ah[rw], bh, acc[rw][ct], 0, 0, 0);
          acc[rw][ct] = __builtin_amdgcn_mfma_f32_16x16x32_bf16(ah[rw], bl, acc[rw][ct], 0, 0, 0);
          if (ASPLIT)
            acc[rw][ct] = __builtin_amdgcn_mfma_f32_16x16x32_bf16(al[rw], bh, acc[rw][ct], 0, 0, 0);
        }
      }
    }
    if (c + 1 < NCH) __syncthreads();
  }

  const int ccol  = lane & 15;
  const int crow0 = (lane >> 4) * 4;
#pragma unroll
  for (int rw = 0; rw < RW; ++rw) {
#pragma unroll
    for (int ct = 0; ct < 4; ++ct) {
      int gc = c0 + ct * 16 + ccol;
      float bb = bias[gc];
#pragma unroll
      for (int r = 0; r < 4; ++r) {
        int gr = r0 + rw * 16 + crow0 + r;
        if (gr >= M) continue;
        float o = acc[rw][ct][r] + bb;
        if (EPI == 1) o = gelu_f(o);
        if (EPI == 2) o += res[(size_t)gr * NC + gc];
        if (QPACK) {
          if (c0 < 128) Cf[(size_t)gr * 128 + gc] = o * 0.17677669529663687f;
          else          Chi[(size_t)gr * 256 + gc - 128] = f2bf(o);
        } else {
          if (WF32) {
            Cf[(size_t)gr * NC + gc] = o;
            if (Cf2) Cf2[(size_t)gr * NC + gc] = o;
          }
          if (WB == 1) {
            unsigned short hh, ll;
            splitf(o, hh, ll);
            Chi[(size_t)gr * NC + gc] = hh;
            Clo[(size_t)gr * NC + gc] = ll;
          }
          if (WB == 2) Chi[(size_t)gr * NC + gc] = f2bf(o);
        }
      }
    }
  }
}

// ---------------------------------------------------------------------------
// Fused O-projection (K=128, NC=128) + residual + LayerNorm.
// A single bf16 plane; outputs LN fp32 + LN single bf16 plane.
// ---------------------------------------------------------------------------
__global__ __launch_bounds__(128, 4) void ogemm_ln_k(
    const unsigned short* __restrict__ A,
    const unsigned short* __restrict__ Bthi, const unsigned short* __restrict__ Btlo,
    const float* __restrict__ bias, const float* __restrict__ resid,
    const float* __restrict__ lnw, const float* __restrict__ lnb,
    float* __restrict__ lnF, unsigned short* __restrict__ lnB, int M)
{
  const int wave = threadIdx.x >> 6;
  const int lane = threadIdx.x & 63;
  const int l15  = lane & 15;
  const int kq8  = (lane >> 4) * 8;
  const int r0   = blockIdx.x * 32 + wave * 16;

  f32x4 acc[8];
#pragma unroll
  for (int ct = 0; ct < 8; ++ct) acc[ct] = (f32x4){0.f, 0.f, 0.f, 0.f};

  const unsigned short* ar  = A + (size_t)(r0 + l15) * 128 + kq8;
  const unsigned short* bth = Bthi + (size_t)l15 * 128 + kq8;
  const unsigned short* btl = Btlo + (size_t)l15 * 128 + kq8;

#pragma unroll
  for (int k0 = 0; k0 < 128; k0 += 32) {
    bf16x8 ah = *(const bf16x8*)(ar + k0);
#pragma unroll
    for (int ct = 0; ct < 8; ++ct) {
      bf16x8 bh = *(const bf16x8*)(bth + ct * 16 * 128 + k0);
      bf16x8 bl = *(const bf16x8*)(btl + ct * 16 * 128 + k0);
      acc[ct] = __builtin_amdgcn_mfma_f32_16x16x32_bf16(ah, bh, acc[ct], 0, 0, 0);
      acc[ct] = __builtin_amdgcn_mfma_f32_16x16x32_bf16(ah, bl, acc[ct], 0, 0, 0);
    }
  }

  const int ccol  = lane & 15;
  const int crow0 = (lane >> 4) * 4;

#pragma unroll
  for (int ct = 0; ct < 8; ++ct) {
    int gc = ct * 16 + ccol;
    float bb = bias[gc];
#pragma unroll
    for (int r = 0; r < 4; ++r) {
      int gr = r0 + crow0 + r;
      acc[ct][r] += bb + resid[(size_t)gr * 128 + gc];
    }
  }

  float mu[4];
#pragma unroll
  for (int r = 0; r < 4; ++r) {
    float s = 0.f;
#pragma unroll
    for (int ct = 0; ct < 8; ++ct) s += acc[ct][r];
    s += __shfl_xor(s, 1); s += __shfl_xor(s, 2);
    s += __shfl_xor(s, 4); s += __shfl_xor(s, 8);
    mu[r] = s * (1.f / 128.f);
  }
  float rstd[4];
#pragma unroll
  for (int r = 0; r < 4; ++r) {
    float s = 0.f;
#pragma unroll
    for (int ct = 0; ct < 8; ++ct) { float d = acc[ct][r] - mu[r]; s += d * d; }
    s += __shfl_xor(s, 1); s += __shfl_xor(s, 2);
    s += __shfl_xor(s, 4); s += __shfl_xor(s, 8);
    rstd[r] = rsqrtf(s * (1.f / 128.f) + 1e-5f);
  }

#pragma unroll
  for (int ct = 0; ct < 8; ++ct) {
    int gc = ct * 16 + ccol;
    float ww = lnw[gc], bb = lnb[gc];
#pragma unroll
    for (int r = 0; r < 4; ++r) {
      int gr = r0 + crow0 + r;
      if (gr >= M) continue;
      float o = (acc[ct][r] - mu[r]) * rstd[r] * ww + bb;
      lnF[(size_t)gr * 128 + gc] = o;
      lnB[(size_t)gr * 128 + gc] = f2bf(o);
    }
  }
}

// ---------------------------------------------------------------------------
// prep_k: ALL per-launch weight prep fused into one grid-stride kernel.
// ---------------------------------------------------------------------------
__global__ __launch_bounds__(256) void prep_k(
    const float* __restrict__ qw, const float* __restrict__ kw,
    const float* __restrict__ vw, const float* __restrict__ ow,
    const float* __restrict__ mw1, const float* __restrict__ mw2,
    const float* __restrict__ emb_w,
    const float* __restrict__ qb, const float* __restrict__ kb,
    const float* __restrict__ vb,
    const float* __restrict__ nf,
    unsigned short* __restrict__ wqkv_hi, unsigned short* __restrict__ wqkv_lo,
    unsigned short* __restrict__ wo_hi, unsigned short* __restrict__ wo_lo,
    unsigned short* __restrict__ w1_hi, unsigned short* __restrict__ w1_lo,
    unsigned short* __restrict__ w2_hi, unsigned short* __restrict__ w2_lo,
    unsigned short* __restrict__ we_hi, unsigned short* __restrict__ we_lo,
    float* __restrict__ qkvb,
    unsigned short* __restrict__ nf_hi, unsigned short* __restrict__ nf_lo,
    int* __restrict__ deg, int* __restrict__ cur)
{
  constexpr int T_qkv = 3 * L_ * 16384;
  constexpr int T_o   = T_qkv + L_ * 16384;
  constexpr int T_w1  = T_o + L_ * 65536;
  constexpr int T_w2  = T_w1 + L_ * 65536;
  constexpr int T_we  = T_w2 + 8192;
  constexpr int T_b   = T_we + L_ * 384;
  constexpr int T_nf  = T_b + N_ * 64;
  constexpr int T_z   = T_nf + 2 * N_;

  unsigned short hh, ll;
  for (int i = blockIdx.x * 256 + threadIdx.x; i < T_z; i += gridDim.x * 256) {
    if (i < T_qkv) {
      int which = i / (L_ * 16384);
      int r = i - which * (L_ * 16384);
      int l = r >> 14, rr = r & 16383;
      int k = rr >> 7, c = rr & 127;
      const float* src = (which == 0) ? qw : (which == 1) ? kw : vw;
      splitf(src[r], hh, ll);
      size_t op = (size_t)l * 49152 + (size_t)(which * 128 + c) * 128 + k;
      wqkv_hi[op] = hh; wqkv_lo[op] = ll;
    } else if (i < T_o) {
      int r = i - T_qkv;
      int l = r >> 14, rr = r & 16383;
      int k = rr >> 7, c = rr & 127;
      splitf(ow[r], hh, ll);
      size_t op = (size_t)l * 16384 + (size_t)c * 128 + k;
      wo_hi[op] = hh; wo_lo[op] = ll;
    } else if (i < T_w1) {
      int r = i - T_o;
      int l = r >> 16, rr = r & 65535;
      int k = rr >> 9, c = rr & 511;
      splitf(mw1[r], hh, ll);
      size_t op = (size_t)l * 65536 + (size_t)c * 128 + k;
      w1_hi[op] = hh; w1_lo[op] = ll;
    } else if (i < T_w2) {
      int r = i - T_w1;
      int l = r >> 16, rr = r & 65535;
      int k = rr >> 7, c = rr & 127;
      splitf(mw2[r], hh, ll);
      size_t op = (size_t)l * 65536 + (size_t)c * 512 + k;
      w2_hi[op] = hh; w2_lo[op] = ll;
    } else if (i < T_we) {
      int r = i - T_w2;
      int k = r >> 7, c = r & 127;
      splitf(emb_w[r], hh, ll);
      size_t op = (size_t)c * 64 + k;
      we_hi[op] = hh; we_lo[op] = ll;
    } else if (i < T_b) {
      int r = i - T_we;
      int l = r / 384, c = r - l * 384;
      float x = (c < 128) ? qb[l * 128 + c]
              : (c < 256) ? kb[l * 128 + c - 128]
                          : vb[l * 128 + c - 256];
      qkvb[r] = x;
    } else if (i < T_nf) {
      int r = i - T_b;
      splitf(nf[r], hh, ll);
      nf_hi[r] = hh; nf_lo[r] = ll;
    } else {
      int r = i - T_nf;
      if (r < N_) deg[r] = 0;
      else cur[r - N_] = 0;
    }
  }
}

// ---------------------------------------------------------------------------
// CSR build
// ---------------------------------------------------------------------------
__global__ __launch_bounds__(256) void deg_k(const int* __restrict__ dst, int* __restrict__ deg, int E) {
  int e = blockIdx.x * blockDim.x + threadIdx.x;
  if (e < E) atomicAdd(&deg[dst[e]], 1);
}

__global__ __launch_bounds__(1024) void scan_k(const int* __restrict__ deg, int* __restrict__ offs, int n) {
  __shared__ int part[1024];
  int tid = threadIdx.x;
  const int chunk = (n + 1023) / 1024;
  int base = tid * chunk;
  int s = 0;
  for (int j = 0; j < chunk; ++j) { int idx = base + j; if (idx < n) s += deg[idx]; }
  part[tid] = s;
  __syncthreads();
  int own = s;
  for (int off = 1; off < 1024; off <<= 1) {
    int t = (tid >= off) ? part[tid - off] : 0;
    __syncthreads();
    part[tid] += t;
    __syncthreads();
  }
  int run = part[tid] - own;
  for (int j = 0; j < chunk; ++j) {
    int idx = base + j;
    if (idx <= n) offs[idx] = run;
    if (idx < n) run += deg[idx];
  }
}

__global__ __launch_bounds__(256) void fill_k(
    const int* __restrict__ src, const int* __restrict__ dst,
    const int* __restrict__ offs, int* __restrict__ cur,
    int* __restrict__ csrc, int* __restrict__ cdst, int E)
{
  int e = blockIdx.x * blockDim.x + threadIdx.x;
  if (e < E) {
    int d = dst[e];
    int p = atomicAdd(&cur[d], 1);
    int o = offs[d] + p;
    csrc[o] = src[e];
    cdst[o] = d;
  }
}

// ---------------------------------------------------------------------------
// Attention phase 1: edge-parallel scores, XCD-chunked (grid 5000 = 8*625)
// ---------------------------------------------------------------------------
__global__ __launch_bounds__(256) void scores_k(
    const float* __restrict__ q, const unsigned short* __restrict__ kvbf,
    const int* __restrict__ csrc, const int* __restrict__ cdst,
    float* __restrict__ sc)
{
  int nb = blockIdx.x;
  int bid = (nb & 7) * 625 + (nb >> 3);
  int t = bid * 256 + threadIdx.x;
  int lane = t & 63;
  int slot = (t >> 6) * 16 + (lane & 15);
  int h = lane >> 4;
  if (slot >= E_) return;
  int s = csrc[slot], d = cdst[slot];
  const unsigned short* kr = kvbf + (size_t)s * 256 + h * 32;
  const float* qr = q + (size_t)d * 128 + h * 32;
  float acc = 0.f;
#pragma unroll
  for (int i = 0; i < 4; ++i) {
    bf16x8 k8 = *(const bf16x8*)(kr + i * 8);
    float4 q0 = *(const float4*)(qr + i * 8);
    float4 q1 = *(const float4*)(qr + i * 8 + 4);
    acc = fmaf(q0.x, bf2f((unsigned short)k8[0]), acc);
    acc = fmaf(q0.y, bf2f((unsigned short)k8[1]), acc);
    acc = fmaf(q0.z, bf2f((unsigned short)k8[2]), acc);
    acc = fmaf(q0.w, bf2f((unsigned short)k8[3]), acc);
    acc = fmaf(q1.x, bf2f((unsigned short)k8[4]), acc);
    acc = fmaf(q1.y, bf2f((unsigned short)k8[5]), acc);
    acc = fmaf(q1.z, bf2f((unsigned short)k8[6]), acc);
    acc = fmaf(q1.w, bf2f((unsigned short)k8[7]), acc);
  }
  sc[(size_t)h * E_ + slot] = acc;
}

// ---------------------------------------------------------------------------
// Attention phase 2: single-pass softmax + V aggregation -> single bf16 plane
// ---------------------------------------------------------------------------
__global__ __launch_bounds__(256) void agg_k(
    const float* __restrict__ sc, const unsigned short* __restrict__ kvbf,
    const int* __restrict__ offs, const int* __restrict__ csrc,
    unsigned short* __restrict__ agg, int M)
{
  int nb = blockIdx.x;
  int bid = (nb & 7) * 1250 + (nb >> 3);
  int gw = bid * 4 + (int)(threadIdx.x >> 6);
  int lane = threadIdx.x & 63;
  int n = gw >> 1, hp = gw & 1;
  if (n >= M) return;
  int col = hp * 64 + lane;
  const int e0 = offs[n], e1 = offs[n + 1];
  if (e0 == e1) {
    agg[(size_t)n * 128 + col] = 0;
    return;
  }
  const int h2 = hp * 2 + (lane >> 5);
  const int l31 = lane & 31;
  const float* scp = sc + (size_t)h2 * E_;

  float denp = 0.f, acc = 0.f;
  for (int c = e0; c < e1; c += 32) {
    int e = c + l31;
    bool val = e < e1;
    float w = val ? __expf(scp[e]) : 0.f;
    int sv = val ? csrc[e] : 0;
    denp += w;
    int cnt = e1 - c; if (cnt > 32) cnt = 32;
    int cnt4 = (cnt + 3) & ~3;
    for (int i = 0; i < cnt4; i += 4) {
      float wb0 = __shfl(w, (lane & 32) + i + 0);
      float wb1 = __shfl(w, (lane & 32) + i + 1);
      float wb2 = __shfl(w, (lane & 32) + i + 2);
      float wb3 = __shfl(w, (lane & 32) + i + 3);
      int sb0 = __shfl(sv, i + 0);
      int sb1 = __shfl(sv, i + 1);
      int sb2 = __shfl(sv, i + 2);
      int sb3 = __shfl(sv, i + 3);
      float v0 = bf2f(kvbf[(size_t)sb0 * 256 + 128 + col]);
      float v1 = bf2f(kvbf[(size_t)sb1 * 256 + 128 + col]);
      float v2 = bf2f(kvbf[(size_t)sb2 * 256 + 128 + col]);
      float v3 = bf2f(kvbf[(size_t)sb3 * 256 + 128 + col]);
      acc = fmaf(wb0, v0, acc);
      acc = fmaf(wb1, v1, acc);
      acc = fmaf(wb2, v2, acc);
      acc = fmaf(wb3, v3, acc);
    }
  }
  float den = denp;
  den += __shfl_xor(den, 1);
  den += __shfl_xor(den, 2);
  den += __shfl_xor(den, 4);
  den += __shfl_xor(den, 8);
  den += __shfl_xor(den, 16);
  agg[(size_t)n * 128 + col] = f2bf(acc / den);
}

// ---------------------------------------------------------------------------
// Column sum, two-stage, no atomics
// ---------------------------------------------------------------------------
__global__ __launch_bounds__(256) void colsum1_k(
    const float* __restrict__ h, float* __restrict__ partial, int M)
{
  __shared__ float sd[8][128];
  int tid = threadIdx.x;
  int cq = (tid & 31) * 4;
  int rg = tid >> 5;
  float4 s = make_float4(0.f, 0.f, 0.f, 0.f);
  for (int r = blockIdx.x * 8 + rg; r < M; r += gridDim.x * 8) {
    float4 v = *(const float4*)(h + (size_t)r * 128 + cq);
    s.x += v.x; s.y += v.y; s.z += v.z; s.w += v.w;
  }
  *(float4*)&sd[rg][cq] = s;
  __syncthreads();
  if (tid < 32) {
    int c4 = tid * 4;
    float4 a = *(float4*)&sd[0][c4];
#pragma unroll
    for (int g2 = 1; g2 < 8; ++g2) {
      float4 b = *(float4*)&sd[g2][c4];
      a.x += b.x; a.y += b.y; a.z += b.z; a.w += b.w;
    }
    *(float4*)&partial[(size_t)blockIdx.x * 128 + c4] = a;
  }
}

__global__ __launch_bounds__(256) void colsum2_k(
    const float* __restrict__ partial, float* __restrict__ gsum, int P)
{
  __shared__ float sd[256];
  int tid = threadIdx.x;
  int col = tid & 127, half = tid >> 7;
  float s = 0.f;
  for (int i = half; i < P; i += 2) s += partial[(size_t)i * 128 + col];
  sd[tid] = s;
  __syncthreads();
  if (tid < 128) gsum[tid] = sd[tid] + sd[tid + 128];
}

__global__ __launch_bounds__(256) void classifier_k(
    const float* __restrict__ gsum,
    const float* __restrict__ lnw, const float* __restrict__ lnb,
    const float* __restrict__ cw1, const float* __restrict__ cb1,
    const float* __restrict__ cw2, const float* __restrict__ cb2,
    const float* __restrict__ clsw, const float* __restrict__ clsb,
    float* __restrict__ out_logits, float* __restrict__ out_g, float invN)
{
  __shared__ float z[128], h1[256], z2[128];
  int tid = threadIdx.x;
  if (tid < 128) {
    float gg = gsum[tid] * invN;
    out_g[tid] = gg;
    z[tid] = gg;
  }
  __syncthreads();
  if (tid < 64) {
    float a = z[tid], b2 = z[tid + 64];
    float s = a + b2;
#pragma unroll
    for (int d = 1; d < 64; d <<= 1) s += __shfl_xor(s, d);
    float mean = s * (1.f / 128.f);
    float ea = a - mean, eb = b2 - mean;
    float sq = ea * ea + eb * eb;
#pragma unroll
    for (int d = 1; d < 64; d <<= 1) sq += __shfl_xor(sq, d);
    float rstd = rsqrtf(sq * (1.f / 128.f) + 1e-5f);
    z[tid]      = ea * rstd * lnw[tid] + lnb[tid];
    z[tid + 64] = eb * rstd * lnw[tid + 64] + lnb[tid + 64];
  }
  __syncthreads();
  {
    float acc = cb1[tid];
    for (int f = 0; f < 128; ++f) acc = fmaf(z[f], cw1[f * 256 + tid], acc);
    h1[tid] = gelu_f(acc);
  }
  __syncthreads();
  if (tid < 128) {
    float acc = cb2[tid];
    for (int f = 0; f < 256; ++f) acc = fmaf(h1[f], cw2[f * 128 + tid], acc);
    z2[tid] = acc;
  }
  __syncthreads();
  if (tid < 10) {
    float acc = clsb[tid];
    for (int f = 0; f < 128; ++f) acc = fmaf(z2[f], clsw[f * 10 + tid], acc);
    out_logits[tid] = acc;
  }
}

// ---------------------------------------------------------------------------
extern "C" void kernel_launch(void* const* d_in, const int* in_sizes, int n_in,
                              void* d_out, int out_size, void* d_ws, size_t ws_size,
                              hipStream_t stream) {
  const float* node_features = (const float*)d_in[0];
  const int*   ei            = (const int*)d_in[1];
  const float* emb_w = (const float*)d_in[3];
  const float* emb_b = (const float*)d_in[4];
  const float* qw  = (const float*)d_in[7];  const float* qb  = (const float*)d_in[8];
  const float* kw  = (const float*)d_in[9];  const float* kb  = (const float*)d_in[10];
  const float* vw  = (const float*)d_in[11]; const float* vb  = (const float*)d_in[12];
  const float* ow  = (const float*)d_in[13]; const float* ob  = (const float*)d_in[14];
  const float* lnw = (const float*)d_in[15]; const float* lnb = (const float*)d_in[16];
  const float* mw1 = (const float*)d_in[17]; const float* mb1 = (const float*)d_in[18];
  const float* mw2 = (const float*)d_in[19]; const float* mb2 = (const float*)d_in[20];
  const float* clnw = (const float*)d_in[21]; const float* clnb = (const float*)d_in[22];
  const float* cw1 = (const float*)d_in[23]; const float* cb1 = (const float*)d_in[24];
  const float* cw2 = (const float*)d_in[25]; const float* cb2 = (const float*)d_in[26];
  const float* clsw = (const float*)d_in[27]; const float* clsb = (const float*)d_in[28];

  float* out = (float*)d_out;
  float* out_h = out + 10;
  float* out_g = out + 10 + (size_t)N_ * DIM_;

  char* p = (char*)d_ws;
  auto alloc = [&](size_t bytes) { char* r = p; p += (bytes + 255) & ~(size_t)255; return r; };

  float* h    = (float*)alloc((size_t)MP_ * 128 * 4);
  float* qbuf = (float*)alloc((size_t)MP_ * 128 * 4);
  float* tmp  = (float*)alloc((size_t)MP_ * 128 * 4);
  unsigned short* kvbf = (unsigned short*)alloc((size_t)MP_ * 256 * 2);
  float* scb  = (float*)alloc((size_t)4 * E_ * 4);
  unsigned short* h_hi = (unsigned short*)alloc((size_t)MP_ * 128 * 2);
  unsigned short* h_lo = (unsigned short*)alloc((size_t)MP_ * 128 * 2);
  unsigned short* sp   = (unsigned short*)alloc((size_t)MP_ * 128 * 2);   // agg bf16
  unsigned short* lnB  = (unsigned short*)alloc((size_t)MP_ * 128 * 2);   // LN bf16
  unsigned short* hid  = (unsigned short*)alloc((size_t)MP_ * 512 * 2);
  unsigned short* wqkv_hi = (unsigned short*)alloc((size_t)L_ * 384 * 128 * 2);
  unsigned short* wqkv_lo = (unsigned short*)alloc((size_t)L_ * 384 * 128 * 2);
  unsigned short* wo_hi   = (unsigned short*)alloc((size_t)L_ * 128 * 128 * 2);
  unsigned short* wo_lo   = (unsigned short*)alloc((size_t)L_ * 128 * 128 * 2);
  unsigned short* w1_hi   = (unsigned short*)alloc((size_t)L_ * 512 * 128 * 2);
  unsigned short* w1_lo   = (unsigned short*)alloc((size_t)L_ * 512 * 128 * 2);
  unsigned short* w2_hi   = (unsigned short*)alloc((size_t)L_ * 128 * 512 * 2);
  unsigned short* w2_lo   = (unsigned short*)alloc((size_t)L_ * 128 * 512 * 2);
  unsigned short* we_hi   = (unsigned short*)alloc((size_t)128 * 64 * 2);
  unsigned short* we_lo   = (unsigned short*)alloc((size_t)128 * 64 * 2);
  float* qkvb = (float*)alloc((size_t)L_ * 384 * 4);
  float* gsum = (float*)alloc(128 * 4);
  float* cpart = (float*)alloc((size_t)256 * 128 * 4);
  int* deg  = (int*)alloc((size_t)N_ * 4);
  int* cur  = (int*)alloc((size_t)N_ * 4);
  int* offs = (int*)alloc(((size_t)N_ + 1) * 4);
  int* csrc = (int*)alloc((size_t)E_ * 4);
  int* cdst = (int*)alloc((size_t)E_ * 4);
  unsigned short* nf_hi = hid;
  unsigned short* nf_lo = hid + (size_t)MP_ * 64;

  const int* esrc = ei;
  const int* edst = ei + E_;

  prep_k<<<2048, 256, 0, stream>>>(
      qw, kw, vw, ow, mw1, mw2, emb_w, qb, kb, vb, node_features,
      wqkv_hi, wqkv_lo, wo_hi, wo_lo, w1_hi, w1_lo, w2_hi, w2_lo,
      we_hi, we_lo, qkvb, nf_hi, nf_lo, deg, cur);

  deg_k<<<(E_ + 255) / 256, 256, 0, stream>>>(edst, deg, E_);
  scan_k<<<1, 1024, 0, stream>>>(deg, offs, N_);
  fill_k<<<(E_ + 255) / 256, 256, 0, stream>>>(esrc, edst, offs, cur, csrc, cdst, E_);

  // grids: 8 XCDs * RPB row-groups * NCY col-chunks
  const dim3 g_embed(8 * 40 * 2);
  const dim3 g_qkv(8 * 40 * 6);
  const dim3 g_up(8 * 40 * 8);
  const dim3 g_down(8 * 79 * 2);

  // embed: h = nf @ emb_w + emb_b (fp32 + hi/lo planes for qkv)
  mgemm3_k<64, 128, 0, true, 1, false, true, 2><<<g_embed, 128, 0, stream>>>(
      nf_hi, nf_lo, we_hi, we_lo, emb_b, nullptr, h, nullptr, h_hi, h_lo, N_);

  for (int i = 0; i < L_; ++i) {
    const unsigned short* wq_h = wqkv_hi + (size_t)i * 384 * 128;
    const unsigned short* wq_l = wqkv_lo + (size_t)i * 384 * 128;

    // fused QKV -> q fp32 (pre-scaled) + kv bf16 packed
    mgemm3_k<128, 384, 0, false, 0, true, true, 2><<<g_qkv, 128, 0, stream>>>(
        h_hi, h_lo, wq_h, wq_l, qkvb + (size_t)i * 384, nullptr,
        qbuf, nullptr, kvbf, nullptr, N_);

    scores_k<<<5000, 256, 0, stream>>>(qbuf, kvbf, csrc, cdst, scb);
    agg_k<<<10000, 256, 0, stream>>>(scb, kvbf, offs, csrc, sp, N_);

    // fused O-proj + residual(h) + LN -> tmp fp32 + lnB bf16
    ogemm_ln_k<<<dim3((N_ + 31) / 32), 128, 0, stream>>>(
        sp, wo_hi + (size_t)i * 128 * 128, wo_lo + (size_t)i * 128 * 128,
        ob + (size_t)i * 128, h, lnw + (size_t)i * 128, lnb + (size_t)i * 128,
        tmp, lnB, N_);

    // MLP up: hid (single bf16) = gelu(lnB @ mw1 + mb1)
    mgemm3_k<128, 512, 1, false, 2, false, false, 2><<<g_up, 128, 0, stream>>>(
        lnB, nullptr, w1_hi + (size_t)i * 512 * 128, w1_lo + (size_t)i * 512 * 128,
        mb1 + (size_t)i * 512, nullptr, nullptr, nullptr, hid, nullptr, N_);

    // MLP down + residual(tmp): h = hid @ mw2 + mb2 + tmp
    if (i == L_ - 1) {
      mgemm3_k<512, 128, 2, true, 0, false, false, 1><<<g_down, 128, 0, stream>>>(
          hid, nullptr, w2_hi + (size_t)i * 128 * 512, w2_lo + (size_t)i * 128 * 512,
          mb2 + (size_t)i * 128, tmp, h, out_h, nullptr, nullptr, N_);
    } else {
      mgemm3_k<512, 128, 2, true, 1, false, false, 1><<<g_down, 128, 0, stream>>>(
          hid, nullptr, w2_hi + (size_t)i * 128 * 512, w2_lo + (size_t)i * 128 * 512,
          mb2 + (size_t)i * 128, tmp, h, nullptr, h_hi, h_lo, N_);
    }
  }

  colsum1_k<<<256, 256, 0, stream>>>(h, cpart, N_);
  colsum2_k<<<1, 256, 0, stream>>>(cpart, gsum, 256);
  classifier_k<<<1, 256, 0, stream>>>(gsum, clnw, clnb, cw1, cb1, cw2, cb2, clsw, clsb,
                                      out, out_g, 1.0f / (float)N_);
}